// Round 1
// baseline (3622.356 us; speedup 1.0000x reference)
//
#include <hip/hip_runtime.h>
#include <hip/hip_bf16.h>
#include <math.h>

#define D_MODEL 1024
#define N_LAYERS 4
#define INTER 2048
#define D_CONV 4
#define D_STATE 16
#define DT_RANK 64
#define B_SZ 4
#define SEQ 1024
#define TOK (B_SZ*SEQ)          // 4096 token rows
#define XROWS 128               // x_proj rows padded 96 -> 128
#define EPSV 1e-5f

typedef unsigned short u16;
typedef __attribute__((ext_vector_type(8))) short bf16x8;
typedef __attribute__((ext_vector_type(4))) float f32x4;

__device__ __forceinline__ u16 f2b(float f) {
    union { float f; unsigned u; } v; v.f = f;
    unsigned r = v.u + 0x7fffu + ((v.u >> 16) & 1u);
    return (u16)(r >> 16);
}
__device__ __forceinline__ float b2f(u16 h) {
    union { unsigned u; float f; } v; v.u = ((unsigned)h) << 16;
    return v.f;
}
__device__ __forceinline__ float silu(float x) {
    return x / (1.f + __expf(-x));
}

// ---------------------------------------------------------------------------
// GEMM: C[M,N] = A[M,K] @ B[N,K]^T   (A,B bf16 row-major, fp32 MFMA accum)
// 128x128 tile, 4 waves (2x2), each wave 4x4 fragments of 16x16x32.
// EPI: 0 = fp32 store, 1 = bf16 store, 2 = softplus(acc+aux[col]) -> bf16,
//      3 = fp32 store of aux[idx] + acc (residual add; aux may alias C)
// ---------------------------------------------------------------------------
template<int EPI>
__global__ __launch_bounds__(256)
void gemm_bt(const u16* __restrict__ A, const u16* __restrict__ B,
             void* __restrict__ C, const float* __restrict__ aux,
             int K, int ldc)
{
    __shared__ u16 As[128 * 32];
    __shared__ u16 Bs[128 * 32];
    const int tid  = threadIdx.x;
    const int lane = tid & 63;
    const int w    = tid >> 6;
    const int wr   = w >> 1, wc = w & 1;
    const int row0 = blockIdx.y * 128;
    const int col0 = blockIdx.x * 128;
    const int r16   = lane & 15;
    const int khalf = lane >> 4;      // 0..3

    f32x4 acc[4][4];
#pragma unroll
    for (int m = 0; m < 4; ++m)
#pragma unroll
        for (int n = 0; n < 4; ++n)
            acc[m][n] = (f32x4)0.f;

    for (int k0 = 0; k0 < K; k0 += 32) {
        __syncthreads();
#pragma unroll
        for (int c = 0; c < 2; ++c) {
            int chunk = tid + c * 256;           // 0..511
            int r  = chunk >> 2;                 // 0..127
            int k8 = (chunk & 3) * 8;
            *(bf16x8*)&As[r * 32 + k8] =
                *(const bf16x8*)&A[(size_t)(row0 + r) * K + k0 + k8];
            *(bf16x8*)&Bs[r * 32 + k8] =
                *(const bf16x8*)&B[(size_t)(col0 + r) * K + k0 + k8];
        }
        __syncthreads();
        bf16x8 af[4], bfr[4];
#pragma unroll
        for (int m = 0; m < 4; ++m)
            af[m]  = *(const bf16x8*)&As[(wr * 64 + m * 16 + r16) * 32 + khalf * 8];
#pragma unroll
        for (int n = 0; n < 4; ++n)
            bfr[n] = *(const bf16x8*)&Bs[(wc * 64 + n * 16 + r16) * 32 + khalf * 8];
#pragma unroll
        for (int m = 0; m < 4; ++m)
#pragma unroll
            for (int n = 0; n < 4; ++n)
                acc[m][n] = __builtin_amdgcn_mfma_f32_16x16x32_bf16(
                    af[m], bfr[n], acc[m][n], 0, 0, 0);
    }

    const int orow = row0 + wr * 64;
    const int ocol = col0 + wc * 64;
#pragma unroll
    for (int m = 0; m < 4; ++m)
#pragma unroll
        for (int n = 0; n < 4; ++n) {
#pragma unroll
            for (int r = 0; r < 4; ++r) {
                int rr = orow + m * 16 + khalf * 4 + r;
                int cc = ocol + n * 16 + r16;
                float v = acc[m][n][r];
                size_t o = (size_t)rr * ldc + cc;
                if (EPI == 0) {
                    ((float*)C)[o] = v;
                } else if (EPI == 1) {
                    ((u16*)C)[o] = f2b(v);
                } else if (EPI == 2) {
                    float x = v + aux[cc];
                    float sp = (x > 20.f) ? x : log1pf(__expf(x));
                    ((u16*)C)[o] = f2b(sp);
                } else {
                    ((float*)C)[o] = aux[o] + v;
                }
            }
        }
}

// ---------------------------------------------------------------------------
// RMSNorm over rows of 1024 fp32. OUTBF=1 -> bf16 out, else fp32 out.
// ---------------------------------------------------------------------------
template<int OUTBF>
__global__ __launch_bounds__(256)
void rmsnorm_k(const float* __restrict__ in, const float* __restrict__ w,
               void* __restrict__ out)
{
    __shared__ float red[4];
    const int row = blockIdx.x;
    const int tid = threadIdx.x;
    const float* r = in + (size_t)row * D_MODEL;
    f32x4 v = *(const f32x4*)&r[tid * 4];
    float ss = v[0]*v[0] + v[1]*v[1] + v[2]*v[2] + v[3]*v[3];
#pragma unroll
    for (int m = 32; m >= 1; m >>= 1) ss += __shfl_xor(ss, m, 64);
    if ((tid & 63) == 0) red[tid >> 6] = ss;
    __syncthreads();
    if (tid == 0) {
        float s = red[0] + red[1] + red[2] + red[3];
        red[0] = rsqrtf(s / (float)D_MODEL + EPSV);
    }
    __syncthreads();
    float sc = red[0];
    if (OUTBF) {
        u16* o = (u16*)out + (size_t)row * D_MODEL + tid * 4;
#pragma unroll
        for (int j = 0; j < 4; ++j) o[j] = f2b(v[j] * sc * w[tid * 4 + j]);
    } else {
        float* o = (float*)out + (size_t)row * D_MODEL + tid * 4;
#pragma unroll
        for (int j = 0; j < 4; ++j) o[j] = v[j] * sc * w[tid * 4 + j];
    }
}

// ---------------------------------------------------------------------------
// Depthwise causal conv (width 4) + bias + SiLU.  hs = proj_bf[:, 0:2048].
// ---------------------------------------------------------------------------
__global__ __launch_bounds__(256)
void conv_silu_k(const u16* __restrict__ projbf, const float* __restrict__ w,
                 const float* __restrict__ bias, u16* __restrict__ ubf)
{
    int idx = blockIdx.x * 256 + threadIdx.x;      // over TOK*INTER
    if (idx >= TOK * INTER) return;
    int i   = idx & (INTER - 1);
    int row = idx >> 11;
    int t   = row & (SEQ - 1);
    float acc = bias[i];
    const f32x4 wv = *(const f32x4*)&w[i * 4];
#pragma unroll
    for (int k = 0; k < 4; ++k) {
        int tt = t - 3 + k;
        if (tt >= 0)
            acc += b2f(projbf[(size_t)(row - 3 + k) * 4096 + i]) * wv[k];
    }
    ubf[idx] = f2b(silu(acc));
}

// ssm[:, 0:64] fp32 -> bf16 (dt_proj A-operand)
__global__ __launch_bounds__(256)
void cvt_dtr_k(const float* __restrict__ ssm, u16* __restrict__ dtr)
{
    int idx = blockIdx.x * 256 + threadIdx.x;      // TOK*64
    if (idx >= TOK * 64) return;
    int r = idx >> 6, c = idx & 63;
    dtr[idx] = f2b(ssm[(size_t)r * XROWS + c]);
}

// ---------------------------------------------------------------------------
// Selective scan. 4 lanes per channel, 4 states per lane. Fuses skip (D*u)
// and gate*silu, writes y bf16 for out_proj.
// grid = 8192*4/64 = 512 blocks of 64.
// ---------------------------------------------------------------------------
__global__ __launch_bounds__(64)
void scan_k(const u16* __restrict__ dtbf, const u16* __restrict__ ubf,
            const float* __restrict__ ssm, const u16* __restrict__ projbf,
            const float* __restrict__ Alog, const float* __restrict__ Dp,
            u16* __restrict__ ybf)
{
    const int tid  = threadIdx.x;
    const int chan = blockIdx.x * 16 + (tid >> 2);   // 0..8191
    const int sub  = tid & 3;
    const int n0   = sub * 4;
    const int b    = chan >> 11;
    const int i    = chan & (INTER - 1);

    float a[4];
#pragma unroll
    for (int j = 0; j < 4; ++j)
        a[j] = -__expf(Alog[(size_t)i * D_STATE + n0 + j]);
    const float Di = Dp[i];

    const u16*  dtp = dtbf  + (size_t)b * SEQ * INTER + i;
    const u16*  up  = ubf   + (size_t)b * SEQ * INTER + i;
    const float* bp = ssm   + (size_t)b * SEQ * XROWS + DT_RANK + n0;
    const u16*  gp  = projbf + (size_t)b * SEQ * 4096 + INTER + i;
    u16*        yp  = ybf   + (size_t)b * SEQ * INTER + i;

    float s0 = 0.f, s1 = 0.f, s2 = 0.f, s3 = 0.f;
    for (int t = 0; t < SEQ; ++t) {
        float dt = b2f(*dtp);
        float u  = b2f(*up);
        f32x4 Bv = *(const f32x4*)bp;
        f32x4 Cv = *(const f32x4*)(bp + D_STATE);
        float du = dt * u;
        s0 = __expf(dt * a[0]) * s0 + du * Bv[0];
        s1 = __expf(dt * a[1]) * s1 + du * Bv[1];
        s2 = __expf(dt * a[2]) * s2 + du * Bv[2];
        s3 = __expf(dt * a[3]) * s3 + du * Bv[3];
        float y = s0 * Cv[0] + s1 * Cv[1] + s2 * Cv[2] + s3 * Cv[3];
        y += __shfl_xor(y, 1, 64);
        y += __shfl_xor(y, 2, 64);
        if (sub == 0) {
            float g = b2f(*gp);
            yp[0] = f2b((y + Di * u) * silu(g));
        }
        dtp += INTER; up += INTER; bp += XROWS; gp += 4096; yp += INTER;
    }
}

// ---------------------------------------------------------------------------
// Weight conversion fp32 -> bf16
// ---------------------------------------------------------------------------
__global__ __launch_bounds__(256)
void cvt_f2b_k(const float* __restrict__ in, u16* __restrict__ out, int n)
{
    int idx = blockIdx.x * 256 + threadIdx.x;
    if (idx < n) out[idx] = f2b(in[idx]);
}

// x_w [4,96,2048] -> padded bf16 [4,128,2048] (rows 96..127 zero)
__global__ __launch_bounds__(256)
void pad_xw_k(const float* __restrict__ xw, u16* __restrict__ out)
{
    int idx = blockIdx.x * 256 + threadIdx.x;      // 4*128*2048
    if (idx >= N_LAYERS * XROWS * INTER) return;
    int l = idx / (XROWS * INTER);
    int r = (idx >> 11) & (XROWS - 1);
    int c = idx & (INTER - 1);
    out[idx] = (r < 96) ? f2b(xw[((size_t)l * 96 + r) * INTER + c]) : (u16)0;
}

// ---------------------------------------------------------------------------
extern "C" void kernel_launch(void* const* d_in, const int* in_sizes, int n_in,
                              void* d_out, int out_size, void* d_ws, size_t ws_size,
                              hipStream_t stream)
{
    const float* x      = (const float*)d_in[0];
    const float* in_w   = (const float*)d_in[1];
    const float* conv_w = (const float*)d_in[2];
    const float* conv_b = (const float*)d_in[3];
    const float* x_w    = (const float*)d_in[4];
    const float* dt_w   = (const float*)d_in[5];
    const float* dt_b   = (const float*)d_in[6];
    const float* A_log  = (const float*)d_in[7];
    const float* Dp     = (const float*)d_in[8];
    const float* out_w  = (const float*)d_in[9];
    const float* norm_w = (const float*)d_in[10];
    const float* norm_f = (const float*)d_in[11];

    char* ws = (char*)d_ws;
    size_t off = 0;
    auto alloc = [&](size_t bytes) { char* p = ws + off; off += (bytes + 255) & ~(size_t)255; return p; };

    u16*   inw_bf  = (u16*)  alloc((size_t)N_LAYERS * 4096 * 1024 * 2);
    u16*   xw_bf   = (u16*)  alloc((size_t)N_LAYERS * XROWS * INTER * 2);
    u16*   dtw_bf  = (u16*)  alloc((size_t)N_LAYERS * INTER * DT_RANK * 2);
    u16*   outw_bf = (u16*)  alloc((size_t)N_LAYERS * D_MODEL * INTER * 2);
    float* h       = (float*)alloc((size_t)TOK * D_MODEL * 4);
    u16*   xn_bf   = (u16*)  alloc((size_t)TOK * D_MODEL * 2);
    u16*   proj_bf = (u16*)  alloc((size_t)TOK * 4096 * 2);
    u16*   u_bf    = (u16*)  alloc((size_t)TOK * INTER * 2);
    float* ssm     = (float*)alloc((size_t)TOK * XROWS * 4);
    u16*   dtr_bf  = (u16*)  alloc((size_t)TOK * DT_RANK * 2);
    u16*   dt_bf   = (u16*)  alloc((size_t)TOK * INTER * 2);
    u16*   y_bf    = (u16*)  alloc((size_t)TOK * INTER * 2);
    (void)ws_size; (void)n_in; (void)in_sizes; (void)out_size;

    // weight conversion (every launch; deterministic)
    {
        int n = N_LAYERS * 4096 * 1024;
        cvt_f2b_k<<<n / 256, 256, 0, stream>>>(in_w, inw_bf, n);
        int np = N_LAYERS * XROWS * INTER;
        pad_xw_k<<<np / 256, 256, 0, stream>>>(x_w, xw_bf);
        int nd = N_LAYERS * INTER * DT_RANK;
        cvt_f2b_k<<<nd / 256, 256, 0, stream>>>(dt_w, dtw_bf, nd);
        int no = N_LAYERS * D_MODEL * INTER;
        cvt_f2b_k<<<no / 256, 256, 0, stream>>>(out_w, outw_bf, no);
    }

    hipMemcpyAsync(h, x, (size_t)TOK * D_MODEL * 4, hipMemcpyDeviceToDevice, stream);

    for (int l = 0; l < N_LAYERS; ++l) {
        // 1. rmsnorm -> xn_bf
        rmsnorm_k<1><<<TOK, 256, 0, stream>>>(h, norm_w + (size_t)l * D_MODEL, xn_bf);
        // 2. in_proj: [4096,1024] @ [4096,1024]^T -> proj_bf [4096,4096]
        gemm_bt<1><<<dim3(32, 32), 256, 0, stream>>>(
            xn_bf, inw_bf + (size_t)l * 4096 * 1024, proj_bf, nullptr, 1024, 4096);
        // 3. conv + silu -> u_bf
        conv_silu_k<<<(TOK * INTER) / 256, 256, 0, stream>>>(
            proj_bf, conv_w + (size_t)l * INTER * D_CONV, conv_b + (size_t)l * INTER, u_bf);
        // 4. x_proj: [4096,2048] @ [128,2048]^T -> ssm fp32 [4096,128]
        gemm_bt<0><<<dim3(1, 32), 256, 0, stream>>>(
            u_bf, xw_bf + (size_t)l * XROWS * INTER, ssm, nullptr, INTER, XROWS);
        // 5. dt rank cols -> bf16
        cvt_dtr_k<<<(TOK * DT_RANK) / 256, 256, 0, stream>>>(ssm, dtr_bf);
        // 6. dt_proj + softplus -> dt_bf [4096,2048]
        gemm_bt<2><<<dim3(16, 32), 256, 0, stream>>>(
            dtr_bf, dtw_bf + (size_t)l * INTER * DT_RANK, dt_bf,
            dt_b + (size_t)l * INTER, DT_RANK, INTER);
        // 7. scan (+ skip + gate) -> y_bf
        scan_k<<<512, 64, 0, stream>>>(
            dt_bf, u_bf, ssm, proj_bf,
            A_log + (size_t)l * INTER * D_STATE, Dp + (size_t)l * INTER, y_bf);
        // 8. out_proj + residual -> h
        gemm_bt<3><<<dim3(8, 32), 256, 0, stream>>>(
            y_bf, outw_bf + (size_t)l * D_MODEL * INTER, h, h, INTER, D_MODEL);
    }
    // final rmsnorm -> d_out (fp32)
    rmsnorm_k<0><<<TOK, 256, 0, stream>>>(h, norm_f, d_out);
}

// Round 2
// 1675.997 us; speedup vs baseline: 2.1613x; 2.1613x over previous
//
#include <hip/hip_runtime.h>
#include <hip/hip_bf16.h>
#include <math.h>

#define D_MODEL 1024
#define N_LAYERS 4
#define INTER 2048
#define D_CONV 4
#define D_STATE 16
#define DT_RANK 64
#define B_SZ 4
#define SEQ 1024
#define TOK (B_SZ*SEQ)          // 4096 token rows
#define XROWS 128               // x_proj rows padded 96 -> 128
#define EPSV 1e-5f
#define GCH 8                   // scan chunks
#define TC (SEQ/GCH)            // 128 timesteps per chunk

typedef unsigned short u16;
typedef __attribute__((ext_vector_type(8))) short bf16x8;
typedef __attribute__((ext_vector_type(4))) float f32x4;

__device__ __forceinline__ u16 f2b(float f) {
    union { float f; unsigned u; } v; v.f = f;
    unsigned r = v.u + 0x7fffu + ((v.u >> 16) & 1u);
    return (u16)(r >> 16);
}
__device__ __forceinline__ float b2f(u16 h) {
    union { unsigned u; float f; } v; v.u = ((unsigned)h) << 16;
    return v.f;
}
__device__ __forceinline__ float silu(float x) {
    return x / (1.f + __expf(-x));
}
__device__ __forceinline__ void gload16(const void* g, void* l) {
    __builtin_amdgcn_global_load_lds(
        (const __attribute__((address_space(1))) void*)g,
        (__attribute__((address_space(3))) void*)l, 16, 0, 0);
}

// ---------------------------------------------------------------------------
// GEMM: C[M,N] = A[M,K] @ B[N,K]^T   (A,B bf16 row-major, fp32 MFMA accum)
// 128x128 tile, 4 waves (2x2), each wave 4x4 fragments of 16x16x32.
// Staging via global_load_lds width=16 (m97 recipe): LDS layout is
// chunk-linear in tid order, dest = wave-uniform base + lane*16.
// EPI: 0 = fp32 store, 1 = bf16 store, 2 = softplus(acc+aux[col]) -> bf16,
//      3 = fp32 store of aux[idx] + acc (residual add; aux may alias C)
// ---------------------------------------------------------------------------
template<int EPI>
__global__ __launch_bounds__(256)
void gemm_bt(const u16* __restrict__ A, const u16* __restrict__ B,
             void* __restrict__ C, const float* __restrict__ aux,
             int K, int ldc)
{
    __shared__ u16 As[128 * 32];
    __shared__ u16 Bs[128 * 32];
    const int tid  = threadIdx.x;
    const int lane = tid & 63;
    const int w    = tid >> 6;
    const int wr   = w >> 1, wc = w & 1;
    const int row0 = blockIdx.y * 128;
    const int col0 = blockIdx.x * 128;
    const int r16   = lane & 15;
    const int khalf = lane >> 4;      // 0..3

    f32x4 acc[4][4];
#pragma unroll
    for (int m = 0; m < 4; ++m)
#pragma unroll
        for (int n = 0; n < 4; ++n)
            acc[m][n] = (f32x4)0.f;

    for (int k0 = 0; k0 < K; k0 += 32) {
        __syncthreads();   // previous iter's ds_reads done before overwrite
#pragma unroll
        for (int c = 0; c < 2; ++c) {
            int chunk = tid + c * 256;           // 0..511, 16B each
            int r  = chunk >> 2;                 // 0..127
            int k8 = (chunk & 3) * 8;
            gload16(&A[(size_t)(row0 + r) * K + k0 + k8], &As[chunk * 8]);
            gload16(&B[(size_t)(col0 + r) * K + k0 + k8], &Bs[chunk * 8]);
        }
        __syncthreads();   // vmcnt(0) drain -> LDS filled
        bf16x8 af[4], bfr[4];
#pragma unroll
        for (int m = 0; m < 4; ++m)
            af[m]  = *(const bf16x8*)&As[(wr * 64 + m * 16 + r16) * 32 + khalf * 8];
#pragma unroll
        for (int n = 0; n < 4; ++n)
            bfr[n] = *(const bf16x8*)&Bs[(wc * 64 + n * 16 + r16) * 32 + khalf * 8];
#pragma unroll
        for (int m = 0; m < 4; ++m)
#pragma unroll
            for (int n = 0; n < 4; ++n)
                acc[m][n] = __builtin_amdgcn_mfma_f32_16x16x32_bf16(
                    af[m], bfr[n], acc[m][n], 0, 0, 0);
    }

    const int orow = row0 + wr * 64;
    const int ocol = col0 + wc * 64;
#pragma unroll
    for (int m = 0; m < 4; ++m)
#pragma unroll
        for (int n = 0; n < 4; ++n) {
#pragma unroll
            for (int r = 0; r < 4; ++r) {
                int rr = orow + m * 16 + khalf * 4 + r;
                int cc = ocol + n * 16 + r16;
                float v = acc[m][n][r];
                size_t o = (size_t)rr * ldc + cc;
                if (EPI == 0) {
                    ((float*)C)[o] = v;
                } else if (EPI == 1) {
                    ((u16*)C)[o] = f2b(v);
                } else if (EPI == 2) {
                    float x = v + aux[cc];
                    float sp = (x > 20.f) ? x : log1pf(__expf(x));
                    ((u16*)C)[o] = f2b(sp);
                } else {
                    ((float*)C)[o] = aux[o] + v;
                }
            }
        }
}

// ---------------------------------------------------------------------------
// RMSNorm over rows of 1024 fp32. OUTBF=1 -> bf16 out, else fp32 out.
// ---------------------------------------------------------------------------
template<int OUTBF>
__global__ __launch_bounds__(256)
void rmsnorm_k(const float* __restrict__ in, const float* __restrict__ w,
               void* __restrict__ out)
{
    __shared__ float red[4];
    const int row = blockIdx.x;
    const int tid = threadIdx.x;
    const float* r = in + (size_t)row * D_MODEL;
    f32x4 v = *(const f32x4*)&r[tid * 4];
    float ss = v[0]*v[0] + v[1]*v[1] + v[2]*v[2] + v[3]*v[3];
#pragma unroll
    for (int m = 32; m >= 1; m >>= 1) ss += __shfl_xor(ss, m, 64);
    if ((tid & 63) == 0) red[tid >> 6] = ss;
    __syncthreads();
    if (tid == 0) {
        float s = red[0] + red[1] + red[2] + red[3];
        red[0] = rsqrtf(s / (float)D_MODEL + EPSV);
    }
    __syncthreads();
    float sc = red[0];
    if (OUTBF) {
        u16* o = (u16*)out + (size_t)row * D_MODEL + tid * 4;
#pragma unroll
        for (int j = 0; j < 4; ++j) o[j] = f2b(v[j] * sc * w[tid * 4 + j]);
    } else {
        float* o = (float*)out + (size_t)row * D_MODEL + tid * 4;
#pragma unroll
        for (int j = 0; j < 4; ++j) o[j] = v[j] * sc * w[tid * 4 + j];
    }
}

// ---------------------------------------------------------------------------
// Depthwise causal conv (width 4) + bias + SiLU.  hs = proj_bf[:, 0:2048].
// ---------------------------------------------------------------------------
__global__ __launch_bounds__(256)
void conv_silu_k(const u16* __restrict__ projbf, const float* __restrict__ w,
                 const float* __restrict__ bias, u16* __restrict__ ubf)
{
    int idx = blockIdx.x * 256 + threadIdx.x;      // over TOK*INTER
    if (idx >= TOK * INTER) return;
    int i   = idx & (INTER - 1);
    int row = idx >> 11;
    int t   = row & (SEQ - 1);
    float acc = bias[i];
    const f32x4 wv = *(const f32x4*)&w[i * 4];
#pragma unroll
    for (int k = 0; k < 4; ++k) {
        int tt = t - 3 + k;
        if (tt >= 0)
            acc += b2f(projbf[(size_t)(row - 3 + k) * 4096 + i]) * wv[k];
    }
    ubf[idx] = f2b(silu(acc));
}

// ssm[:, 0:64] fp32 -> bf16 (dt_proj A-operand)
__global__ __launch_bounds__(256)
void cvt_dtr_k(const float* __restrict__ ssm, u16* __restrict__ dtr)
{
    int idx = blockIdx.x * 256 + threadIdx.x;      // TOK*64
    if (idx >= TOK * 64) return;
    int r = idx >> 6, c = idx & 63;
    dtr[idx] = f2b(ssm[(size_t)r * XROWS + c]);
}

// ---------------------------------------------------------------------------
// Chunked parallel selective scan. One lane per channel, 16 states in regs.
//   pass1: per (b,i,chunk) local scan (zero init) -> final state + dt-sum
//   pass2: sequential combine over the GCH chunk boundaries -> start states
//   pass3: recompute local scans with true start state, emit y (fused skip+gate)
// ---------------------------------------------------------------------------
__global__ __launch_bounds__(256)
void scan1_k(const u16* __restrict__ dtbf, const u16* __restrict__ ubf,
             const float* __restrict__ ssm, const float* __restrict__ Alog,
             float* __restrict__ cst, float* __restrict__ dts)
{
    __shared__ float Bs[TC][D_STATE];
    const int tid = threadIdx.x;
    const int i   = blockIdx.x * 256 + tid;
    const int g   = blockIdx.y;
    const int b   = blockIdx.z;
    const int t0  = g * TC;
    for (int idx = tid * 4; idx < TC * D_STATE; idx += 1024) {
        int t = idx >> 4, n = idx & 15;
        *(f32x4*)&Bs[t][n] =
            *(const f32x4*)&ssm[(size_t)(b * SEQ + t0 + t) * XROWS + DT_RANK + n];
    }
    __syncthreads();

    float a[D_STATE];
#pragma unroll
    for (int n = 0; n < D_STATE; ++n)
        a[n] = -__expf(Alog[(size_t)i * D_STATE + n]);

    float s[D_STATE];
#pragma unroll
    for (int n = 0; n < D_STATE; ++n) s[n] = 0.f;
    float dsum = 0.f;

    const u16* dtp = dtbf + (size_t)(b * SEQ + t0) * INTER + i;
    const u16* up  = ubf  + (size_t)(b * SEQ + t0) * INTER + i;
#pragma unroll 2
    for (int t = 0; t < TC; ++t) {
        float dt = b2f(dtp[(size_t)t * INTER]);
        float u  = b2f(up[(size_t)t * INTER]);
        float du = dt * u;
        dsum += dt;
        f32x4 B0 = *(const f32x4*)&Bs[t][0];
        f32x4 B1 = *(const f32x4*)&Bs[t][4];
        f32x4 B2 = *(const f32x4*)&Bs[t][8];
        f32x4 B3 = *(const f32x4*)&Bs[t][12];
#pragma unroll
        for (int n = 0; n < 4; ++n) {
            s[n]      = __expf(dt * a[n])      * s[n]      + du * B0[n];
            s[n + 4]  = __expf(dt * a[n + 4])  * s[n + 4]  + du * B1[n];
            s[n + 8]  = __expf(dt * a[n + 8])  * s[n + 8]  + du * B2[n];
            s[n + 12] = __expf(dt * a[n + 12]) * s[n + 12] + du * B3[n];
        }
    }
    size_t o = ((size_t)(b * GCH + g) * INTER + i) * D_STATE;
#pragma unroll
    for (int n = 0; n < D_STATE; n += 4) {
        f32x4 v = { s[n], s[n+1], s[n+2], s[n+3] };
        *(f32x4*)&cst[o + n] = v;
    }
    dts[(size_t)(b * GCH + g) * INTER + i] = dsum;
}

__global__ __launch_bounds__(256)
void scan2_k(const float* __restrict__ cst, const float* __restrict__ dts,
             const float* __restrict__ Alog, float* __restrict__ sst)
{
    int idx = blockIdx.x * 256 + threadIdx.x;    // 0..8191
    int b = idx >> 11, i = idx & (INTER - 1);
    float a[D_STATE];
#pragma unroll
    for (int n = 0; n < D_STATE; ++n)
        a[n] = -__expf(Alog[(size_t)i * D_STATE + n]);
    float s[D_STATE];
#pragma unroll
    for (int n = 0; n < D_STATE; ++n) s[n] = 0.f;
    for (int g = 0; g < GCH; ++g) {
        size_t o = ((size_t)(b * GCH + g) * INTER + i) * D_STATE;
#pragma unroll
        for (int n = 0; n < D_STATE; n += 4) {
            f32x4 v = { s[n], s[n+1], s[n+2], s[n+3] };
            *(f32x4*)&sst[o + n] = v;
        }
        float d = dts[(size_t)(b * GCH + g) * INTER + i];
#pragma unroll
        for (int n = 0; n < D_STATE; ++n)
            s[n] = __expf(a[n] * d) * s[n] + cst[o + n];
    }
}

__global__ __launch_bounds__(256)
void scan3_k(const u16* __restrict__ dtbf, const u16* __restrict__ ubf,
             const float* __restrict__ ssm, const u16* __restrict__ projbf,
             const float* __restrict__ Alog, const float* __restrict__ Dp,
             const float* __restrict__ sst, u16* __restrict__ ybf)
{
    __shared__ float Bs[TC][D_STATE];
    __shared__ float Cs[TC][D_STATE];
    const int tid = threadIdx.x;
    const int i   = blockIdx.x * 256 + tid;
    const int g   = blockIdx.y;
    const int b   = blockIdx.z;
    const int t0  = g * TC;
    for (int idx = tid * 4; idx < TC * D_STATE; idx += 1024) {
        int t = idx >> 4, n = idx & 15;
        size_t row = (size_t)(b * SEQ + t0 + t) * XROWS;
        *(f32x4*)&Bs[t][n] = *(const f32x4*)&ssm[row + DT_RANK + n];
        *(f32x4*)&Cs[t][n] = *(const f32x4*)&ssm[row + DT_RANK + D_STATE + n];
    }
    __syncthreads();

    float a[D_STATE];
#pragma unroll
    for (int n = 0; n < D_STATE; ++n)
        a[n] = -__expf(Alog[(size_t)i * D_STATE + n]);
    const float Di = Dp[i];

    float s[D_STATE];
    size_t so = ((size_t)(b * GCH + g) * INTER + i) * D_STATE;
#pragma unroll
    for (int n = 0; n < D_STATE; n += 4) {
        f32x4 v = *(const f32x4*)&sst[so + n];
        s[n] = v[0]; s[n+1] = v[1]; s[n+2] = v[2]; s[n+3] = v[3];
    }

    const u16* dtp = dtbf   + (size_t)(b * SEQ + t0) * INTER + i;
    const u16* up  = ubf    + (size_t)(b * SEQ + t0) * INTER + i;
    const u16* gp  = projbf + (size_t)(b * SEQ + t0) * 4096 + INTER + i;
    u16*       yp  = ybf    + (size_t)(b * SEQ + t0) * INTER + i;
#pragma unroll 2
    for (int t = 0; t < TC; ++t) {
        float dt = b2f(dtp[(size_t)t * INTER]);
        float u  = b2f(up[(size_t)t * INTER]);
        float gt = b2f(gp[(size_t)t * 4096]);
        float du = dt * u;
        f32x4 B0 = *(const f32x4*)&Bs[t][0];
        f32x4 B1 = *(const f32x4*)&Bs[t][4];
        f32x4 B2 = *(const f32x4*)&Bs[t][8];
        f32x4 B3 = *(const f32x4*)&Bs[t][12];
        f32x4 C0 = *(const f32x4*)&Cs[t][0];
        f32x4 C1 = *(const f32x4*)&Cs[t][4];
        f32x4 C2 = *(const f32x4*)&Cs[t][8];
        f32x4 C3 = *(const f32x4*)&Cs[t][12];
        float y = 0.f;
#pragma unroll
        for (int n = 0; n < 4; ++n) {
            s[n]      = __expf(dt * a[n])      * s[n]      + du * B0[n];
            s[n + 4]  = __expf(dt * a[n + 4])  * s[n + 4]  + du * B1[n];
            s[n + 8]  = __expf(dt * a[n + 8])  * s[n + 8]  + du * B2[n];
            s[n + 12] = __expf(dt * a[n + 12]) * s[n + 12] + du * B3[n];
            y += s[n] * C0[n] + s[n + 4] * C1[n] + s[n + 8] * C2[n] + s[n + 12] * C3[n];
        }
        yp[(size_t)t * INTER] = f2b((y + Di * u) * silu(gt));
    }
}

// ---------------------------------------------------------------------------
// Weight conversion fp32 -> bf16
// ---------------------------------------------------------------------------
__global__ __launch_bounds__(256)
void cvt_f2b_k(const float* __restrict__ in, u16* __restrict__ out, int n)
{
    int idx = blockIdx.x * 256 + threadIdx.x;
    if (idx < n) out[idx] = f2b(in[idx]);
}

// x_w [4,96,2048] -> padded bf16 [4,128,2048] (rows 96..127 zero)
__global__ __launch_bounds__(256)
void pad_xw_k(const float* __restrict__ xw, u16* __restrict__ out)
{
    int idx = blockIdx.x * 256 + threadIdx.x;      // 4*128*2048
    if (idx >= N_LAYERS * XROWS * INTER) return;
    int l = idx / (XROWS * INTER);
    int r = (idx >> 11) & (XROWS - 1);
    int c = idx & (INTER - 1);
    out[idx] = (r < 96) ? f2b(xw[((size_t)l * 96 + r) * INTER + c]) : (u16)0;
}

// ---------------------------------------------------------------------------
extern "C" void kernel_launch(void* const* d_in, const int* in_sizes, int n_in,
                              void* d_out, int out_size, void* d_ws, size_t ws_size,
                              hipStream_t stream)
{
    const float* x      = (const float*)d_in[0];
    const float* in_w   = (const float*)d_in[1];
    const float* conv_w = (const float*)d_in[2];
    const float* conv_b = (const float*)d_in[3];
    const float* x_w    = (const float*)d_in[4];
    const float* dt_w   = (const float*)d_in[5];
    const float* dt_b   = (const float*)d_in[6];
    const float* A_log  = (const float*)d_in[7];
    const float* Dp     = (const float*)d_in[8];
    const float* out_w  = (const float*)d_in[9];
    const float* norm_w = (const float*)d_in[10];
    const float* norm_f = (const float*)d_in[11];

    char* ws = (char*)d_ws;
    size_t off = 0;
    auto alloc = [&](size_t bytes) { char* p = ws + off; off += (bytes + 255) & ~(size_t)255; return p; };

    u16*   inw_bf  = (u16*)  alloc((size_t)N_LAYERS * 4096 * 1024 * 2);
    u16*   xw_bf   = (u16*)  alloc((size_t)N_LAYERS * XROWS * INTER * 2);
    u16*   dtw_bf  = (u16*)  alloc((size_t)N_LAYERS * INTER * DT_RANK * 2);
    u16*   outw_bf = (u16*)  alloc((size_t)N_LAYERS * D_MODEL * INTER * 2);
    float* h       = (float*)alloc((size_t)TOK * D_MODEL * 4);
    u16*   xn_bf   = (u16*)  alloc((size_t)TOK * D_MODEL * 2);
    u16*   proj_bf = (u16*)  alloc((size_t)TOK * 4096 * 2);
    u16*   u_bf    = (u16*)  alloc((size_t)TOK * INTER * 2);
    float* ssm     = (float*)alloc((size_t)TOK * XROWS * 4);
    u16*   dtr_bf  = (u16*)  alloc((size_t)TOK * DT_RANK * 2);
    u16*   dt_bf   = (u16*)  alloc((size_t)TOK * INTER * 2);
    u16*   y_bf    = (u16*)  alloc((size_t)TOK * INTER * 2);
    float* cst     = (float*)alloc((size_t)B_SZ * GCH * INTER * D_STATE * 4);
    float* sst     = (float*)alloc((size_t)B_SZ * GCH * INTER * D_STATE * 4);
    float* dts     = (float*)alloc((size_t)B_SZ * GCH * INTER * 4);
    (void)ws_size; (void)n_in; (void)in_sizes; (void)out_size;

    // weight conversion (every launch; deterministic)
    {
        int n = N_LAYERS * 4096 * 1024;
        cvt_f2b_k<<<n / 256, 256, 0, stream>>>(in_w, inw_bf, n);
        int np = N_LAYERS * XROWS * INTER;
        pad_xw_k<<<np / 256, 256, 0, stream>>>(x_w, xw_bf);
        int nd = N_LAYERS * INTER * DT_RANK;
        cvt_f2b_k<<<nd / 256, 256, 0, stream>>>(dt_w, dtw_bf, nd);
        int no = N_LAYERS * D_MODEL * INTER;
        cvt_f2b_k<<<no / 256, 256, 0, stream>>>(out_w, outw_bf, no);
    }

    hipMemcpyAsync(h, x, (size_t)TOK * D_MODEL * 4, hipMemcpyDeviceToDevice, stream);

    for (int l = 0; l < N_LAYERS; ++l) {
        // 1. rmsnorm -> xn_bf
        rmsnorm_k<1><<<TOK, 256, 0, stream>>>(h, norm_w + (size_t)l * D_MODEL, xn_bf);
        // 2. in_proj: [4096,1024] @ [4096,1024]^T -> proj_bf [4096,4096]
        gemm_bt<1><<<dim3(32, 32), 256, 0, stream>>>(
            xn_bf, inw_bf + (size_t)l * 4096 * 1024, proj_bf, nullptr, 1024, 4096);
        // 3. conv + silu -> u_bf
        conv_silu_k<<<(TOK * INTER) / 256, 256, 0, stream>>>(
            proj_bf, conv_w + (size_t)l * INTER * D_CONV, conv_b + (size_t)l * INTER, u_bf);
        // 4. x_proj: [4096,2048] @ [128,2048]^T -> ssm fp32 [4096,128]
        gemm_bt<0><<<dim3(1, 32), 256, 0, stream>>>(
            u_bf, xw_bf + (size_t)l * XROWS * INTER, ssm, nullptr, INTER, XROWS);
        // 5. dt rank cols -> bf16
        cvt_dtr_k<<<(TOK * DT_RANK) / 256, 256, 0, stream>>>(ssm, dtr_bf);
        // 6. dt_proj + softplus -> dt_bf [4096,2048]
        gemm_bt<2><<<dim3(16, 32), 256, 0, stream>>>(
            dtr_bf, dtw_bf + (size_t)l * INTER * DT_RANK, dt_bf,
            dt_b + (size_t)l * INTER, DT_RANK, INTER);
        // 7. chunked scan (+ skip + gate) -> y_bf
        scan1_k<<<dim3(INTER / 256, GCH, B_SZ), 256, 0, stream>>>(
            dt_bf, u_bf, ssm, A_log + (size_t)l * INTER * D_STATE, cst, dts);
        scan2_k<<<(B_SZ * INTER) / 256, 256, 0, stream>>>(
            cst, dts, A_log + (size_t)l * INTER * D_STATE, sst);
        scan3_k<<<dim3(INTER / 256, GCH, B_SZ), 256, 0, stream>>>(
            dt_bf, u_bf, ssm, proj_bf, A_log + (size_t)l * INTER * D_STATE,
            Dp + (size_t)l * INTER, sst, y_bf);
        // 8. out_proj + residual -> h
        gemm_bt<3><<<dim3(8, 32), 256, 0, stream>>>(
            y_bf, outw_bf + (size_t)l * D_MODEL * INTER, h, h, INTER, D_MODEL);
    }
    // final rmsnorm -> d_out (fp32)
    rmsnorm_k<0><<<TOK, 256, 0, stream>>>(h, norm_f, d_out);
}

// Round 3
// 1252.521 us; speedup vs baseline: 2.8921x; 1.3381x over previous
//
#include <hip/hip_runtime.h>
#include <hip/hip_bf16.h>
#include <math.h>

#define D_MODEL 1024
#define N_LAYERS 4
#define INTER 2048
#define D_CONV 4
#define D_STATE 16
#define DT_RANK 64
#define B_SZ 4
#define SEQ 1024
#define TOK (B_SZ*SEQ)          // 4096 token rows
#define XROWS 128               // x_proj rows padded 96 -> 128
#define EPSV 1e-5f
#define GCH 32                  // scan chunks (32 -> 1024 blocks -> 4 blocks/CU)
#define TC (SEQ/GCH)            // 32 timesteps per chunk

typedef unsigned short u16;
typedef __attribute__((ext_vector_type(8))) short bf16x8;
typedef __attribute__((ext_vector_type(4))) float f32x4;

__device__ __forceinline__ u16 f2b(float f) {
    union { float f; unsigned u; } v; v.f = f;
    unsigned r = v.u + 0x7fffu + ((v.u >> 16) & 1u);
    return (u16)(r >> 16);
}
__device__ __forceinline__ float b2f(u16 h) {
    union { unsigned u; float f; } v; v.u = ((unsigned)h) << 16;
    return v.f;
}
__device__ __forceinline__ float silu(float x) {
    return x / (1.f + __expf(-x));
}
__device__ __forceinline__ void gload16(const void* g, void* l) {
    __builtin_amdgcn_global_load_lds(
        (const __attribute__((address_space(1))) void*)g,
        (__attribute__((address_space(3))) void*)l, 16, 0, 0);
}

// ---------------------------------------------------------------------------
// GEMM: C[M,N] = A[M,K] @ B[N,K]^T   (A,B bf16 row-major, fp32 MFMA accum)
// 128x128 tile, 4 waves (2x2), each wave 4x4 fragments of 16x16x32.
// Staging via global_load_lds width=16 (m97 recipe).
// EPI: 0 = fp32 store, 1 = bf16 store, 2 = softplus(acc+aux[col]) -> bf16,
//      3 = fp32 store of aux[idx] + acc (residual add; aux may alias C)
// ---------------------------------------------------------------------------
template<int EPI>
__global__ __launch_bounds__(256)
void gemm_bt(const u16* __restrict__ A, const u16* __restrict__ B,
             void* __restrict__ C, const float* __restrict__ aux,
             int K, int ldc)
{
    __shared__ u16 As[128 * 32];
    __shared__ u16 Bs[128 * 32];
    const int tid  = threadIdx.x;
    const int lane = tid & 63;
    const int w    = tid >> 6;
    const int wr   = w >> 1, wc = w & 1;
    const int row0 = blockIdx.y * 128;
    const int col0 = blockIdx.x * 128;
    const int r16   = lane & 15;
    const int khalf = lane >> 4;      // 0..3

    f32x4 acc[4][4];
#pragma unroll
    for (int m = 0; m < 4; ++m)
#pragma unroll
        for (int n = 0; n < 4; ++n)
            acc[m][n] = (f32x4)0.f;

    for (int k0 = 0; k0 < K; k0 += 32) {
        __syncthreads();   // previous iter's ds_reads done before overwrite
#pragma unroll
        for (int c = 0; c < 2; ++c) {
            int chunk = tid + c * 256;           // 0..511, 16B each
            int r  = chunk >> 2;                 // 0..127
            int k8 = (chunk & 3) * 8;
            gload16(&A[(size_t)(row0 + r) * K + k0 + k8], &As[chunk * 8]);
            gload16(&B[(size_t)(col0 + r) * K + k0 + k8], &Bs[chunk * 8]);
        }
        __syncthreads();   // vmcnt(0) drain -> LDS filled
        bf16x8 af[4], bfr[4];
#pragma unroll
        for (int m = 0; m < 4; ++m)
            af[m]  = *(const bf16x8*)&As[(wr * 64 + m * 16 + r16) * 32 + khalf * 8];
#pragma unroll
        for (int n = 0; n < 4; ++n)
            bfr[n] = *(const bf16x8*)&Bs[(wc * 64 + n * 16 + r16) * 32 + khalf * 8];
#pragma unroll
        for (int m = 0; m < 4; ++m)
#pragma unroll
            for (int n = 0; n < 4; ++n)
                acc[m][n] = __builtin_amdgcn_mfma_f32_16x16x32_bf16(
                    af[m], bfr[n], acc[m][n], 0, 0, 0);
    }

    const int orow = row0 + wr * 64;
    const int ocol = col0 + wc * 64;
#pragma unroll
    for (int m = 0; m < 4; ++m)
#pragma unroll
        for (int n = 0; n < 4; ++n) {
#pragma unroll
            for (int r = 0; r < 4; ++r) {
                int rr = orow + m * 16 + khalf * 4 + r;
                int cc = ocol + n * 16 + r16;
                float v = acc[m][n][r];
                size_t o = (size_t)rr * ldc + cc;
                if (EPI == 0) {
                    ((float*)C)[o] = v;
                } else if (EPI == 1) {
                    ((u16*)C)[o] = f2b(v);
                } else if (EPI == 2) {
                    float x = v + aux[cc];
                    float sp = (x > 20.f) ? x : log1pf(__expf(x));
                    ((u16*)C)[o] = f2b(sp);
                } else {
                    ((float*)C)[o] = aux[o] + v;
                }
            }
        }
}

// ---------------------------------------------------------------------------
// RMSNorm over rows of 1024 fp32. OUTBF=1 -> bf16 out, else fp32 out.
// ---------------------------------------------------------------------------
template<int OUTBF>
__global__ __launch_bounds__(256)
void rmsnorm_k(const float* __restrict__ in, const float* __restrict__ w,
               void* __restrict__ out)
{
    __shared__ float red[4];
    const int row = blockIdx.x;
    const int tid = threadIdx.x;
    const float* r = in + (size_t)row * D_MODEL;
    f32x4 v = *(const f32x4*)&r[tid * 4];
    float ss = v[0]*v[0] + v[1]*v[1] + v[2]*v[2] + v[3]*v[3];
#pragma unroll
    for (int m = 32; m >= 1; m >>= 1) ss += __shfl_xor(ss, m, 64);
    if ((tid & 63) == 0) red[tid >> 6] = ss;
    __syncthreads();
    if (tid == 0) {
        float s = red[0] + red[1] + red[2] + red[3];
        red[0] = rsqrtf(s / (float)D_MODEL + EPSV);
    }
    __syncthreads();
    float sc = red[0];
    if (OUTBF) {
        u16* o = (u16*)out + (size_t)row * D_MODEL + tid * 4;
#pragma unroll
        for (int j = 0; j < 4; ++j) o[j] = f2b(v[j] * sc * w[tid * 4 + j]);
    } else {
        float* o = (float*)out + (size_t)row * D_MODEL + tid * 4;
#pragma unroll
        for (int j = 0; j < 4; ++j) o[j] = v[j] * sc * w[tid * 4 + j];
    }
}

// ---------------------------------------------------------------------------
// Depthwise causal conv (width 4) + bias + SiLU.  hs = proj_bf[:, 0:2048].
// ---------------------------------------------------------------------------
__global__ __launch_bounds__(256)
void conv_silu_k(const u16* __restrict__ projbf, const float* __restrict__ w,
                 const float* __restrict__ bias, u16* __restrict__ ubf)
{
    int idx = blockIdx.x * 256 + threadIdx.x;      // over TOK*INTER
    if (idx >= TOK * INTER) return;
    int i   = idx & (INTER - 1);
    int row = idx >> 11;
    int t   = row & (SEQ - 1);
    float acc = bias[i];
    const f32x4 wv = *(const f32x4*)&w[i * 4];
#pragma unroll
    for (int k = 0; k < 4; ++k) {
        int tt = t - 3 + k;
        if (tt >= 0)
            acc += b2f(projbf[(size_t)(row - 3 + k) * 4096 + i]) * wv[k];
    }
    ubf[idx] = f2b(silu(acc));
}

// ssm[:, 0:64] fp32 -> bf16 (dt_proj A-operand)
__global__ __launch_bounds__(256)
void cvt_dtr_k(const float* __restrict__ ssm, u16* __restrict__ dtr)
{
    int idx = blockIdx.x * 256 + threadIdx.x;      // TOK*64
    if (idx >= TOK * 64) return;
    int r = idx >> 6, c = idx & 63;
    dtr[idx] = f2b(ssm[(size_t)r * XROWS + c]);
}

// ---------------------------------------------------------------------------
// Chunked parallel selective scan. One lane per channel, 16 states in regs.
//   pass1: per (b,i,chunk) local scan (zero init) -> final state + dt-sum
//   pass2: in-place over chunk boundaries: cstate[local] -> cstate[start]
//   pass3: recompute local scans with true start state, emit y (fused skip+gate)
// ---------------------------------------------------------------------------
__global__ __launch_bounds__(256)
void scan1_k(const u16* __restrict__ dtbf, const u16* __restrict__ ubf,
             const float* __restrict__ ssm, const float* __restrict__ Alog,
             float* __restrict__ cst, float* __restrict__ dts)
{
    __shared__ float Bs[TC][D_STATE];
    const int tid = threadIdx.x;
    const int i   = blockIdx.x * 256 + tid;
    const int g   = blockIdx.y;
    const int b   = blockIdx.z;
    const int t0  = g * TC;
    for (int idx = tid * 4; idx < TC * D_STATE; idx += 1024) {
        int t = idx >> 4, n = idx & 15;
        *(f32x4*)&Bs[t][n] =
            *(const f32x4*)&ssm[(size_t)(b * SEQ + t0 + t) * XROWS + DT_RANK + n];
    }
    __syncthreads();

    float a[D_STATE];
#pragma unroll
    for (int n = 0; n < D_STATE; ++n)
        a[n] = -__expf(Alog[(size_t)i * D_STATE + n]);

    float s[D_STATE];
#pragma unroll
    for (int n = 0; n < D_STATE; ++n) s[n] = 0.f;
    float dsum = 0.f;

    const u16* dtp = dtbf + (size_t)(b * SEQ + t0) * INTER + i;
    const u16* up  = ubf  + (size_t)(b * SEQ + t0) * INTER + i;
#pragma unroll 2
    for (int t = 0; t < TC; ++t) {
        float dt = b2f(dtp[(size_t)t * INTER]);
        float u  = b2f(up[(size_t)t * INTER]);
        float du = dt * u;
        dsum += dt;
        f32x4 B0 = *(const f32x4*)&Bs[t][0];
        f32x4 B1 = *(const f32x4*)&Bs[t][4];
        f32x4 B2 = *(const f32x4*)&Bs[t][8];
        f32x4 B3 = *(const f32x4*)&Bs[t][12];
#pragma unroll
        for (int n = 0; n < 4; ++n) {
            s[n]      = __expf(dt * a[n])      * s[n]      + du * B0[n];
            s[n + 4]  = __expf(dt * a[n + 4])  * s[n + 4]  + du * B1[n];
            s[n + 8]  = __expf(dt * a[n + 8])  * s[n + 8]  + du * B2[n];
            s[n + 12] = __expf(dt * a[n + 12]) * s[n + 12] + du * B3[n];
        }
    }
    size_t o = ((size_t)(b * GCH + g) * INTER + i) * D_STATE;
#pragma unroll
    for (int n = 0; n < D_STATE; n += 4) {
        f32x4 v = { s[n], s[n+1], s[n+2], s[n+3] };
        *(f32x4*)&cst[o + n] = v;
    }
    dts[(size_t)(b * GCH + g) * INTER + i] = dsum;
}

// in-place: cst holds local chunk-end states; rewrite to chunk-START states.
// one thread per (b, i, state-quad): 32768 threads.
__global__ __launch_bounds__(256)
void scan2_k(float* __restrict__ cst, const float* __restrict__ dts,
             const float* __restrict__ Alog)
{
    int idx = blockIdx.x * 256 + threadIdx.x;    // 0..B*INTER*4-1
    int sub = idx & 3;
    int i   = (idx >> 2) & (INTER - 1);
    int b   = idx >> 13;
    int n0  = sub * 4;
    float a[4];
#pragma unroll
    for (int n = 0; n < 4; ++n)
        a[n] = -__expf(Alog[(size_t)i * D_STATE + n0 + n]);
    f32x4 s = (f32x4)0.f;
    for (int g = 0; g < GCH; ++g) {
        size_t o = ((size_t)(b * GCH + g) * INTER + i) * D_STATE + n0;
        f32x4 tmp = *(const f32x4*)&cst[o];
        *(f32x4*)&cst[o] = s;                    // start state for chunk g
        float d = dts[(size_t)(b * GCH + g) * INTER + i];
#pragma unroll
        for (int n = 0; n < 4; ++n)
            s[n] = __expf(a[n] * d) * s[n] + tmp[n];
    }
}

__global__ __launch_bounds__(256)
void scan3_k(const u16* __restrict__ dtbf, const u16* __restrict__ ubf,
             const float* __restrict__ ssm, const u16* __restrict__ projbf,
             const float* __restrict__ Alog, const float* __restrict__ Dp,
             const float* __restrict__ sst, u16* __restrict__ ybf)
{
    __shared__ float Bs[TC][D_STATE];
    __shared__ float Cs[TC][D_STATE];
    const int tid = threadIdx.x;
    const int i   = blockIdx.x * 256 + tid;
    const int g   = blockIdx.y;
    const int b   = blockIdx.z;
    const int t0  = g * TC;
    for (int idx = tid * 4; idx < TC * D_STATE; idx += 1024) {
        int t = idx >> 4, n = idx & 15;
        size_t row = (size_t)(b * SEQ + t0 + t) * XROWS;
        *(f32x4*)&Bs[t][n] = *(const f32x4*)&ssm[row + DT_RANK + n];
        *(f32x4*)&Cs[t][n] = *(const f32x4*)&ssm[row + DT_RANK + D_STATE + n];
    }
    __syncthreads();

    float a[D_STATE];
#pragma unroll
    for (int n = 0; n < D_STATE; ++n)
        a[n] = -__expf(Alog[(size_t)i * D_STATE + n]);
    const float Di = Dp[i];

    float s[D_STATE];
    size_t so = ((size_t)(b * GCH + g) * INTER + i) * D_STATE;
#pragma unroll
    for (int n = 0; n < D_STATE; n += 4) {
        f32x4 v = *(const f32x4*)&sst[so + n];
        s[n] = v[0]; s[n+1] = v[1]; s[n+2] = v[2]; s[n+3] = v[3];
    }

    const u16* dtp = dtbf   + (size_t)(b * SEQ + t0) * INTER + i;
    const u16* up  = ubf    + (size_t)(b * SEQ + t0) * INTER + i;
    const u16* gp  = projbf + (size_t)(b * SEQ + t0) * 4096 + INTER + i;
    u16*       yp  = ybf    + (size_t)(b * SEQ + t0) * INTER + i;
#pragma unroll 2
    for (int t = 0; t < TC; ++t) {
        float dt = b2f(dtp[(size_t)t * INTER]);
        float u  = b2f(up[(size_t)t * INTER]);
        float gt = b2f(gp[(size_t)t * 4096]);
        float du = dt * u;
        f32x4 B0 = *(const f32x4*)&Bs[t][0];
        f32x4 B1 = *(const f32x4*)&Bs[t][4];
        f32x4 B2 = *(const f32x4*)&Bs[t][8];
        f32x4 B3 = *(const f32x4*)&Bs[t][12];
        f32x4 C0 = *(const f32x4*)&Cs[t][0];
        f32x4 C1 = *(const f32x4*)&Cs[t][4];
        f32x4 C2 = *(const f32x4*)&Cs[t][8];
        f32x4 C3 = *(const f32x4*)&Cs[t][12];
        float y = 0.f;
#pragma unroll
        for (int n = 0; n < 4; ++n) {
            s[n]      = __expf(dt * a[n])      * s[n]      + du * B0[n];
            s[n + 4]  = __expf(dt * a[n + 4])  * s[n + 4]  + du * B1[n];
            s[n + 8]  = __expf(dt * a[n + 8])  * s[n + 8]  + du * B2[n];
            s[n + 12] = __expf(dt * a[n + 12]) * s[n + 12] + du * B3[n];
            y += s[n] * C0[n] + s[n + 4] * C1[n] + s[n + 8] * C2[n] + s[n + 12] * C3[n];
        }
        yp[(size_t)t * INTER] = f2b((y + Di * u) * silu(gt));
    }
}

// ---------------------------------------------------------------------------
// Weight conversion fp32 -> bf16
// ---------------------------------------------------------------------------
__global__ __launch_bounds__(256)
void cvt_f2b_k(const float* __restrict__ in, u16* __restrict__ out, int n)
{
    int idx = blockIdx.x * 256 + threadIdx.x;
    if (idx < n) out[idx] = f2b(in[idx]);
}

// x_w [4,96,2048] -> padded bf16 [4,128,2048] (rows 96..127 zero)
__global__ __launch_bounds__(256)
void pad_xw_k(const float* __restrict__ xw, u16* __restrict__ out)
{
    int idx = blockIdx.x * 256 + threadIdx.x;      // 4*128*2048
    if (idx >= N_LAYERS * XROWS * INTER) return;
    int l = idx / (XROWS * INTER);
    int r = (idx >> 11) & (XROWS - 1);
    int c = idx & (INTER - 1);
    out[idx] = (r < 96) ? f2b(xw[((size_t)l * 96 + r) * INTER + c]) : (u16)0;
}

// ---------------------------------------------------------------------------
extern "C" void kernel_launch(void* const* d_in, const int* in_sizes, int n_in,
                              void* d_out, int out_size, void* d_ws, size_t ws_size,
                              hipStream_t stream)
{
    const float* x      = (const float*)d_in[0];
    const float* in_w   = (const float*)d_in[1];
    const float* conv_w = (const float*)d_in[2];
    const float* conv_b = (const float*)d_in[3];
    const float* x_w    = (const float*)d_in[4];
    const float* dt_w   = (const float*)d_in[5];
    const float* dt_b   = (const float*)d_in[6];
    const float* A_log  = (const float*)d_in[7];
    const float* Dp     = (const float*)d_in[8];
    const float* out_w  = (const float*)d_in[9];
    const float* norm_w = (const float*)d_in[10];
    const float* norm_f = (const float*)d_in[11];

    char* ws = (char*)d_ws;
    size_t off = 0;
    auto alloc = [&](size_t bytes) { char* p = ws + off; off += (bytes + 255) & ~(size_t)255; return p; };

    u16*   inw_bf  = (u16*)  alloc((size_t)N_LAYERS * 4096 * 1024 * 2);
    u16*   xw_bf   = (u16*)  alloc((size_t)N_LAYERS * XROWS * INTER * 2);
    u16*   dtw_bf  = (u16*)  alloc((size_t)N_LAYERS * INTER * DT_RANK * 2);
    u16*   outw_bf = (u16*)  alloc((size_t)N_LAYERS * D_MODEL * INTER * 2);
    float* h       = (float*)alloc((size_t)TOK * D_MODEL * 4);
    u16*   xn_bf   = (u16*)  alloc((size_t)TOK * D_MODEL * 2);
    u16*   proj_bf = (u16*)  alloc((size_t)TOK * 4096 * 2);
    u16*   u_bf    = (u16*)  alloc((size_t)TOK * INTER * 2);
    float* ssm     = (float*)alloc((size_t)TOK * XROWS * 4);
    u16*   dtr_bf  = (u16*)  alloc((size_t)TOK * DT_RANK * 2);
    u16*   dt_bf   = (u16*)  alloc((size_t)TOK * INTER * 2);
    u16*   y_bf    = (u16*)  alloc((size_t)TOK * INTER * 2);
    float* cst     = (float*)alloc((size_t)B_SZ * GCH * INTER * D_STATE * 4);
    float* dts     = (float*)alloc((size_t)B_SZ * GCH * INTER * 4);
    (void)ws_size; (void)n_in; (void)in_sizes; (void)out_size;

    // weight conversion (every launch; deterministic)
    {
        int n = N_LAYERS * 4096 * 1024;
        cvt_f2b_k<<<n / 256, 256, 0, stream>>>(in_w, inw_bf, n);
        int np = N_LAYERS * XROWS * INTER;
        pad_xw_k<<<np / 256, 256, 0, stream>>>(x_w, xw_bf);
        int nd = N_LAYERS * INTER * DT_RANK;
        cvt_f2b_k<<<nd / 256, 256, 0, stream>>>(dt_w, dtw_bf, nd);
        int no = N_LAYERS * D_MODEL * INTER;
        cvt_f2b_k<<<no / 256, 256, 0, stream>>>(out_w, outw_bf, no);
    }

    hipMemcpyAsync(h, x, (size_t)TOK * D_MODEL * 4, hipMemcpyDeviceToDevice, stream);

    for (int l = 0; l < N_LAYERS; ++l) {
        // 1. rmsnorm -> xn_bf
        rmsnorm_k<1><<<TOK, 256, 0, stream>>>(h, norm_w + (size_t)l * D_MODEL, xn_bf);
        // 2. in_proj: [4096,1024] @ [4096,1024]^T -> proj_bf [4096,4096]
        gemm_bt<1><<<dim3(32, 32), 256, 0, stream>>>(
            xn_bf, inw_bf + (size_t)l * 4096 * 1024, proj_bf, nullptr, 1024, 4096);
        // 3. conv + silu -> u_bf
        conv_silu_k<<<(TOK * INTER) / 256, 256, 0, stream>>>(
            proj_bf, conv_w + (size_t)l * INTER * D_CONV, conv_b + (size_t)l * INTER, u_bf);
        // 4. x_proj: [4096,2048] @ [128,2048]^T -> ssm fp32 [4096,128]
        gemm_bt<0><<<dim3(1, 32), 256, 0, stream>>>(
            u_bf, xw_bf + (size_t)l * XROWS * INTER, ssm, nullptr, INTER, XROWS);
        // 5. dt rank cols -> bf16
        cvt_dtr_k<<<(TOK * DT_RANK) / 256, 256, 0, stream>>>(ssm, dtr_bf);
        // 6. dt_proj + softplus -> dt_bf [4096,2048]
        gemm_bt<2><<<dim3(16, 32), 256, 0, stream>>>(
            dtr_bf, dtw_bf + (size_t)l * INTER * DT_RANK, dt_bf,
            dt_b + (size_t)l * INTER, DT_RANK, INTER);
        // 7. chunked scan (+ skip + gate) -> y_bf
        scan1_k<<<dim3(INTER / 256, GCH, B_SZ), 256, 0, stream>>>(
            dt_bf, u_bf, ssm, A_log + (size_t)l * INTER * D_STATE, cst, dts);
        scan2_k<<<(B_SZ * INTER * 4) / 256, 256, 0, stream>>>(
            cst, dts, A_log + (size_t)l * INTER * D_STATE);
        scan3_k<<<dim3(INTER / 256, GCH, B_SZ), 256, 0, stream>>>(
            dt_bf, u_bf, ssm, proj_bf, A_log + (size_t)l * INTER * D_STATE,
            Dp + (size_t)l * INTER, cst, y_bf);
        // 8. out_proj + residual -> h
        gemm_bt<3><<<dim3(8, 32), 256, 0, stream>>>(
            y_bf, outw_bf + (size_t)l * D_MODEL * INTER, h, h, INTER, D_MODEL);
    }
    // final rmsnorm -> d_out (fp32)
    rmsnorm_k<0><<<TOK, 256, 0, stream>>>(h, norm_f, d_out);
}

// Round 4
// 1180.369 us; speedup vs baseline: 3.0688x; 1.0611x over previous
//
#include <hip/hip_runtime.h>
#include <hip/hip_bf16.h>
#include <math.h>

#define D_MODEL 1024
#define N_LAYERS 4
#define INTER 2048
#define D_CONV 4
#define D_STATE 16
#define DT_RANK 64
#define B_SZ 4
#define SEQ 1024
#define TOK (B_SZ*SEQ)          // 4096 token rows
#define XROWS 128               // x_proj rows padded 96 -> 128
#define EPSV 1e-5f
#define GCH 32                  // scan chunks
#define TC (SEQ/GCH)            // 32 timesteps per chunk

typedef unsigned short u16;
typedef __attribute__((ext_vector_type(8))) short bf16x8;
typedef __attribute__((ext_vector_type(4))) float f32x4;

__device__ __forceinline__ u16 f2b(float f) {
    union { float f; unsigned u; } v; v.f = f;
    unsigned r = v.u + 0x7fffu + ((v.u >> 16) & 1u);
    return (u16)(r >> 16);
}
__device__ __forceinline__ float b2f(u16 h) {
    union { unsigned u; float f; } v; v.u = ((unsigned)h) << 16;
    return v.f;
}
__device__ __forceinline__ float silu(float x) {
    return x / (1.f + __expf(-x));
}
__device__ __forceinline__ void gload16(const void* g, void* l) {
    __builtin_amdgcn_global_load_lds(
        (const __attribute__((address_space(1))) void*)g,
        (__attribute__((address_space(3))) void*)l, 16, 0, 0);
}

// ---------------------------------------------------------------------------
// GEMM: C[M,N] = A[M,K] @ B[N,K]^T   (A,B bf16 row-major, fp32 MFMA accum)
// 128x128 tile, 4 waves (2x2), each wave 4x4 fragments of 16x16x32.
// Double-buffered LDS; next tile's global_load_lds issued BEFORE current
// tile's ds_read+MFMA so loads land under compute (T3 minimal 2-phase).
// EPI: 0 = fp32 store, 1 = bf16 store, 2 = softplus(acc+aux[col]) -> bf16,
//      3 = fp32 store of aux[idx] + acc (residual add; aux may alias C)
//      4 = fp32 store + bf16 copy of cols < DT_RANK into auxb
// ---------------------------------------------------------------------------
template<int EPI>
__global__ __launch_bounds__(256)
void gemm_bt(const u16* __restrict__ A, const u16* __restrict__ B,
             void* __restrict__ C, const float* __restrict__ aux,
             void* __restrict__ auxb, int K, int ldc)
{
    __shared__ u16 As[2][128 * 32];
    __shared__ u16 Bs[2][128 * 32];
    const int tid  = threadIdx.x;
    const int lane = tid & 63;
    const int w    = tid >> 6;
    const int wr   = w >> 1, wc = w & 1;
    const int row0 = blockIdx.y * 128;
    const int col0 = blockIdx.x * 128;
    const int r16   = lane & 15;
    const int khalf = lane >> 4;      // 0..3

    auto stage = [&](int buf, int k0) {
#pragma unroll
        for (int c = 0; c < 2; ++c) {
            int chunk = tid + c * 256;           // 0..511, 16B each
            int r  = chunk >> 2;                 // 0..127
            int k8 = (chunk & 3) * 8;
            gload16(&A[(size_t)(row0 + r) * K + k0 + k8], &As[buf][chunk * 8]);
            gload16(&B[(size_t)(col0 + r) * K + k0 + k8], &Bs[buf][chunk * 8]);
        }
    };

    f32x4 acc[4][4];
#pragma unroll
    for (int m = 0; m < 4; ++m)
#pragma unroll
        for (int n = 0; n < 4; ++n)
            acc[m][n] = (f32x4)0.f;

    const int nt = K >> 5;
    stage(0, 0);
    asm volatile("s_waitcnt vmcnt(0)" ::: "memory");
    __builtin_amdgcn_s_barrier();

    int cur = 0;
    for (int t = 0; t < nt; ++t) {
        if (t + 1 < nt) stage(cur ^ 1, (t + 1) << 5);
        asm volatile("" ::: "memory");   // keep stage-issue ahead of ds_reads
        bf16x8 af[4], bfr[4];
#pragma unroll
        for (int m = 0; m < 4; ++m)
            af[m]  = *(const bf16x8*)&As[cur][(wr * 64 + m * 16 + r16) * 32 + khalf * 8];
#pragma unroll
        for (int n = 0; n < 4; ++n)
            bfr[n] = *(const bf16x8*)&Bs[cur][(wc * 64 + n * 16 + r16) * 32 + khalf * 8];
#pragma unroll
        for (int m = 0; m < 4; ++m)
#pragma unroll
            for (int n = 0; n < 4; ++n)
                acc[m][n] = __builtin_amdgcn_mfma_f32_16x16x32_bf16(
                    af[m], bfr[n], acc[m][n], 0, 0, 0);
        asm volatile("s_waitcnt vmcnt(0)" ::: "memory");  // next tile staged
        __builtin_amdgcn_s_barrier();
        cur ^= 1;
    }

    const int orow = row0 + wr * 64;
    const int ocol = col0 + wc * 64;
#pragma unroll
    for (int m = 0; m < 4; ++m)
#pragma unroll
        for (int n = 0; n < 4; ++n) {
#pragma unroll
            for (int r = 0; r < 4; ++r) {
                int rr = orow + m * 16 + khalf * 4 + r;
                int cc = ocol + n * 16 + r16;
                float v = acc[m][n][r];
                size_t o = (size_t)rr * ldc + cc;
                if (EPI == 0) {
                    ((float*)C)[o] = v;
                } else if (EPI == 1) {
                    ((u16*)C)[o] = f2b(v);
                } else if (EPI == 2) {
                    float x = v + aux[cc];
                    float sp = (x > 20.f) ? x : log1pf(__expf(x));
                    ((u16*)C)[o] = f2b(sp);
                } else if (EPI == 3) {
                    ((float*)C)[o] = aux[o] + v;
                } else {
                    ((float*)C)[o] = v;
                    if (cc < DT_RANK)     // uniform per wave (wc==0, n<4)
                        ((u16*)auxb)[(size_t)rr * DT_RANK + cc] = f2b(v);
                }
            }
        }
}

// ---------------------------------------------------------------------------
// RMSNorm over rows of 1024 fp32. OUTBF=1 -> bf16 out, else fp32 out.
// ---------------------------------------------------------------------------
template<int OUTBF>
__global__ __launch_bounds__(256)
void rmsnorm_k(const float* __restrict__ in, const float* __restrict__ w,
               void* __restrict__ out)
{
    __shared__ float red[4];
    const int row = blockIdx.x;
    const int tid = threadIdx.x;
    const float* r = in + (size_t)row * D_MODEL;
    f32x4 v = *(const f32x4*)&r[tid * 4];
    float ss = v[0]*v[0] + v[1]*v[1] + v[2]*v[2] + v[3]*v[3];
#pragma unroll
    for (int m = 32; m >= 1; m >>= 1) ss += __shfl_xor(ss, m, 64);
    if ((tid & 63) == 0) red[tid >> 6] = ss;
    __syncthreads();
    if (tid == 0) {
        float s = red[0] + red[1] + red[2] + red[3];
        red[0] = rsqrtf(s / (float)D_MODEL + EPSV);
    }
    __syncthreads();
    float sc = red[0];
    if (OUTBF) {
        u16* o = (u16*)out + (size_t)row * D_MODEL + tid * 4;
#pragma unroll
        for (int j = 0; j < 4; ++j) o[j] = f2b(v[j] * sc * w[tid * 4 + j]);
    } else {
        float* o = (float*)out + (size_t)row * D_MODEL + tid * 4;
#pragma unroll
        for (int j = 0; j < 4; ++j) o[j] = v[j] * sc * w[tid * 4 + j];
    }
}

// ---------------------------------------------------------------------------
// Depthwise causal conv (width 4) + bias + SiLU, vectorized 8 channels/thread.
// grid = TOK blocks x 256 threads. hs = proj_bf[:, 0:2048].
// ---------------------------------------------------------------------------
__global__ __launch_bounds__(256)
void conv_silu_k(const u16* __restrict__ projbf, const float* __restrict__ w,
                 const float* __restrict__ bias, u16* __restrict__ ubf)
{
    const int row = blockIdx.x;               // 0..TOK-1
    const int t   = row & (SEQ - 1);
    const int i0  = threadIdx.x * 8;
    float acc[8];
    {
        f32x4 b0 = *(const f32x4*)&bias[i0];
        f32x4 b1 = *(const f32x4*)&bias[i0 + 4];
#pragma unroll
        for (int j = 0; j < 4; ++j) { acc[j] = b0[j]; acc[j + 4] = b1[j]; }
    }
    f32x4 wv[8];
#pragma unroll
    for (int j = 0; j < 8; ++j)
        wv[j] = *(const f32x4*)&w[(i0 + j) * 4];
#pragma unroll
    for (int k = 0; k < 4; ++k) {
        int tt = t - 3 + k;
        if (tt >= 0) {
            bf16x8 hv = *(const bf16x8*)&projbf[(size_t)(row - 3 + k) * 4096 + i0];
#pragma unroll
            for (int j = 0; j < 8; ++j)
                acc[j] += b2f((u16)hv[j]) * wv[j][k];
        }
    }
    bf16x8 o;
#pragma unroll
    for (int j = 0; j < 8; ++j)
        o[j] = (short)f2b(silu(acc[j]));
    *(bf16x8*)&ubf[(size_t)row * INTER + i0] = o;
}

// ---------------------------------------------------------------------------
// Chunked parallel selective scan. One lane per channel, 16 states in regs.
//   pass1: per (b,i,chunk) local scan (zero init) -> final state + dt-sum
//   pass2: in-place over chunk boundaries: cstate[local] -> cstate[start]
//   pass3: recompute local scans with true start state, emit y (fused skip+gate)
// ---------------------------------------------------------------------------
__global__ __launch_bounds__(256)
void scan1_k(const u16* __restrict__ dtbf, const u16* __restrict__ ubf,
             const float* __restrict__ ssm, const float* __restrict__ Alog,
             float* __restrict__ cst, float* __restrict__ dts)
{
    __shared__ float Bs[TC][D_STATE];
    const int tid = threadIdx.x;
    const int i   = blockIdx.x * 256 + tid;
    const int g   = blockIdx.y;
    const int b   = blockIdx.z;
    const int t0  = g * TC;
    for (int idx = tid * 4; idx < TC * D_STATE; idx += 1024) {
        int t = idx >> 4, n = idx & 15;
        *(f32x4*)&Bs[t][n] =
            *(const f32x4*)&ssm[(size_t)(b * SEQ + t0 + t) * XROWS + DT_RANK + n];
    }
    __syncthreads();

    float a[D_STATE];
#pragma unroll
    for (int n = 0; n < D_STATE; ++n)
        a[n] = -__expf(Alog[(size_t)i * D_STATE + n]);

    float s[D_STATE];
#pragma unroll
    for (int n = 0; n < D_STATE; ++n) s[n] = 0.f;
    float dsum = 0.f;

    const u16* dtp = dtbf + (size_t)(b * SEQ + t0) * INTER + i;
    const u16* up  = ubf  + (size_t)(b * SEQ + t0) * INTER + i;
#pragma unroll 2
    for (int t = 0; t < TC; ++t) {
        float dt = b2f(dtp[(size_t)t * INTER]);
        float u  = b2f(up[(size_t)t * INTER]);
        float du = dt * u;
        dsum += dt;
        f32x4 B0 = *(const f32x4*)&Bs[t][0];
        f32x4 B1 = *(const f32x4*)&Bs[t][4];
        f32x4 B2 = *(const f32x4*)&Bs[t][8];
        f32x4 B3 = *(const f32x4*)&Bs[t][12];
#pragma unroll
        for (int n = 0; n < 4; ++n) {
            s[n]      = __expf(dt * a[n])      * s[n]      + du * B0[n];
            s[n + 4]  = __expf(dt * a[n + 4])  * s[n + 4]  + du * B1[n];
            s[n + 8]  = __expf(dt * a[n + 8])  * s[n + 8]  + du * B2[n];
            s[n + 12] = __expf(dt * a[n + 12]) * s[n + 12] + du * B3[n];
        }
    }
    size_t o = ((size_t)(b * GCH + g) * INTER + i) * D_STATE;
#pragma unroll
    for (int n = 0; n < D_STATE; n += 4) {
        f32x4 v = { s[n], s[n+1], s[n+2], s[n+3] };
        *(f32x4*)&cst[o + n] = v;
    }
    dts[(size_t)(b * GCH + g) * INTER + i] = dsum;
}

// in-place: cst holds local chunk-end states; rewrite to chunk-START states.
// one thread per (b, i, state-quad): 32768 threads.
__global__ __launch_bounds__(256)
void scan2_k(float* __restrict__ cst, const float* __restrict__ dts,
             const float* __restrict__ Alog)
{
    int idx = blockIdx.x * 256 + threadIdx.x;    // 0..B*INTER*4-1
    int sub = idx & 3;
    int i   = (idx >> 2) & (INTER - 1);
    int b   = idx >> 13;
    int n0  = sub * 4;
    float a[4];
#pragma unroll
    for (int n = 0; n < 4; ++n)
        a[n] = -__expf(Alog[(size_t)i * D_STATE + n0 + n]);
    f32x4 s = (f32x4)0.f;
    for (int g = 0; g < GCH; ++g) {
        size_t o = ((size_t)(b * GCH + g) * INTER + i) * D_STATE + n0;
        f32x4 tmp = *(const f32x4*)&cst[o];
        *(f32x4*)&cst[o] = s;                    // start state for chunk g
        float d = dts[(size_t)(b * GCH + g) * INTER + i];
#pragma unroll
        for (int n = 0; n < 4; ++n)
            s[n] = __expf(a[n] * d) * s[n] + tmp[n];
    }
}

__global__ __launch_bounds__(256)
void scan3_k(const u16* __restrict__ dtbf, const u16* __restrict__ ubf,
             const float* __restrict__ ssm, const u16* __restrict__ projbf,
             const float* __restrict__ Alog, const float* __restrict__ Dp,
             const float* __restrict__ sst, u16* __restrict__ ybf)
{
    __shared__ float Bs[TC][D_STATE];
    __shared__ float Cs[TC][D_STATE];
    const int tid = threadIdx.x;
    const int i   = blockIdx.x * 256 + tid;
    const int g   = blockIdx.y;
    const int b   = blockIdx.z;
    const int t0  = g * TC;
    for (int idx = tid * 4; idx < TC * D_STATE; idx += 1024) {
        int t = idx >> 4, n = idx & 15;
        size_t row = (size_t)(b * SEQ + t0 + t) * XROWS;
        *(f32x4*)&Bs[t][n] = *(const f32x4*)&ssm[row + DT_RANK + n];
        *(f32x4*)&Cs[t][n] = *(const f32x4*)&ssm[row + DT_RANK + D_STATE + n];
    }
    __syncthreads();

    float a[D_STATE];
#pragma unroll
    for (int n = 0; n < D_STATE; ++n)
        a[n] = -__expf(Alog[(size_t)i * D_STATE + n]);
    const float Di = Dp[i];

    float s[D_STATE];
    size_t so = ((size_t)(b * GCH + g) * INTER + i) * D_STATE;
#pragma unroll
    for (int n = 0; n < D_STATE; n += 4) {
        f32x4 v = *(const f32x4*)&sst[so + n];
        s[n] = v[0]; s[n+1] = v[1]; s[n+2] = v[2]; s[n+3] = v[3];
    }

    const u16* dtp = dtbf   + (size_t)(b * SEQ + t0) * INTER + i;
    const u16* up  = ubf    + (size_t)(b * SEQ + t0) * INTER + i;
    const u16* gp  = projbf + (size_t)(b * SEQ + t0) * 4096 + INTER + i;
    u16*       yp  = ybf    + (size_t)(b * SEQ + t0) * INTER + i;
#pragma unroll 2
    for (int t = 0; t < TC; ++t) {
        float dt = b2f(dtp[(size_t)t * INTER]);
        float u  = b2f(up[(size_t)t * INTER]);
        float gt = b2f(gp[(size_t)t * 4096]);
        float du = dt * u;
        f32x4 B0 = *(const f32x4*)&Bs[t][0];
        f32x4 B1 = *(const f32x4*)&Bs[t][4];
        f32x4 B2 = *(const f32x4*)&Bs[t][8];
        f32x4 B3 = *(const f32x4*)&Bs[t][12];
        f32x4 C0 = *(const f32x4*)&Cs[t][0];
        f32x4 C1 = *(const f32x4*)&Cs[t][4];
        f32x4 C2 = *(const f32x4*)&Cs[t][8];
        f32x4 C3 = *(const f32x4*)&Cs[t][12];
        float y = 0.f;
#pragma unroll
        for (int n = 0; n < 4; ++n) {
            s[n]      = __expf(dt * a[n])      * s[n]      + du * B0[n];
            s[n + 4]  = __expf(dt * a[n + 4])  * s[n + 4]  + du * B1[n];
            s[n + 8]  = __expf(dt * a[n + 8])  * s[n + 8]  + du * B2[n];
            s[n + 12] = __expf(dt * a[n + 12]) * s[n + 12] + du * B3[n];
            y += s[n] * C0[n] + s[n + 4] * C1[n] + s[n + 8] * C2[n] + s[n + 12] * C3[n];
        }
        yp[(size_t)t * INTER] = f2b((y + Di * u) * silu(gt));
    }
}

// ---------------------------------------------------------------------------
// Weight conversion fp32 -> bf16
// ---------------------------------------------------------------------------
__global__ __launch_bounds__(256)
void cvt_f2b_k(const float* __restrict__ in, u16* __restrict__ out, int n)
{
    int idx = blockIdx.x * 256 + threadIdx.x;
    if (idx < n) out[idx] = f2b(in[idx]);
}

// x_w [4,96,2048] -> padded bf16 [4,128,2048] (rows 96..127 zero)
__global__ __launch_bounds__(256)
void pad_xw_k(const float* __restrict__ xw, u16* __restrict__ out)
{
    int idx = blockIdx.x * 256 + threadIdx.x;      // 4*128*2048
    if (idx >= N_LAYERS * XROWS * INTER) return;
    int l = idx / (XROWS * INTER);
    int r = (idx >> 11) & (XROWS - 1);
    int c = idx & (INTER - 1);
    out[idx] = (r < 96) ? f2b(xw[((size_t)l * 96 + r) * INTER + c]) : (u16)0;
}

// ---------------------------------------------------------------------------
extern "C" void kernel_launch(void* const* d_in, const int* in_sizes, int n_in,
                              void* d_out, int out_size, void* d_ws, size_t ws_size,
                              hipStream_t stream)
{
    const float* x      = (const float*)d_in[0];
    const float* in_w   = (const float*)d_in[1];
    const float* conv_w = (const float*)d_in[2];
    const float* conv_b = (const float*)d_in[3];
    const float* x_w    = (const float*)d_in[4];
    const float* dt_w   = (const float*)d_in[5];
    const float* dt_b   = (const float*)d_in[6];
    const float* A_log  = (const float*)d_in[7];
    const float* Dp     = (const float*)d_in[8];
    const float* out_w  = (const float*)d_in[9];
    const float* norm_w = (const float*)d_in[10];
    const float* norm_f = (const float*)d_in[11];

    char* ws = (char*)d_ws;
    size_t off = 0;
    auto alloc = [&](size_t bytes) { char* p = ws + off; off += (bytes + 255) & ~(size_t)255; return p; };

    u16*   inw_bf  = (u16*)  alloc((size_t)N_LAYERS * 4096 * 1024 * 2);
    u16*   xw_bf   = (u16*)  alloc((size_t)N_LAYERS * XROWS * INTER * 2);
    u16*   dtw_bf  = (u16*)  alloc((size_t)N_LAYERS * INTER * DT_RANK * 2);
    u16*   outw_bf = (u16*)  alloc((size_t)N_LAYERS * D_MODEL * INTER * 2);
    float* h       = (float*)alloc((size_t)TOK * D_MODEL * 4);
    u16*   xn_bf   = (u16*)  alloc((size_t)TOK * D_MODEL * 2);
    u16*   proj_bf = (u16*)  alloc((size_t)TOK * 4096 * 2);
    u16*   u_bf    = (u16*)  alloc((size_t)TOK * INTER * 2);
    float* ssm     = (float*)alloc((size_t)TOK * XROWS * 4);
    u16*   dtr_bf  = (u16*)  alloc((size_t)TOK * DT_RANK * 2);
    u16*   dt_bf   = (u16*)  alloc((size_t)TOK * INTER * 2);
    u16*   y_bf    = (u16*)  alloc((size_t)TOK * INTER * 2);
    float* cst     = (float*)alloc((size_t)B_SZ * GCH * INTER * D_STATE * 4);
    float* dts     = (float*)alloc((size_t)B_SZ * GCH * INTER * 4);
    (void)ws_size; (void)n_in; (void)in_sizes; (void)out_size;

    // weight conversion (every launch; deterministic)
    {
        int n = N_LAYERS * 4096 * 1024;
        cvt_f2b_k<<<n / 256, 256, 0, stream>>>(in_w, inw_bf, n);
        int np = N_LAYERS * XROWS * INTER;
        pad_xw_k<<<np / 256, 256, 0, stream>>>(x_w, xw_bf);
        int nd = N_LAYERS * INTER * DT_RANK;
        cvt_f2b_k<<<nd / 256, 256, 0, stream>>>(dt_w, dtw_bf, nd);
        int no = N_LAYERS * D_MODEL * INTER;
        cvt_f2b_k<<<no / 256, 256, 0, stream>>>(out_w, outw_bf, no);
    }

    hipMemcpyAsync(h, x, (size_t)TOK * D_MODEL * 4, hipMemcpyDeviceToDevice, stream);

    for (int l = 0; l < N_LAYERS; ++l) {
        // 1. rmsnorm -> xn_bf
        rmsnorm_k<1><<<TOK, 256, 0, stream>>>(h, norm_w + (size_t)l * D_MODEL, xn_bf);
        // 2. in_proj: [4096,1024] @ [4096,1024]^T -> proj_bf [4096,4096]
        gemm_bt<1><<<dim3(32, 32), 256, 0, stream>>>(
            xn_bf, inw_bf + (size_t)l * 4096 * 1024, proj_bf, nullptr, nullptr, 1024, 4096);
        // 3. conv + silu -> u_bf
        conv_silu_k<<<TOK, 256, 0, stream>>>(
            proj_bf, conv_w + (size_t)l * INTER * D_CONV, conv_b + (size_t)l * INTER, u_bf);
        // 4. x_proj: [4096,2048] @ [128,2048]^T -> ssm fp32 [4096,128] + dtr bf16
        gemm_bt<4><<<dim3(1, 32), 256, 0, stream>>>(
            u_bf, xw_bf + (size_t)l * XROWS * INTER, ssm, nullptr, dtr_bf, INTER, XROWS);
        // 5. dt_proj + softplus -> dt_bf [4096,2048]
        gemm_bt<2><<<dim3(16, 32), 256, 0, stream>>>(
            dtr_bf, dtw_bf + (size_t)l * INTER * DT_RANK, dt_bf,
            dt_b + (size_t)l * INTER, nullptr, DT_RANK, INTER);
        // 6. chunked scan (+ skip + gate) -> y_bf
        scan1_k<<<dim3(INTER / 256, GCH, B_SZ), 256, 0, stream>>>(
            dt_bf, u_bf, ssm, A_log + (size_t)l * INTER * D_STATE, cst, dts);
        scan2_k<<<(B_SZ * INTER * 4) / 256, 256, 0, stream>>>(
            cst, dts, A_log + (size_t)l * INTER * D_STATE);
        scan3_k<<<dim3(INTER / 256, GCH, B_SZ), 256, 0, stream>>>(
            dt_bf, u_bf, ssm, proj_bf, A_log + (size_t)l * INTER * D_STATE,
            Dp + (size_t)l * INTER, cst, y_bf);
        // 7. out_proj + residual -> h
        gemm_bt<3><<<dim3(8, 32), 256, 0, stream>>>(
            y_bf, outw_bf + (size_t)l * D_MODEL * INTER, h, h, nullptr, INTER, D_MODEL);
    }
    // final rmsnorm -> d_out (fp32)
    rmsnorm_k<0><<<TOK, 256, 0, stream>>>(h, norm_f, d_out);
}

// Round 5
// 1093.775 us; speedup vs baseline: 3.3118x; 1.0792x over previous
//
#include <hip/hip_runtime.h>
#include <hip/hip_bf16.h>
#include <math.h>

#define D_MODEL 1024
#define N_LAYERS 4
#define INTER 2048
#define D_CONV 4
#define D_STATE 16
#define DT_RANK 64
#define B_SZ 4
#define SEQ 1024
#define TOK (B_SZ*SEQ)          // 4096 token rows
#define XROWS 128               // x_proj rows padded 96 -> 128
#define EPSV 1e-5f
#define GCH 32                  // scan chunks
#define TC (SEQ/GCH)            // 32 timesteps per chunk
#define KSPL 4                  // x_proj K-split factor

typedef unsigned short u16;
typedef __attribute__((ext_vector_type(8))) short bf16x8;
typedef __attribute__((ext_vector_type(4))) short s16x4;
typedef __attribute__((ext_vector_type(4))) float f32x4;

__device__ __forceinline__ u16 f2b(float f) {
    union { float f; unsigned u; } v; v.f = f;
    unsigned r = v.u + 0x7fffu + ((v.u >> 16) & 1u);
    return (u16)(r >> 16);
}
__device__ __forceinline__ float b2f(u16 h) {
    union { unsigned u; float f; } v; v.u = ((unsigned)h) << 16;
    return v.f;
}
__device__ __forceinline__ float silu(float x) {
    return x / (1.f + __expf(-x));
}
__device__ __forceinline__ void gload16(const void* g, void* l) {
    __builtin_amdgcn_global_load_lds(
        (const __attribute__((address_space(1))) void*)g,
        (__attribute__((address_space(3))) void*)l, 16, 0, 0);
}

// ---------------------------------------------------------------------------
// GEMM: C[M,N] = A[M,K] @ B[N,K]^T   (A,B bf16 row-major, fp32 MFMA accum)
// 128x128 tile, 4 waves (2x2), 4x4 fragments of 16x16x32 per wave.
// 3-buffer LDS pipeline, counted vmcnt(8) -> 2 tiles in flight across
// barriers (T4). XOR swizzle slot^=(row>>1)&3 applied on global SOURCE and
// on ds_read (LDS dest linear, rule #21) -> 2-way banks (free).
// EPI: 0 = fp32 store, 1 = bf16 store, 2 = softplus(acc+aux[col]) -> bf16,
//      3 = fp32 store of aux[idx] + acc (residual; aux may alias C)
//      4 = split-K partial fp32 store (blockIdx.x = K-part, col0 = 0)
// ---------------------------------------------------------------------------
template<int EPI>
__global__ __launch_bounds__(256)
void gemm_bt(const u16* __restrict__ A, const u16* __restrict__ B,
             void* __restrict__ C, const float* __restrict__ aux,
             int K, int lda, int ldc)
{
    __shared__ u16 As[3][128 * 32];
    __shared__ u16 Bs[3][128 * 32];
    const int tid  = threadIdx.x;
    const int lane = tid & 63;
    const int w    = tid >> 6;
    const int wr   = w >> 1, wc = w & 1;
    const int row0 = blockIdx.y * 128;
    int col0 = blockIdx.x * 128;
    if (EPI == 4) {
        int part = blockIdx.x;
        col0 = 0;
        A += (size_t)part * K;
        B += (size_t)part * K;
        C = (void*)((float*)C + (size_t)part * TOK * XROWS);
    }
    const int r16   = lane & 15;
    const int khalf = lane >> 4;                  // 0..3
    const int kslot = khalf ^ ((r16 >> 1) & 3);   // swizzled read slot

    auto stage = [&](int buf, int k0) {
#pragma unroll
        for (int c = 0; c < 2; ++c) {
            int chunk = tid + c * 256;            // 0..511, 16B each
            int r  = chunk >> 2;                  // 0..127
            int j  = chunk & 3;
            int k8 = (j ^ ((r >> 1) & 3)) * 8;    // pre-swizzled global column
            gload16(&A[(size_t)(row0 + r) * lda + k0 + k8], &As[buf][chunk * 8]);
            gload16(&B[(size_t)(col0 + r) * lda + k0 + k8], &Bs[buf][chunk * 8]);
        }
    };

    f32x4 acc[4][4];
#pragma unroll
    for (int m = 0; m < 4; ++m)
#pragma unroll
        for (int n = 0; n < 4; ++n)
            acc[m][n] = (f32x4)0.f;

    const int nt = K >> 5;
    stage(0, 0);
    if (nt > 1) stage(1, 32);

    int cur = 0, sb = 2;
    for (int t = 0; t < nt; ++t) {
        if (t + 2 < nt) {
            stage(sb, (t + 2) << 5);
            asm volatile("s_waitcnt vmcnt(8)" ::: "memory");  // tile t landed
        } else if (t + 1 < nt) {
            asm volatile("s_waitcnt vmcnt(4)" ::: "memory");
        } else {
            asm volatile("s_waitcnt vmcnt(0)" ::: "memory");
        }
        __builtin_amdgcn_s_barrier();   // all waves' tile-t loads in LDS

        bf16x8 af[4], bfr[4];
#pragma unroll
        for (int m = 0; m < 4; ++m)
            af[m]  = *(const bf16x8*)&As[cur][(wr * 64 + m * 16 + r16) * 32 + kslot * 8];
#pragma unroll
        for (int n = 0; n < 4; ++n)
            bfr[n] = *(const bf16x8*)&Bs[cur][(wc * 64 + n * 16 + r16) * 32 + kslot * 8];
#pragma unroll
        for (int m = 0; m < 4; ++m)
#pragma unroll
            for (int n = 0; n < 4; ++n)
                acc[m][n] = __builtin_amdgcn_mfma_f32_16x16x32_bf16(
                    af[m], bfr[n], acc[m][n], 0, 0, 0);

        __builtin_amdgcn_sched_barrier(0);                    // rule #18: pin
        asm volatile("s_waitcnt lgkmcnt(0)" ::: "memory");    // reads drained
        __builtin_amdgcn_s_barrier();   // buf cur now safe to overwrite
        cur = (cur == 2) ? 0 : cur + 1;
        sb  = (sb  == 2) ? 0 : sb  + 1;
    }

    const int orow = row0 + wr * 64;
    const int ocol = col0 + wc * 64;
#pragma unroll
    for (int m = 0; m < 4; ++m)
#pragma unroll
        for (int n = 0; n < 4; ++n) {
#pragma unroll
            for (int r = 0; r < 4; ++r) {
                int rr = orow + m * 16 + khalf * 4 + r;
                int cc = ocol + n * 16 + r16;
                float v = acc[m][n][r];
                size_t o = (size_t)rr * ldc + cc;
                if (EPI == 0 || EPI == 4) {
                    ((float*)C)[o] = v;
                } else if (EPI == 1) {
                    ((u16*)C)[o] = f2b(v);
                } else if (EPI == 2) {
                    float x = v + aux[cc];
                    float sp = (x > 20.f) ? x : log1pf(__expf(x));
                    ((u16*)C)[o] = f2b(sp);
                } else {
                    ((float*)C)[o] = aux[o] + v;
                }
            }
        }
}

// ---------------------------------------------------------------------------
// x_proj split-K reduce: ssm = sum of KSPL partials; also emits bf16 dt-rank
// columns for the dt_proj A-operand (fuses old cvt_dtr).
// ---------------------------------------------------------------------------
__global__ __launch_bounds__(256)
void xred_k(const float* __restrict__ part, float* __restrict__ ssm,
            u16* __restrict__ dtr)
{
    int idx = blockIdx.x * 256 + threadIdx.x;     // TOK * 32 quads
    int row = idx >> 5;
    int col = (idx & 31) * 4;
    size_t o = (size_t)row * XROWS + col;
    const size_t stride = (size_t)TOK * XROWS;
    f32x4 v = *(const f32x4*)&part[o];
#pragma unroll
    for (int p = 1; p < KSPL; ++p)
        v += *(const f32x4*)&part[o + p * stride];
    *(f32x4*)&ssm[o] = v;
    if (col < DT_RANK) {
        s16x4 d;
#pragma unroll
        for (int j = 0; j < 4; ++j) d[j] = (short)f2b(v[j]);
        *(s16x4*)&dtr[(size_t)row * DT_RANK + col] = d;
    }
}

// ---------------------------------------------------------------------------
// RMSNorm over rows of 1024 fp32. OUTBF=1 -> bf16 out, else fp32 out.
// ---------------------------------------------------------------------------
template<int OUTBF>
__global__ __launch_bounds__(256)
void rmsnorm_k(const float* __restrict__ in, const float* __restrict__ w,
               void* __restrict__ out)
{
    __shared__ float red[4];
    const int row = blockIdx.x;
    const int tid = threadIdx.x;
    const float* r = in + (size_t)row * D_MODEL;
    f32x4 v = *(const f32x4*)&r[tid * 4];
    float ss = v[0]*v[0] + v[1]*v[1] + v[2]*v[2] + v[3]*v[3];
#pragma unroll
    for (int m = 32; m >= 1; m >>= 1) ss += __shfl_xor(ss, m, 64);
    if ((tid & 63) == 0) red[tid >> 6] = ss;
    __syncthreads();
    if (tid == 0) {
        float s = red[0] + red[1] + red[2] + red[3];
        red[0] = rsqrtf(s / (float)D_MODEL + EPSV);
    }
    __syncthreads();
    float sc = red[0];
    if (OUTBF) {
        u16* o = (u16*)out + (size_t)row * D_MODEL + tid * 4;
#pragma unroll
        for (int j = 0; j < 4; ++j) o[j] = f2b(v[j] * sc * w[tid * 4 + j]);
    } else {
        float* o = (float*)out + (size_t)row * D_MODEL + tid * 4;
#pragma unroll
        for (int j = 0; j < 4; ++j) o[j] = v[j] * sc * w[tid * 4 + j];
    }
}

// ---------------------------------------------------------------------------
// Depthwise causal conv (width 4) + bias + SiLU, 8 channels/thread.
// ---------------------------------------------------------------------------
__global__ __launch_bounds__(256)
void conv_silu_k(const u16* __restrict__ projbf, const float* __restrict__ w,
                 const float* __restrict__ bias, u16* __restrict__ ubf)
{
    const int row = blockIdx.x;               // 0..TOK-1
    const int t   = row & (SEQ - 1);
    const int i0  = threadIdx.x * 8;
    float acc[8];
    {
        f32x4 b0 = *(const f32x4*)&bias[i0];
        f32x4 b1 = *(const f32x4*)&bias[i0 + 4];
#pragma unroll
        for (int j = 0; j < 4; ++j) { acc[j] = b0[j]; acc[j + 4] = b1[j]; }
    }
    f32x4 wv[8];
#pragma unroll
    for (int j = 0; j < 8; ++j)
        wv[j] = *(const f32x4*)&w[(i0 + j) * 4];
#pragma unroll
    for (int k = 0; k < 4; ++k) {
        int tt = t - 3 + k;
        if (tt >= 0) {
            bf16x8 hv = *(const bf16x8*)&projbf[(size_t)(row - 3 + k) * 4096 + i0];
#pragma unroll
            for (int j = 0; j < 8; ++j)
                acc[j] += b2f((u16)hv[j]) * wv[j][k];
        }
    }
    bf16x8 o;
#pragma unroll
    for (int j = 0; j < 8; ++j)
        o[j] = (short)f2b(silu(acc[j]));
    *(bf16x8*)&ubf[(size_t)row * INTER + i0] = o;
}

// ---------------------------------------------------------------------------
// Chunked parallel selective scan. One lane per channel, 16 states in regs.
// ---------------------------------------------------------------------------
__global__ __launch_bounds__(256)
void scan1_k(const u16* __restrict__ dtbf, const u16* __restrict__ ubf,
             const float* __restrict__ ssm, const float* __restrict__ Alog,
             float* __restrict__ cst, float* __restrict__ dts)
{
    __shared__ float Bs[TC][D_STATE];
    const int tid = threadIdx.x;
    const int i   = blockIdx.x * 256 + tid;
    const int g   = blockIdx.y;
    const int b   = blockIdx.z;
    const int t0  = g * TC;
    for (int idx = tid * 4; idx < TC * D_STATE; idx += 1024) {
        int t = idx >> 4, n = idx & 15;
        *(f32x4*)&Bs[t][n] =
            *(const f32x4*)&ssm[(size_t)(b * SEQ + t0 + t) * XROWS + DT_RANK + n];
    }
    __syncthreads();

    float a[D_STATE];
#pragma unroll
    for (int n = 0; n < D_STATE; ++n)
        a[n] = -__expf(Alog[(size_t)i * D_STATE + n]);

    float s[D_STATE];
#pragma unroll
    for (int n = 0; n < D_STATE; ++n) s[n] = 0.f;
    float dsum = 0.f;

    const u16* dtp = dtbf + (size_t)(b * SEQ + t0) * INTER + i;
    const u16* up  = ubf  + (size_t)(b * SEQ + t0) * INTER + i;
#pragma unroll 2
    for (int t = 0; t < TC; ++t) {
        float dt = b2f(dtp[(size_t)t * INTER]);
        float u  = b2f(up[(size_t)t * INTER]);
        float du = dt * u;
        dsum += dt;
        f32x4 B0 = *(const f32x4*)&Bs[t][0];
        f32x4 B1 = *(const f32x4*)&Bs[t][4];
        f32x4 B2 = *(const f32x4*)&Bs[t][8];
        f32x4 B3 = *(const f32x4*)&Bs[t][12];
#pragma unroll
        for (int n = 0; n < 4; ++n) {
            s[n]      = __expf(dt * a[n])      * s[n]      + du * B0[n];
            s[n + 4]  = __expf(dt * a[n + 4])  * s[n + 4]  + du * B1[n];
            s[n + 8]  = __expf(dt * a[n + 8])  * s[n + 8]  + du * B2[n];
            s[n + 12] = __expf(dt * a[n + 12]) * s[n + 12] + du * B3[n];
        }
    }
    size_t o = ((size_t)(b * GCH + g) * INTER + i) * D_STATE;
#pragma unroll
    for (int n = 0; n < D_STATE; n += 4) {
        f32x4 v = { s[n], s[n+1], s[n+2], s[n+3] };
        *(f32x4*)&cst[o + n] = v;
    }
    dts[(size_t)(b * GCH + g) * INTER + i] = dsum;
}

// in-place: cst local chunk-end -> chunk-START states. 32768 threads.
__global__ __launch_bounds__(256)
void scan2_k(float* __restrict__ cst, const float* __restrict__ dts,
             const float* __restrict__ Alog)
{
    int idx = blockIdx.x * 256 + threadIdx.x;
    int sub = idx & 3;
    int i   = (idx >> 2) & (INTER - 1);
    int b   = idx >> 13;
    int n0  = sub * 4;
    float a[4];
#pragma unroll
    for (int n = 0; n < 4; ++n)
        a[n] = -__expf(Alog[(size_t)i * D_STATE + n0 + n]);
    f32x4 s = (f32x4)0.f;
    for (int g = 0; g < GCH; ++g) {
        size_t o = ((size_t)(b * GCH + g) * INTER + i) * D_STATE + n0;
        f32x4 tmp = *(const f32x4*)&cst[o];
        *(f32x4*)&cst[o] = s;
        float d = dts[(size_t)(b * GCH + g) * INTER + i];
#pragma unroll
        for (int n = 0; n < 4; ++n)
            s[n] = __expf(a[n] * d) * s[n] + tmp[n];
    }
}

__global__ __launch_bounds__(256)
void scan3_k(const u16* __restrict__ dtbf, const u16* __restrict__ ubf,
             const float* __restrict__ ssm, const u16* __restrict__ projbf,
             const float* __restrict__ Alog, const float* __restrict__ Dp,
             const float* __restrict__ sst, u16* __restrict__ ybf)
{
    __shared__ float Bs[TC][D_STATE];
    __shared__ float Cs[TC][D_STATE];
    const int tid = threadIdx.x;
    const int i   = blockIdx.x * 256 + tid;
    const int g   = blockIdx.y;
    const int b   = blockIdx.z;
    const int t0  = g * TC;
    for (int idx = tid * 4; idx < TC * D_STATE; idx += 1024) {
        int t = idx >> 4, n = idx & 15;
        size_t row = (size_t)(b * SEQ + t0 + t) * XROWS;
        *(f32x4*)&Bs[t][n] = *(const f32x4*)&ssm[row + DT_RANK + n];
        *(f32x4*)&Cs[t][n] = *(const f32x4*)&ssm[row + DT_RANK + D_STATE + n];
    }
    __syncthreads();

    float a[D_STATE];
#pragma unroll
    for (int n = 0; n < D_STATE; ++n)
        a[n] = -__expf(Alog[(size_t)i * D_STATE + n]);
    const float Di = Dp[i];

    float s[D_STATE];
    size_t so = ((size_t)(b * GCH + g) * INTER + i) * D_STATE;
#pragma unroll
    for (int n = 0; n < D_STATE; n += 4) {
        f32x4 v = *(const f32x4*)&sst[so + n];
        s[n] = v[0]; s[n+1] = v[1]; s[n+2] = v[2]; s[n+3] = v[3];
    }

    const u16* dtp = dtbf   + (size_t)(b * SEQ + t0) * INTER + i;
    const u16* up  = ubf    + (size_t)(b * SEQ + t0) * INTER + i;
    const u16* gp  = projbf + (size_t)(b * SEQ + t0) * 4096 + INTER + i;
    u16*       yp  = ybf    + (size_t)(b * SEQ + t0) * INTER + i;
#pragma unroll 2
    for (int t = 0; t < TC; ++t) {
        float dt = b2f(dtp[(size_t)t * INTER]);
        float u  = b2f(up[(size_t)t * INTER]);
        float gt = b2f(gp[(size_t)t * 4096]);
        float du = dt * u;
        f32x4 B0 = *(const f32x4*)&Bs[t][0];
        f32x4 B1 = *(const f32x4*)&Bs[t][4];
        f32x4 B2 = *(const f32x4*)&Bs[t][8];
        f32x4 B3 = *(const f32x4*)&Bs[t][12];
        f32x4 C0 = *(const f32x4*)&Cs[t][0];
        f32x4 C1 = *(const f32x4*)&Cs[t][4];
        f32x4 C2 = *(const f32x4*)&Cs[t][8];
        f32x4 C3 = *(const f32x4*)&Cs[t][12];
        float y = 0.f;
#pragma unroll
        for (int n = 0; n < 4; ++n) {
            s[n]      = __expf(dt * a[n])      * s[n]      + du * B0[n];
            s[n + 4]  = __expf(dt * a[n + 4])  * s[n + 4]  + du * B1[n];
            s[n + 8]  = __expf(dt * a[n + 8])  * s[n + 8]  + du * B2[n];
            s[n + 12] = __expf(dt * a[n + 12]) * s[n + 12] + du * B3[n];
            y += s[n] * C0[n] + s[n + 4] * C1[n] + s[n + 8] * C2[n] + s[n + 12] * C3[n];
        }
        yp[(size_t)t * INTER] = f2b((y + Di * u) * silu(gt));
    }
}

// ---------------------------------------------------------------------------
// Weight conversion fp32 -> bf16
// ---------------------------------------------------------------------------
__global__ __launch_bounds__(256)
void cvt_f2b_k(const float* __restrict__ in, u16* __restrict__ out, int n)
{
    int idx = blockIdx.x * 256 + threadIdx.x;
    if (idx < n) out[idx] = f2b(in[idx]);
}

// x_w [4,96,2048] -> padded bf16 [4,128,2048] (rows 96..127 zero)
__global__ __launch_bounds__(256)
void pad_xw_k(const float* __restrict__ xw, u16* __restrict__ out)
{
    int idx = blockIdx.x * 256 + threadIdx.x;
    if (idx >= N_LAYERS * XROWS * INTER) return;
    int l = idx / (XROWS * INTER);
    int r = (idx >> 11) & (XROWS - 1);
    int c = idx & (INTER - 1);
    out[idx] = (r < 96) ? f2b(xw[((size_t)l * 96 + r) * INTER + c]) : (u16)0;
}

// ---------------------------------------------------------------------------
extern "C" void kernel_launch(void* const* d_in, const int* in_sizes, int n_in,
                              void* d_out, int out_size, void* d_ws, size_t ws_size,
                              hipStream_t stream)
{
    const float* x      = (const float*)d_in[0];
    const float* in_w   = (const float*)d_in[1];
    const float* conv_w = (const float*)d_in[2];
    const float* conv_b = (const float*)d_in[3];
    const float* x_w    = (const float*)d_in[4];
    const float* dt_w   = (const float*)d_in[5];
    const float* dt_b   = (const float*)d_in[6];
    const float* A_log  = (const float*)d_in[7];
    const float* Dp     = (const float*)d_in[8];
    const float* out_w  = (const float*)d_in[9];
    const float* norm_w = (const float*)d_in[10];
    const float* norm_f = (const float*)d_in[11];

    char* ws = (char*)d_ws;
    size_t off = 0;
    auto alloc = [&](size_t bytes) { char* p = ws + off; off += (bytes + 255) & ~(size_t)255; return p; };

    u16*   inw_bf  = (u16*)  alloc((size_t)N_LAYERS * 4096 * 1024 * 2);
    u16*   xw_bf   = (u16*)  alloc((size_t)N_LAYERS * XROWS * INTER * 2);
    u16*   dtw_bf  = (u16*)  alloc((size_t)N_LAYERS * INTER * DT_RANK * 2);
    u16*   outw_bf = (u16*)  alloc((size_t)N_LAYERS * D_MODEL * INTER * 2);
    float* h       = (float*)alloc((size_t)TOK * D_MODEL * 4);
    u16*   xn_bf   = (u16*)  alloc((size_t)TOK * D_MODEL * 2);
    u16*   proj_bf = (u16*)  alloc((size_t)TOK * 4096 * 2);
    u16*   u_bf    = (u16*)  alloc((size_t)TOK * INTER * 2);
    float* ssm     = (float*)alloc((size_t)TOK * XROWS * 4);
    float* ssm_p   = (float*)alloc((size_t)KSPL * TOK * XROWS * 4);
    u16*   dtr_bf  = (u16*)  alloc((size_t)TOK * DT_RANK * 2);
    u16*   dt_bf   = (u16*)  alloc((size_t)TOK * INTER * 2);
    u16*   y_bf    = (u16*)  alloc((size_t)TOK * INTER * 2);
    float* cst     = (float*)alloc((size_t)B_SZ * GCH * INTER * D_STATE * 4);
    float* dts     = (float*)alloc((size_t)B_SZ * GCH * INTER * 4);
    (void)ws_size; (void)n_in; (void)in_sizes; (void)out_size;

    // weight conversion (every launch; deterministic)
    {
        int n = N_LAYERS * 4096 * 1024;
        cvt_f2b_k<<<n / 256, 256, 0, stream>>>(in_w, inw_bf, n);
        int np = N_LAYERS * XROWS * INTER;
        pad_xw_k<<<np / 256, 256, 0, stream>>>(x_w, xw_bf);
        int nd = N_LAYERS * INTER * DT_RANK;
        cvt_f2b_k<<<nd / 256, 256, 0, stream>>>(dt_w, dtw_bf, nd);
        int no = N_LAYERS * D_MODEL * INTER;
        cvt_f2b_k<<<no / 256, 256, 0, stream>>>(out_w, outw_bf, no);
    }

    hipMemcpyAsync(h, x, (size_t)TOK * D_MODEL * 4, hipMemcpyDeviceToDevice, stream);

    for (int l = 0; l < N_LAYERS; ++l) {
        // 1. rmsnorm -> xn_bf
        rmsnorm_k<1><<<TOK, 256, 0, stream>>>(h, norm_w + (size_t)l * D_MODEL, xn_bf);
        // 2. in_proj: [4096,1024] @ [4096,1024]^T -> proj_bf [4096,4096]
        gemm_bt<1><<<dim3(32, 32), 256, 0, stream>>>(
            xn_bf, inw_bf + (size_t)l * 4096 * 1024, proj_bf, nullptr, 1024, 1024, 4096);
        // 3. conv + silu -> u_bf
        conv_silu_k<<<TOK, 256, 0, stream>>>(
            proj_bf, conv_w + (size_t)l * INTER * D_CONV, conv_b + (size_t)l * INTER, u_bf);
        // 4. x_proj split-K: [4096,2048] @ [128,2048]^T -> 4 partials
        gemm_bt<4><<<dim3(KSPL, 32), 256, 0, stream>>>(
            u_bf, xw_bf + (size_t)l * XROWS * INTER, ssm_p, nullptr,
            INTER / KSPL, INTER, XROWS);
        // 4b. reduce partials -> ssm fp32 + dtr bf16
        xred_k<<<(TOK * 32) / 256, 256, 0, stream>>>(ssm_p, ssm, dtr_bf);
        // 5. dt_proj + softplus -> dt_bf [4096,2048]
        gemm_bt<2><<<dim3(16, 32), 256, 0, stream>>>(
            dtr_bf, dtw_bf + (size_t)l * INTER * DT_RANK, dt_bf,
            dt_b + (size_t)l * INTER, DT_RANK, DT_RANK, INTER);
        // 6. chunked scan (+ skip + gate) -> y_bf
        scan1_k<<<dim3(INTER / 256, GCH, B_SZ), 256, 0, stream>>>(
            dt_bf, u_bf, ssm, A_log + (size_t)l * INTER * D_STATE, cst, dts);
        scan2_k<<<(B_SZ * INTER * 4) / 256, 256, 0, stream>>>(
            cst, dts, A_log + (size_t)l * INTER * D_STATE);
        scan3_k<<<dim3(INTER / 256, GCH, B_SZ), 256, 0, stream>>>(
            dt_bf, u_bf, ssm, proj_bf, A_log + (size_t)l * INTER * D_STATE,
            Dp + (size_t)l * INTER, cst, y_bf);
        // 7. out_proj + residual -> h
        gemm_bt<3><<<dim3(8, 32), 256, 0, stream>>>(
            y_bf, outw_bf + (size_t)l * D_MODEL * INTER, h, h, INTER, INTER, D_MODEL);
    }
    // final rmsnorm -> d_out (fp32)
    rmsnorm_k<0><<<TOK, 256, 0, stream>>>(h, norm_f, d_out);
}

// Round 6
// 1051.120 us; speedup vs baseline: 3.4462x; 1.0406x over previous
//
#include <hip/hip_runtime.h>
#include <hip/hip_bf16.h>
#include <math.h>

#define D_MODEL 1024
#define N_LAYERS 4
#define INTER 2048
#define D_CONV 4
#define D_STATE 16
#define DT_RANK 64
#define B_SZ 4
#define SEQ 1024
#define TOK (B_SZ*SEQ)          // 4096 token rows
#define XROWS 128               // x_proj rows padded 96 -> 128
#define EPSV 1e-5f
#define GCH 32                  // scan chunks
#define TC (SEQ/GCH)            // 32 timesteps per chunk
#define KSPL 4                  // x_proj K-split factor

typedef unsigned short u16;
typedef __attribute__((ext_vector_type(8))) short bf16x8;
typedef __attribute__((ext_vector_type(4))) short s16x4;
typedef __attribute__((ext_vector_type(4))) float f32x4;

__device__ __forceinline__ u16 f2b(float f) {
    union { float f; unsigned u; } v; v.f = f;
    unsigned r = v.u + 0x7fffu + ((v.u >> 16) & 1u);
    return (u16)(r >> 16);
}
__device__ __forceinline__ float b2f(u16 h) {
    union { unsigned u; float f; } v; v.u = ((unsigned)h) << 16;
    return v.f;
}
__device__ __forceinline__ float silu(float x) {
    return x / (1.f + __expf(-x));
}
__device__ __forceinline__ void gload16(const void* g, void* l) {
    __builtin_amdgcn_global_load_lds(
        (const __attribute__((address_space(1))) void*)g,
        (__attribute__((address_space(3))) void*)l, 16, 0, 0);
}

// ---------------------------------------------------------------------------
// 256x256 8-phase GEMM (in_proj): C[M,N] = A[M,K] @ B[N,K]^T, bf16 store.
// BK=64, 8 waves (2Mx4N), 512 thr, 128KB LDS double-buffer.
// Per K-tile: 4 quadrant phases, each {ds_read subtile | stage -> barrier ->
// lgkmcnt(0) -> setprio(1) 16 MFMA setprio(0) -> barrier}. All 8 stage-loads
// for tile j+1 issued in phase 0 of tile j; single vmcnt(0) at phase-3 end
// (runway ~3 phases => drain lands pre-satisfied). XOR swizzle slot^=(row&7)
// on global source + ds_read (LDS dest linear, rule #21) -> conflict-free.
// ---------------------------------------------------------------------------
__global__ __launch_bounds__(512, 2)
void gemm256_k(const u16* __restrict__ A, const u16* __restrict__ B,
               u16* __restrict__ C, int K, int ldc)
{
    __shared__ u16 lds[2][2][256 * 64];   // [buf][op 0=A 1=B][row*64 + slot*8]
    const int tid  = threadIdx.x;
    const int lane = tid & 63;
    const int wid  = tid >> 6;            // 0..7
    const int wr   = wid >> 2;            // 0..1  (row half)
    const int wc   = wid & 3;             // 0..3  (col quarter)
    const int row0 = blockIdx.y * 256;
    const int col0 = blockIdx.x * 256;
    const int r16   = lane & 15;
    const int khalf = lane >> 4;          // 0..3

    auto stage = [&](int buf, int k0) {
#pragma unroll
        for (int l = 0; l < 8; ++l) {
            int op = l >> 2;
            int c  = tid + (l & 3) * 512;         // 0..2047 chunk
            int r  = c >> 3;                      // 0..255
            int ds = c & 7;                       // dest slot
            int sc = (ds ^ (r & 7)) * 8;          // pre-swizzled src col
            const u16* src = op ? &B[(size_t)(col0 + r) * K + k0 + sc]
                                : &A[(size_t)(row0 + r) * K + k0 + sc];
            gload16(src, &lds[buf][op][c * 8]);
        }
    };
    auto rdA = [&](int buf, int mrow, int ks) -> bf16x8 {
        int row  = wr * 128 + mrow + r16;
        int phys = ((ks << 2) | khalf) ^ (row & 7);
        return *(const bf16x8*)&lds[buf][0][row * 64 + phys * 8];
    };
    auto rdB = [&](int buf, int nrow, int ks) -> bf16x8 {
        int row  = wc * 64 + nrow + r16;
        int phys = ((ks << 2) | khalf) ^ (row & 7);
        return *(const bf16x8*)&lds[buf][1][row * 64 + phys * 8];
    };

    f32x4 acc[8][4];
#pragma unroll
    for (int m = 0; m < 8; ++m)
#pragma unroll
        for (int n = 0; n < 4; ++n)
            acc[m][n] = (f32x4)0.f;

    bf16x8 af[4][2], bf2[2][2];

#define PHASE_MFMA(MH, NH, VMDRAIN) do {                                      \
    asm volatile("s_waitcnt lgkmcnt(0)" ::: "memory");                        \
    __builtin_amdgcn_sched_barrier(0);                                        \
    __builtin_amdgcn_s_setprio(1);                                            \
    _Pragma("unroll")                                                         \
    for (int ks = 0; ks < 2; ++ks)                                            \
        _Pragma("unroll")                                                     \
        for (int m = 0; m < 4; ++m)                                           \
            _Pragma("unroll")                                                 \
            for (int n = 0; n < 2; ++n)                                       \
                acc[(MH)*4+m][(NH)*2+n] =                                     \
                    __builtin_amdgcn_mfma_f32_16x16x32_bf16(                  \
                        af[m][ks], bf2[n][ks], acc[(MH)*4+m][(NH)*2+n],0,0,0);\
    __builtin_amdgcn_s_setprio(0);                                            \
    if (VMDRAIN) { asm volatile("s_waitcnt vmcnt(0)" ::: "memory"); }         \
    __builtin_amdgcn_s_barrier();                                             \
} while (0)

    const int nt = K >> 6;
    stage(0, 0);
    asm volatile("s_waitcnt vmcnt(0)" ::: "memory");
    __builtin_amdgcn_s_barrier();

    for (int j = 0; j < nt; ++j) {
        const int buf = j & 1;
        // phase 0: quadrant (0,0); stage whole next K-tile
        if (j + 1 < nt) stage(buf ^ 1, (j + 1) << 6);
#pragma unroll
        for (int m = 0; m < 4; ++m) {
            af[m][0] = rdA(buf, m * 16, 0); af[m][1] = rdA(buf, m * 16, 1);
        }
#pragma unroll
        for (int n = 0; n < 2; ++n) {
            bf2[n][0] = rdB(buf, n * 16, 0); bf2[n][1] = rdB(buf, n * 16, 1);
        }
        __builtin_amdgcn_s_barrier();
        PHASE_MFMA(0, 0, 0);
        // phase 1: quadrant (0,1)
#pragma unroll
        for (int n = 0; n < 2; ++n) {
            bf2[n][0] = rdB(buf, 32 + n * 16, 0); bf2[n][1] = rdB(buf, 32 + n * 16, 1);
        }
        __builtin_amdgcn_s_barrier();
        PHASE_MFMA(0, 1, 0);
        // phase 2: quadrant (1,1)
#pragma unroll
        for (int m = 0; m < 4; ++m) {
            af[m][0] = rdA(buf, 64 + m * 16, 0); af[m][1] = rdA(buf, 64 + m * 16, 1);
        }
        __builtin_amdgcn_s_barrier();
        PHASE_MFMA(1, 1, 0);
        // phase 3: quadrant (1,0); drain stage loads before next-tile reads
#pragma unroll
        for (int n = 0; n < 2; ++n) {
            bf2[n][0] = rdB(buf, n * 16, 0); bf2[n][1] = rdB(buf, n * 16, 1);
        }
        __builtin_amdgcn_s_barrier();
        PHASE_MFMA(1, 0, 1);
    }
#undef PHASE_MFMA

    const int orow = row0 + wr * 128;
    const int ocol = col0 + wc * 64;
#pragma unroll
    for (int am = 0; am < 8; ++am)
#pragma unroll
        for (int an = 0; an < 4; ++an)
#pragma unroll
            for (int r = 0; r < 4; ++r) {
                int rr = orow + am * 16 + khalf * 4 + r;
                int cc = ocol + an * 16 + r16;
                C[(size_t)rr * ldc + cc] = f2b(acc[am][an][r]);
            }
}

// ---------------------------------------------------------------------------
// 128x128 GEMM (x_proj/dt_proj/out_proj): 3-buffer pipeline, swizzled.
// EPI: 0 = fp32, 2 = softplus(acc+aux[col])->bf16, 3 = residual fp32,
//      4 = split-K partial fp32 (blockIdx.x = K-part)
// ---------------------------------------------------------------------------
template<int EPI>
__global__ __launch_bounds__(256)
void gemm_bt(const u16* __restrict__ A, const u16* __restrict__ B,
             void* __restrict__ C, const float* __restrict__ aux,
             int K, int lda, int ldc)
{
    __shared__ u16 As[3][128 * 32];
    __shared__ u16 Bs[3][128 * 32];
    const int tid  = threadIdx.x;
    const int lane = tid & 63;
    const int w    = tid >> 6;
    const int wr   = w >> 1, wc = w & 1;
    const int row0 = blockIdx.y * 128;
    int col0 = blockIdx.x * 128;
    if (EPI == 4) {
        int part = blockIdx.x;
        col0 = 0;
        A += (size_t)part * K;
        B += (size_t)part * K;
        C = (void*)((float*)C + (size_t)part * TOK * XROWS);
    }
    const int r16   = lane & 15;
    const int khalf = lane >> 4;
    const int kslot = khalf ^ ((r16 >> 1) & 3);

    auto stage = [&](int buf, int k0) {
#pragma unroll
        for (int c = 0; c < 2; ++c) {
            int chunk = tid + c * 256;
            int r  = chunk >> 2;
            int j  = chunk & 3;
            int k8 = (j ^ ((r >> 1) & 3)) * 8;
            gload16(&A[(size_t)(row0 + r) * lda + k0 + k8], &As[buf][chunk * 8]);
            gload16(&B[(size_t)(col0 + r) * lda + k0 + k8], &Bs[buf][chunk * 8]);
        }
    };

    f32x4 acc[4][4];
#pragma unroll
    for (int m = 0; m < 4; ++m)
#pragma unroll
        for (int n = 0; n < 4; ++n)
            acc[m][n] = (f32x4)0.f;

    const int nt = K >> 5;
    stage(0, 0);
    if (nt > 1) stage(1, 32);

    int cur = 0, sb = 2;
    for (int t = 0; t < nt; ++t) {
        if (t + 2 < nt) {
            stage(sb, (t + 2) << 5);
            asm volatile("s_waitcnt vmcnt(8)" ::: "memory");
        } else if (t + 1 < nt) {
            asm volatile("s_waitcnt vmcnt(4)" ::: "memory");
        } else {
            asm volatile("s_waitcnt vmcnt(0)" ::: "memory");
        }
        __builtin_amdgcn_s_barrier();

        bf16x8 af[4], bfr[4];
#pragma unroll
        for (int m = 0; m < 4; ++m)
            af[m]  = *(const bf16x8*)&As[cur][(wr * 64 + m * 16 + r16) * 32 + kslot * 8];
#pragma unroll
        for (int n = 0; n < 4; ++n)
            bfr[n] = *(const bf16x8*)&Bs[cur][(wc * 64 + n * 16 + r16) * 32 + kslot * 8];
#pragma unroll
        for (int m = 0; m < 4; ++m)
#pragma unroll
            for (int n = 0; n < 4; ++n)
                acc[m][n] = __builtin_amdgcn_mfma_f32_16x16x32_bf16(
                    af[m], bfr[n], acc[m][n], 0, 0, 0);

        __builtin_amdgcn_sched_barrier(0);
        asm volatile("s_waitcnt lgkmcnt(0)" ::: "memory");
        __builtin_amdgcn_s_barrier();
        cur = (cur == 2) ? 0 : cur + 1;
        sb  = (sb  == 2) ? 0 : sb  + 1;
    }

    const int orow = row0 + wr * 64;
    const int ocol = col0 + wc * 64;
#pragma unroll
    for (int m = 0; m < 4; ++m)
#pragma unroll
        for (int n = 0; n < 4; ++n) {
#pragma unroll
            for (int r = 0; r < 4; ++r) {
                int rr = orow + m * 16 + khalf * 4 + r;
                int cc = ocol + n * 16 + r16;
                float v = acc[m][n][r];
                size_t o = (size_t)rr * ldc + cc;
                if (EPI == 0 || EPI == 4) {
                    ((float*)C)[o] = v;
                } else if (EPI == 2) {
                    float x = v + aux[cc];
                    float sp = (x > 20.f) ? x : log1pf(__expf(x));
                    ((u16*)C)[o] = f2b(sp);
                } else {
                    ((float*)C)[o] = aux[o] + v;
                }
            }
        }
}

// ---------------------------------------------------------------------------
// x_proj split-K reduce: ssm = sum of KSPL partials + bf16 dt-rank cols.
// ---------------------------------------------------------------------------
__global__ __launch_bounds__(256)
void xred_k(const float* __restrict__ part, float* __restrict__ ssm,
            u16* __restrict__ dtr)
{
    int idx = blockIdx.x * 256 + threadIdx.x;
    int row = idx >> 5;
    int col = (idx & 31) * 4;
    size_t o = (size_t)row * XROWS + col;
    const size_t stride = (size_t)TOK * XROWS;
    f32x4 v = *(const f32x4*)&part[o];
#pragma unroll
    for (int p = 1; p < KSPL; ++p)
        v += *(const f32x4*)&part[o + p * stride];
    *(f32x4*)&ssm[o] = v;
    if (col < DT_RANK) {
        s16x4 d;
#pragma unroll
        for (int j = 0; j < 4; ++j) d[j] = (short)f2b(v[j]);
        *(s16x4*)&dtr[(size_t)row * DT_RANK + col] = d;
    }
}

// ---------------------------------------------------------------------------
// RMSNorm over rows of 1024 fp32. OUTBF=1 -> bf16 out, else fp32 out.
// ---------------------------------------------------------------------------
template<int OUTBF>
__global__ __launch_bounds__(256)
void rmsnorm_k(const float* __restrict__ in, const float* __restrict__ w,
               void* __restrict__ out)
{
    __shared__ float red[4];
    const int row = blockIdx.x;
    const int tid = threadIdx.x;
    const float* r = in + (size_t)row * D_MODEL;
    f32x4 v = *(const f32x4*)&r[tid * 4];
    float ss = v[0]*v[0] + v[1]*v[1] + v[2]*v[2] + v[3]*v[3];
#pragma unroll
    for (int m = 32; m >= 1; m >>= 1) ss += __shfl_xor(ss, m, 64);
    if ((tid & 63) == 0) red[tid >> 6] = ss;
    __syncthreads();
    if (tid == 0) {
        float s = red[0] + red[1] + red[2] + red[3];
        red[0] = rsqrtf(s / (float)D_MODEL + EPSV);
    }
    __syncthreads();
    float sc = red[0];
    if (OUTBF) {
        u16* o = (u16*)out + (size_t)row * D_MODEL + tid * 4;
#pragma unroll
        for (int j = 0; j < 4; ++j) o[j] = f2b(v[j] * sc * w[tid * 4 + j]);
    } else {
        float* o = (float*)out + (size_t)row * D_MODEL + tid * 4;
#pragma unroll
        for (int j = 0; j < 4; ++j) o[j] = v[j] * sc * w[tid * 4 + j];
    }
}

// ---------------------------------------------------------------------------
// Depthwise causal conv (width 4) + bias + SiLU, 8 channels/thread.
// ---------------------------------------------------------------------------
__global__ __launch_bounds__(256)
void conv_silu_k(const u16* __restrict__ projbf, const float* __restrict__ w,
                 const float* __restrict__ bias, u16* __restrict__ ubf)
{
    const int row = blockIdx.x;
    const int t   = row & (SEQ - 1);
    const int i0  = threadIdx.x * 8;
    float acc[8];
    {
        f32x4 b0 = *(const f32x4*)&bias[i0];
        f32x4 b1 = *(const f32x4*)&bias[i0 + 4];
#pragma unroll
        for (int j = 0; j < 4; ++j) { acc[j] = b0[j]; acc[j + 4] = b1[j]; }
    }
    f32x4 wv[8];
#pragma unroll
    for (int j = 0; j < 8; ++j)
        wv[j] = *(const f32x4*)&w[(i0 + j) * 4];
#pragma unroll
    for (int k = 0; k < 4; ++k) {
        int tt = t - 3 + k;
        if (tt >= 0) {
            bf16x8 hv = *(const bf16x8*)&projbf[(size_t)(row - 3 + k) * 4096 + i0];
#pragma unroll
            for (int j = 0; j < 8; ++j)
                acc[j] += b2f((u16)hv[j]) * wv[j][k];
        }
    }
    bf16x8 o;
#pragma unroll
    for (int j = 0; j < 8; ++j)
        o[j] = (short)f2b(silu(acc[j]));
    *(bf16x8*)&ubf[(size_t)row * INTER + i0] = o;
}

// ---------------------------------------------------------------------------
// Chunked parallel selective scan.
// ---------------------------------------------------------------------------
__global__ __launch_bounds__(256)
void scan1_k(const u16* __restrict__ dtbf, const u16* __restrict__ ubf,
             const float* __restrict__ ssm, const float* __restrict__ Alog,
             float* __restrict__ cst, float* __restrict__ dts)
{
    __shared__ float Bs[TC][D_STATE];
    const int tid = threadIdx.x;
    const int i   = blockIdx.x * 256 + tid;
    const int g   = blockIdx.y;
    const int b   = blockIdx.z;
    const int t0  = g * TC;
    for (int idx = tid * 4; idx < TC * D_STATE; idx += 1024) {
        int t = idx >> 4, n = idx & 15;
        *(f32x4*)&Bs[t][n] =
            *(const f32x4*)&ssm[(size_t)(b * SEQ + t0 + t) * XROWS + DT_RANK + n];
    }
    __syncthreads();

    float a[D_STATE];
#pragma unroll
    for (int n = 0; n < D_STATE; ++n)
        a[n] = -__expf(Alog[(size_t)i * D_STATE + n]);

    float s[D_STATE];
#pragma unroll
    for (int n = 0; n < D_STATE; ++n) s[n] = 0.f;
    float dsum = 0.f;

    const u16* dtp = dtbf + (size_t)(b * SEQ + t0) * INTER + i;
    const u16* up  = ubf  + (size_t)(b * SEQ + t0) * INTER + i;
#pragma unroll 2
    for (int t = 0; t < TC; ++t) {
        float dt = b2f(dtp[(size_t)t * INTER]);
        float u  = b2f(up[(size_t)t * INTER]);
        float du = dt * u;
        dsum += dt;
        f32x4 B0 = *(const f32x4*)&Bs[t][0];
        f32x4 B1 = *(const f32x4*)&Bs[t][4];
        f32x4 B2 = *(const f32x4*)&Bs[t][8];
        f32x4 B3 = *(const f32x4*)&Bs[t][12];
#pragma unroll
        for (int n = 0; n < 4; ++n) {
            s[n]      = __expf(dt * a[n])      * s[n]      + du * B0[n];
            s[n + 4]  = __expf(dt * a[n + 4])  * s[n + 4]  + du * B1[n];
            s[n + 8]  = __expf(dt * a[n + 8])  * s[n + 8]  + du * B2[n];
            s[n + 12] = __expf(dt * a[n + 12]) * s[n + 12] + du * B3[n];
        }
    }
    size_t o = ((size_t)(b * GCH + g) * INTER + i) * D_STATE;
#pragma unroll
    for (int n = 0; n < D_STATE; n += 4) {
        f32x4 v = { s[n], s[n+1], s[n+2], s[n+3] };
        *(f32x4*)&cst[o + n] = v;
    }
    dts[(size_t)(b * GCH + g) * INTER + i] = dsum;
}

__global__ __launch_bounds__(256)
void scan2_k(float* __restrict__ cst, const float* __restrict__ dts,
             const float* __restrict__ Alog)
{
    int idx = blockIdx.x * 256 + threadIdx.x;
    int sub = idx & 3;
    int i   = (idx >> 2) & (INTER - 1);
    int b   = idx >> 13;
    int n0  = sub * 4;
    float a[4];
#pragma unroll
    for (int n = 0; n < 4; ++n)
        a[n] = -__expf(Alog[(size_t)i * D_STATE + n0 + n]);
    f32x4 s = (f32x4)0.f;
    for (int g = 0; g < GCH; ++g) {
        size_t o = ((size_t)(b * GCH + g) * INTER + i) * D_STATE + n0;
        f32x4 tmp = *(const f32x4*)&cst[o];
        *(f32x4*)&cst[o] = s;
        float d = dts[(size_t)(b * GCH + g) * INTER + i];
#pragma unroll
        for (int n = 0; n < 4; ++n)
            s[n] = __expf(a[n] * d) * s[n] + tmp[n];
    }
}

__global__ __launch_bounds__(256)
void scan3_k(const u16* __restrict__ dtbf, const u16* __restrict__ ubf,
             const float* __restrict__ ssm, const u16* __restrict__ projbf,
             const float* __restrict__ Alog, const float* __restrict__ Dp,
             const float* __restrict__ sst, u16* __restrict__ ybf)
{
    __shared__ float Bs[TC][D_STATE];
    __shared__ float Cs[TC][D_STATE];
    const int tid = threadIdx.x;
    const int i   = blockIdx.x * 256 + tid;
    const int g   = blockIdx.y;
    const int b   = blockIdx.z;
    const int t0  = g * TC;
    for (int idx = tid * 4; idx < TC * D_STATE; idx += 1024) {
        int t = idx >> 4, n = idx & 15;
        size_t row = (size_t)(b * SEQ + t0 + t) * XROWS;
        *(f32x4*)&Bs[t][n] = *(const f32x4*)&ssm[row + DT_RANK + n];
        *(f32x4*)&Cs[t][n] = *(const f32x4*)&ssm[row + DT_RANK + D_STATE + n];
    }
    __syncthreads();

    float a[D_STATE];
#pragma unroll
    for (int n = 0; n < D_STATE; ++n)
        a[n] = -__expf(Alog[(size_t)i * D_STATE + n]);
    const float Di = Dp[i];

    float s[D_STATE];
    size_t so = ((size_t)(b * GCH + g) * INTER + i) * D_STATE;
#pragma unroll
    for (int n = 0; n < D_STATE; n += 4) {
        f32x4 v = *(const f32x4*)&sst[so + n];
        s[n] = v[0]; s[n+1] = v[1]; s[n+2] = v[2]; s[n+3] = v[3];
    }

    const u16* dtp = dtbf   + (size_t)(b * SEQ + t0) * INTER + i;
    const u16* up  = ubf    + (size_t)(b * SEQ + t0) * INTER + i;
    const u16* gp  = projbf + (size_t)(b * SEQ + t0) * 4096 + INTER + i;
    u16*       yp  = ybf    + (size_t)(b * SEQ + t0) * INTER + i;
#pragma unroll 2
    for (int t = 0; t < TC; ++t) {
        float dt = b2f(dtp[(size_t)t * INTER]);
        float u  = b2f(up[(size_t)t * INTER]);
        float gt = b2f(gp[(size_t)t * 4096]);
        float du = dt * u;
        f32x4 B0 = *(const f32x4*)&Bs[t][0];
        f32x4 B1 = *(const f32x4*)&Bs[t][4];
        f32x4 B2 = *(const f32x4*)&Bs[t][8];
        f32x4 B3 = *(const f32x4*)&Bs[t][12];
        f32x4 C0 = *(const f32x4*)&Cs[t][0];
        f32x4 C1 = *(const f32x4*)&Cs[t][4];
        f32x4 C2 = *(const f32x4*)&Cs[t][8];
        f32x4 C3 = *(const f32x4*)&Cs[t][12];
        float y = 0.f;
#pragma unroll
        for (int n = 0; n < 4; ++n) {
            s[n]      = __expf(dt * a[n])      * s[n]      + du * B0[n];
            s[n + 4]  = __expf(dt * a[n + 4])  * s[n + 4]  + du * B1[n];
            s[n + 8]  = __expf(dt * a[n + 8])  * s[n + 8]  + du * B2[n];
            s[n + 12] = __expf(dt * a[n + 12]) * s[n + 12] + du * B3[n];
            y += s[n] * C0[n] + s[n + 4] * C1[n] + s[n + 8] * C2[n] + s[n + 12] * C3[n];
        }
        yp[(size_t)t * INTER] = f2b((y + Di * u) * silu(gt));
    }
}

// ---------------------------------------------------------------------------
__global__ __launch_bounds__(256)
void cvt_f2b_k(const float* __restrict__ in, u16* __restrict__ out, int n)
{
    int idx = blockIdx.x * 256 + threadIdx.x;
    if (idx < n) out[idx] = f2b(in[idx]);
}

__global__ __launch_bounds__(256)
void pad_xw_k(const float* __restrict__ xw, u16* __restrict__ out)
{
    int idx = blockIdx.x * 256 + threadIdx.x;
    if (idx >= N_LAYERS * XROWS * INTER) return;
    int l = idx / (XROWS * INTER);
    int r = (idx >> 11) & (XROWS - 1);
    int c = idx & (INTER - 1);
    out[idx] = (r < 96) ? f2b(xw[((size_t)l * 96 + r) * INTER + c]) : (u16)0;
}

// ---------------------------------------------------------------------------
extern "C" void kernel_launch(void* const* d_in, const int* in_sizes, int n_in,
                              void* d_out, int out_size, void* d_ws, size_t ws_size,
                              hipStream_t stream)
{
    const float* x      = (const float*)d_in[0];
    const float* in_w   = (const float*)d_in[1];
    const float* conv_w = (const float*)d_in[2];
    const float* conv_b = (const float*)d_in[3];
    const float* x_w    = (const float*)d_in[4];
    const float* dt_w   = (const float*)d_in[5];
    const float* dt_b   = (const float*)d_in[6];
    const float* A_log  = (const float*)d_in[7];
    const float* Dp     = (const float*)d_in[8];
    const float* out_w  = (const float*)d_in[9];
    const float* norm_w = (const float*)d_in[10];
    const float* norm_f = (const float*)d_in[11];

    char* ws = (char*)d_ws;
    size_t off = 0;
    auto alloc = [&](size_t bytes) { char* p = ws + off; off += (bytes + 255) & ~(size_t)255; return p; };

    u16*   inw_bf  = (u16*)  alloc((size_t)N_LAYERS * 4096 * 1024 * 2);
    u16*   xw_bf   = (u16*)  alloc((size_t)N_LAYERS * XROWS * INTER * 2);
    u16*   dtw_bf  = (u16*)  alloc((size_t)N_LAYERS * INTER * DT_RANK * 2);
    u16*   outw_bf = (u16*)  alloc((size_t)N_LAYERS * D_MODEL * INTER * 2);
    float* h       = (float*)alloc((size_t)TOK * D_MODEL * 4);
    u16*   xn_bf   = (u16*)  alloc((size_t)TOK * D_MODEL * 2);
    u16*   proj_bf = (u16*)  alloc((size_t)TOK * 4096 * 2);
    u16*   u_bf    = (u16*)  alloc((size_t)TOK * INTER * 2);
    float* ssm     = (float*)alloc((size_t)TOK * XROWS * 4);
    float* ssm_p   = (float*)alloc((size_t)KSPL * TOK * XROWS * 4);
    u16*   dtr_bf  = (u16*)  alloc((size_t)TOK * DT_RANK * 2);
    u16*   dt_bf   = (u16*)  alloc((size_t)TOK * INTER * 2);
    u16*   y_bf    = (u16*)  alloc((size_t)TOK * INTER * 2);
    float* cst     = (float*)alloc((size_t)B_SZ * GCH * INTER * D_STATE * 4);
    float* dts     = (float*)alloc((size_t)B_SZ * GCH * INTER * 4);
    (void)ws_size; (void)n_in; (void)in_sizes; (void)out_size;

    // weight conversion (every launch; deterministic)
    {
        int n = N_LAYERS * 4096 * 1024;
        cvt_f2b_k<<<n / 256, 256, 0, stream>>>(in_w, inw_bf, n);
        int np = N_LAYERS * XROWS * INTER;
        pad_xw_k<<<np / 256, 256, 0, stream>>>(x_w, xw_bf);
        int nd = N_LAYERS * INTER * DT_RANK;
        cvt_f2b_k<<<nd / 256, 256, 0, stream>>>(dt_w, dtw_bf, nd);
        int no = N_LAYERS * D_MODEL * INTER;
        cvt_f2b_k<<<no / 256, 256, 0, stream>>>(out_w, outw_bf, no);
    }

    hipMemcpyAsync(h, x, (size_t)TOK * D_MODEL * 4, hipMemcpyDeviceToDevice, stream);

    for (int l = 0; l < N_LAYERS; ++l) {
        // 1. rmsnorm -> xn_bf
        rmsnorm_k<1><<<TOK, 256, 0, stream>>>(h, norm_w + (size_t)l * D_MODEL, xn_bf);
        // 2. in_proj (256^2 8-phase): [4096,1024] @ [4096,1024]^T -> proj_bf
        gemm256_k<<<dim3(16, 16), 512, 0, stream>>>(
            xn_bf, inw_bf + (size_t)l * 4096 * 1024, proj_bf, 1024, 4096);
        // 3. conv + silu -> u_bf
        conv_silu_k<<<TOK, 256, 0, stream>>>(
            proj_bf, conv_w + (size_t)l * INTER * D_CONV, conv_b + (size_t)l * INTER, u_bf);
        // 4. x_proj split-K: [4096,2048] @ [128,2048]^T -> 4 partials
        gemm_bt<4><<<dim3(KSPL, 32), 256, 0, stream>>>(
            u_bf, xw_bf + (size_t)l * XROWS * INTER, ssm_p, nullptr,
            INTER / KSPL, INTER, XROWS);
        // 4b. reduce partials -> ssm fp32 + dtr bf16
        xred_k<<<(TOK * 32) / 256, 256, 0, stream>>>(ssm_p, ssm, dtr_bf);
        // 5. dt_proj + softplus -> dt_bf [4096,2048]
        gemm_bt<2><<<dim3(16, 32), 256, 0, stream>>>(
            dtr_bf, dtw_bf + (size_t)l * INTER * DT_RANK, dt_bf,
            dt_b + (size_t)l * INTER, DT_RANK, DT_RANK, INTER);
        // 6. chunked scan (+ skip + gate) -> y_bf
        scan1_k<<<dim3(INTER / 256, GCH, B_SZ), 256, 0, stream>>>(
            dt_bf, u_bf, ssm, A_log + (size_t)l * INTER * D_STATE, cst, dts);
        scan2_k<<<(B_SZ * INTER * 4) / 256, 256, 0, stream>>>(
            cst, dts, A_log + (size_t)l * INTER * D_STATE);
        scan3_k<<<dim3(INTER / 256, GCH, B_SZ), 256, 0, stream>>>(
            dt_bf, u_bf, ssm, proj_bf, A_log + (size_t)l * INTER * D_STATE,
            Dp + (size_t)l * INTER, cst, y_bf);
        // 7. out_proj + residual -> h
        gemm_bt<3><<<dim3(8, 32), 256, 0, stream>>>(
            y_bf, outw_bf + (size_t)l * D_MODEL * INTER, h, h, INTER, INTER, D_MODEL);
    }
    // final rmsnorm -> d_out (fp32)
    rmsnorm_k<0><<<TOK, 256, 0, stream>>>(h, norm_f, d_out);
}

// Round 7
// 970.050 us; speedup vs baseline: 3.7342x; 1.0836x over previous
//
#include <hip/hip_runtime.h>
#include <hip/hip_bf16.h>
#include <math.h>

#define D_MODEL 1024
#define N_LAYERS 4
#define INTER 2048
#define D_CONV 4
#define D_STATE 16
#define DT_RANK 64
#define B_SZ 4
#define SEQ 1024
#define TOK (B_SZ*SEQ)          // 4096 token rows
#define XROWS 128               // x_proj rows padded 96 -> 128
#define EPSV 1e-5f
#define GCH 64                  // scan chunks (2048 blocks -> 8/CU)
#define TC (SEQ/GCH)            // 16 timesteps per chunk
#define KSPL 4                  // x_proj K-split factor

typedef unsigned short u16;
typedef __attribute__((ext_vector_type(8))) short bf16x8;
typedef __attribute__((ext_vector_type(4))) short s16x4;
typedef __attribute__((ext_vector_type(4))) float f32x4;

__device__ __forceinline__ u16 f2b(float f) {
    union { float f; unsigned u; } v; v.f = f;
    unsigned r = v.u + 0x7fffu + ((v.u >> 16) & 1u);
    return (u16)(r >> 16);
}
__device__ __forceinline__ float b2f(u16 h) {
    union { unsigned u; float f; } v; v.u = ((unsigned)h) << 16;
    return v.f;
}
__device__ __forceinline__ float silu(float x) {
    return x / (1.f + __expf(-x));
}
__device__ __forceinline__ void gload16(const void* g, void* l) {
    __builtin_amdgcn_global_load_lds(
        (const __attribute__((address_space(1))) void*)g,
        (__attribute__((address_space(3))) void*)l, 16, 0, 0);
}

// ---------------------------------------------------------------------------
// 256x256 8-phase GEMM (in_proj). See R5 notes: T2+T3+T4+T5 schedule.
// ---------------------------------------------------------------------------
__global__ __launch_bounds__(512, 2)
void gemm256_k(const u16* __restrict__ A, const u16* __restrict__ B,
               u16* __restrict__ C, int K, int ldc)
{
    __shared__ u16 lds[2][2][256 * 64];
    const int tid  = threadIdx.x;
    const int lane = tid & 63;
    const int wid  = tid >> 6;
    const int wr   = wid >> 2;
    const int wc   = wid & 3;
    const int row0 = blockIdx.y * 256;
    const int col0 = blockIdx.x * 256;
    const int r16   = lane & 15;
    const int khalf = lane >> 4;

    auto stage = [&](int buf, int k0) {
#pragma unroll
        for (int l = 0; l < 8; ++l) {
            int op = l >> 2;
            int c  = tid + (l & 3) * 512;
            int r  = c >> 3;
            int ds = c & 7;
            int sc = (ds ^ (r & 7)) * 8;
            const u16* src = op ? &B[(size_t)(col0 + r) * K + k0 + sc]
                                : &A[(size_t)(row0 + r) * K + k0 + sc];
            gload16(src, &lds[buf][op][c * 8]);
        }
    };
    auto rdA = [&](int buf, int mrow, int ks) -> bf16x8 {
        int row  = wr * 128 + mrow + r16;
        int phys = ((ks << 2) | khalf) ^ (row & 7);
        return *(const bf16x8*)&lds[buf][0][row * 64 + phys * 8];
    };
    auto rdB = [&](int buf, int nrow, int ks) -> bf16x8 {
        int row  = wc * 64 + nrow + r16;
        int phys = ((ks << 2) | khalf) ^ (row & 7);
        return *(const bf16x8*)&lds[buf][1][row * 64 + phys * 8];
    };

    f32x4 acc[8][4];
#pragma unroll
    for (int m = 0; m < 8; ++m)
#pragma unroll
        for (int n = 0; n < 4; ++n)
            acc[m][n] = (f32x4)0.f;

    bf16x8 af[4][2], bf2[2][2];

#define PHASE_MFMA(MH, NH, VMDRAIN) do {                                      \
    asm volatile("s_waitcnt lgkmcnt(0)" ::: "memory");                        \
    __builtin_amdgcn_sched_barrier(0);                                        \
    __builtin_amdgcn_s_setprio(1);                                            \
    _Pragma("unroll")                                                         \
    for (int ks = 0; ks < 2; ++ks)                                            \
        _Pragma("unroll")                                                     \
        for (int m = 0; m < 4; ++m)                                           \
            _Pragma("unroll")                                                 \
            for (int n = 0; n < 2; ++n)                                       \
                acc[(MH)*4+m][(NH)*2+n] =                                     \
                    __builtin_amdgcn_mfma_f32_16x16x32_bf16(                  \
                        af[m][ks], bf2[n][ks], acc[(MH)*4+m][(NH)*2+n],0,0,0);\
    __builtin_amdgcn_s_setprio(0);                                            \
    if (VMDRAIN) { asm volatile("s_waitcnt vmcnt(0)" ::: "memory"); }         \
    __builtin_amdgcn_s_barrier();                                             \
} while (0)

    const int nt = K >> 6;
    stage(0, 0);
    asm volatile("s_waitcnt vmcnt(0)" ::: "memory");
    __builtin_amdgcn_s_barrier();

    for (int j = 0; j < nt; ++j) {
        const int buf = j & 1;
        if (j + 1 < nt) stage(buf ^ 1, (j + 1) << 6);
#pragma unroll
        for (int m = 0; m < 4; ++m) {
            af[m][0] = rdA(buf, m * 16, 0); af[m][1] = rdA(buf, m * 16, 1);
        }
#pragma unroll
        for (int n = 0; n < 2; ++n) {
            bf2[n][0] = rdB(buf, n * 16, 0); bf2[n][1] = rdB(buf, n * 16, 1);
        }
        __builtin_amdgcn_s_barrier();
        PHASE_MFMA(0, 0, 0);
#pragma unroll
        for (int n = 0; n < 2; ++n) {
            bf2[n][0] = rdB(buf, 32 + n * 16, 0); bf2[n][1] = rdB(buf, 32 + n * 16, 1);
        }
        __builtin_amdgcn_s_barrier();
        PHASE_MFMA(0, 1, 0);
#pragma unroll
        for (int m = 0; m < 4; ++m) {
            af[m][0] = rdA(buf, 64 + m * 16, 0); af[m][1] = rdA(buf, 64 + m * 16, 1);
        }
        __builtin_amdgcn_s_barrier();
        PHASE_MFMA(1, 1, 0);
#pragma unroll
        for (int n = 0; n < 2; ++n) {
            bf2[n][0] = rdB(buf, n * 16, 0); bf2[n][1] = rdB(buf, n * 16, 1);
        }
        __builtin_amdgcn_s_barrier();
        PHASE_MFMA(1, 0, 1);
    }
#undef PHASE_MFMA

    const int orow = row0 + wr * 128;
    const int ocol = col0 + wc * 64;
#pragma unroll
    for (int am = 0; am < 8; ++am)
#pragma unroll
        for (int an = 0; an < 4; ++an)
#pragma unroll
            for (int r = 0; r < 4; ++r) {
                int rr = orow + am * 16 + khalf * 4 + r;
                int cc = ocol + an * 16 + r16;
                C[(size_t)rr * ldc + cc] = f2b(acc[am][an][r]);
            }
}

// ---------------------------------------------------------------------------
// 128x128 GEMM (x_proj/dt_proj/out_proj): 3-buffer pipeline, swizzled.
// EPI: 0 = fp32, 2 = softplus(acc+aux[col])->bf16, 3 = residual fp32,
//      4 = split-K partial fp32 (blockIdx.x = K-part)
// ---------------------------------------------------------------------------
template<int EPI>
__global__ __launch_bounds__(256)
void gemm_bt(const u16* __restrict__ A, const u16* __restrict__ B,
             void* __restrict__ C, const float* __restrict__ aux,
             int K, int lda, int ldc)
{
    __shared__ u16 As[3][128 * 32];
    __shared__ u16 Bs[3][128 * 32];
    const int tid  = threadIdx.x;
    const int lane = tid & 63;
    const int w    = tid >> 6;
    const int wr   = w >> 1, wc = w & 1;
    const int row0 = blockIdx.y * 128;
    int col0 = blockIdx.x * 128;
    if (EPI == 4) {
        int part = blockIdx.x;
        col0 = 0;
        A += (size_t)part * K;
        B += (size_t)part * K;
        C = (void*)((float*)C + (size_t)part * TOK * XROWS);
    }
    const int r16   = lane & 15;
    const int khalf = lane >> 4;
    const int kslot = khalf ^ ((r16 >> 1) & 3);

    auto stage = [&](int buf, int k0) {
#pragma unroll
        for (int c = 0; c < 2; ++c) {
            int chunk = tid + c * 256;
            int r  = chunk >> 2;
            int j  = chunk & 3;
            int k8 = (j ^ ((r >> 1) & 3)) * 8;
            gload16(&A[(size_t)(row0 + r) * lda + k0 + k8], &As[buf][chunk * 8]);
            gload16(&B[(size_t)(col0 + r) * lda + k0 + k8], &Bs[buf][chunk * 8]);
        }
    };

    f32x4 acc[4][4];
#pragma unroll
    for (int m = 0; m < 4; ++m)
#pragma unroll
        for (int n = 0; n < 4; ++n)
            acc[m][n] = (f32x4)0.f;

    const int nt = K >> 5;
    stage(0, 0);
    if (nt > 1) stage(1, 32);

    int cur = 0, sb = 2;
    for (int t = 0; t < nt; ++t) {
        if (t + 2 < nt) {
            stage(sb, (t + 2) << 5);
            asm volatile("s_waitcnt vmcnt(8)" ::: "memory");
        } else if (t + 1 < nt) {
            asm volatile("s_waitcnt vmcnt(4)" ::: "memory");
        } else {
            asm volatile("s_waitcnt vmcnt(0)" ::: "memory");
        }
        __builtin_amdgcn_s_barrier();

        bf16x8 af[4], bfr[4];
#pragma unroll
        for (int m = 0; m < 4; ++m)
            af[m]  = *(const bf16x8*)&As[cur][(wr * 64 + m * 16 + r16) * 32 + kslot * 8];
#pragma unroll
        for (int n = 0; n < 4; ++n)
            bfr[n] = *(const bf16x8*)&Bs[cur][(wc * 64 + n * 16 + r16) * 32 + kslot * 8];
#pragma unroll
        for (int m = 0; m < 4; ++m)
#pragma unroll
            for (int n = 0; n < 4; ++n)
                acc[m][n] = __builtin_amdgcn_mfma_f32_16x16x32_bf16(
                    af[m], bfr[n], acc[m][n], 0, 0, 0);

        __builtin_amdgcn_sched_barrier(0);
        asm volatile("s_waitcnt lgkmcnt(0)" ::: "memory");
        __builtin_amdgcn_s_barrier();
        cur = (cur == 2) ? 0 : cur + 1;
        sb  = (sb  == 2) ? 0 : sb  + 1;
    }

    const int orow = row0 + wr * 64;
    const int ocol = col0 + wc * 64;
#pragma unroll
    for (int m = 0; m < 4; ++m)
#pragma unroll
        for (int n = 0; n < 4; ++n) {
#pragma unroll
            for (int r = 0; r < 4; ++r) {
                int rr = orow + m * 16 + khalf * 4 + r;
                int cc = ocol + n * 16 + r16;
                float v = acc[m][n][r];
                size_t o = (size_t)rr * ldc + cc;
                if (EPI == 0 || EPI == 4) {
                    ((float*)C)[o] = v;
                } else if (EPI == 2) {
                    float x = v + aux[cc];
                    float sp = (x > 20.f) ? x : log1pf(__expf(x));
                    ((u16*)C)[o] = f2b(sp);
                } else {
                    ((float*)C)[o] = aux[o] + v;
                }
            }
        }
}

// ---------------------------------------------------------------------------
// x_proj split-K reduce: ssm = sum of KSPL partials + bf16 dt-rank cols.
// ---------------------------------------------------------------------------
__global__ __launch_bounds__(256)
void xred_k(const float* __restrict__ part, float* __restrict__ ssm,
            u16* __restrict__ dtr)
{
    int idx = blockIdx.x * 256 + threadIdx.x;
    int row = idx >> 5;
    int col = (idx & 31) * 4;
    size_t o = (size_t)row * XROWS + col;
    const size_t stride = (size_t)TOK * XROWS;
    f32x4 v = *(const f32x4*)&part[o];
#pragma unroll
    for (int p = 1; p < KSPL; ++p)
        v += *(const f32x4*)&part[o + p * stride];
    *(f32x4*)&ssm[o] = v;
    if (col < DT_RANK) {
        s16x4 d;
#pragma unroll
        for (int j = 0; j < 4; ++j) d[j] = (short)f2b(v[j]);
        *(s16x4*)&dtr[(size_t)row * DT_RANK + col] = d;
    }
}

// ---------------------------------------------------------------------------
// RMSNorm over rows of 1024 fp32.
// ---------------------------------------------------------------------------
template<int OUTBF>
__global__ __launch_bounds__(256)
void rmsnorm_k(const float* __restrict__ in, const float* __restrict__ w,
               void* __restrict__ out)
{
    __shared__ float red[4];
    const int row = blockIdx.x;
    const int tid = threadIdx.x;
    const float* r = in + (size_t)row * D_MODEL;
    f32x4 v = *(const f32x4*)&r[tid * 4];
    float ss = v[0]*v[0] + v[1]*v[1] + v[2]*v[2] + v[3]*v[3];
#pragma unroll
    for (int m = 32; m >= 1; m >>= 1) ss += __shfl_xor(ss, m, 64);
    if ((tid & 63) == 0) red[tid >> 6] = ss;
    __syncthreads();
    if (tid == 0) {
        float s = red[0] + red[1] + red[2] + red[3];
        red[0] = rsqrtf(s / (float)D_MODEL + EPSV);
    }
    __syncthreads();
    float sc = red[0];
    if (OUTBF) {
        u16* o = (u16*)out + (size_t)row * D_MODEL + tid * 4;
#pragma unroll
        for (int j = 0; j < 4; ++j) o[j] = f2b(v[j] * sc * w[tid * 4 + j]);
    } else {
        float* o = (float*)out + (size_t)row * D_MODEL + tid * 4;
#pragma unroll
        for (int j = 0; j < 4; ++j) o[j] = v[j] * sc * w[tid * 4 + j];
    }
}

// ---------------------------------------------------------------------------
// Depthwise causal conv (width 4) + bias + SiLU, 8 channels/thread.
// ---------------------------------------------------------------------------
__global__ __launch_bounds__(256)
void conv_silu_k(const u16* __restrict__ projbf, const float* __restrict__ w,
                 const float* __restrict__ bias, u16* __restrict__ ubf)
{
    const int row = blockIdx.x;
    const int t   = row & (SEQ - 1);
    const int i0  = threadIdx.x * 8;
    float acc[8];
    {
        f32x4 b0 = *(const f32x4*)&bias[i0];
        f32x4 b1 = *(const f32x4*)&bias[i0 + 4];
#pragma unroll
        for (int j = 0; j < 4; ++j) { acc[j] = b0[j]; acc[j + 4] = b1[j]; }
    }
    f32x4 wv[8];
#pragma unroll
    for (int j = 0; j < 8; ++j)
        wv[j] = *(const f32x4*)&w[(i0 + j) * 4];
#pragma unroll
    for (int k = 0; k < 4; ++k) {
        int tt = t - 3 + k;
        if (tt >= 0) {
            bf16x8 hv = *(const bf16x8*)&projbf[(size_t)(row - 3 + k) * 4096 + i0];
#pragma unroll
            for (int j = 0; j < 8; ++j)
                acc[j] += b2f((u16)hv[j]) * wv[j][k];
        }
    }
    bf16x8 o;
#pragma unroll
    for (int j = 0; j < 8; ++j)
        o[j] = (short)f2b(silu(acc[j]));
    *(bf16x8*)&ubf[(size_t)row * INTER + i0] = o;
}

// ---------------------------------------------------------------------------
// A_log structure check: flags[l] stays nonzero iff A_log[l] == log(1..16)
// tiled (within 1e-4). Lets the scan use the w^(n+1) power-chain fast path
// while remaining generically correct.
// ---------------------------------------------------------------------------
__global__ __launch_bounds__(256)
void achk_k(const float* __restrict__ Alog, int* __restrict__ flags)
{
    int idx = blockIdx.x * 256 + threadIdx.x;   // N_LAYERS*INTER*16
    if (idx >= N_LAYERS * INTER * D_STATE) return;
    int l = idx / (INTER * D_STATE);
    int n = idx & (D_STATE - 1);
    float ref = logf((float)(n + 1));
    if (fabsf(Alog[idx] - ref) > 1e-4f) atomicAnd(&flags[l], 0);
}

// ---------------------------------------------------------------------------
// Chunked parallel selective scan. Fast path (flag != 0): decay
// exp(dt*a_n) == w^(n+1), w = exp(-dt)  -> 1 exp + 14 muls per timestep.
// ---------------------------------------------------------------------------
#define POWCHAIN(W)                                                          \
    float w2 = (W)*(W), w3 = w2*(W), w4 = w2*w2;                             \
    float w5 = w4*(W), w6 = w4*w2, w7 = w4*w3, w8 = w4*w4;                   \
    float w9 = w8*(W), w10 = w8*w2, w11 = w8*w3, w12 = w8*w4;                \
    float w13 = w8*w5, w14 = w8*w6, w15 = w8*w7, w16 = w8*w8;

__global__ __launch_bounds__(256)
void scan1_k(const u16* __restrict__ dtbf, const u16* __restrict__ ubf,
             const float* __restrict__ ssm, const float* __restrict__ Alog,
             const int* __restrict__ flag,
             float* __restrict__ cst, float* __restrict__ dts)
{
    __shared__ float Bs[TC][D_STATE];
    const int tid = threadIdx.x;
    const int i   = blockIdx.x * 256 + tid;
    const int g   = blockIdx.y;
    const int b   = blockIdx.z;
    const int t0  = g * TC;
    for (int idx = tid * 4; idx < TC * D_STATE; idx += 1024) {
        int t = idx >> 4, n = idx & 15;
        *(f32x4*)&Bs[t][n] =
            *(const f32x4*)&ssm[(size_t)(b * SEQ + t0 + t) * XROWS + DT_RANK + n];
    }
    __syncthreads();

    float s[D_STATE];
#pragma unroll
    for (int n = 0; n < D_STATE; ++n) s[n] = 0.f;
    float dsum = 0.f;

    const u16* dtp = dtbf + (size_t)(b * SEQ + t0) * INTER + i;
    const u16* up  = ubf  + (size_t)(b * SEQ + t0) * INTER + i;

    if (flag[0]) {
#pragma unroll
        for (int t = 0; t < TC; ++t) {
            float dt = b2f(dtp[(size_t)t * INTER]);
            float u  = b2f(up[(size_t)t * INTER]);
            float du = dt * u;
            dsum += dt;
            float w = __expf(-dt);
            POWCHAIN(w)
            f32x4 B0 = *(const f32x4*)&Bs[t][0];
            f32x4 B1 = *(const f32x4*)&Bs[t][4];
            f32x4 B2 = *(const f32x4*)&Bs[t][8];
            f32x4 B3 = *(const f32x4*)&Bs[t][12];
            s[0]=w*s[0]+du*B0[0];   s[1]=w2*s[1]+du*B0[1];
            s[2]=w3*s[2]+du*B0[2];  s[3]=w4*s[3]+du*B0[3];
            s[4]=w5*s[4]+du*B1[0];  s[5]=w6*s[5]+du*B1[1];
            s[6]=w7*s[6]+du*B1[2];  s[7]=w8*s[7]+du*B1[3];
            s[8]=w9*s[8]+du*B2[0];  s[9]=w10*s[9]+du*B2[1];
            s[10]=w11*s[10]+du*B2[2]; s[11]=w12*s[11]+du*B2[3];
            s[12]=w13*s[12]+du*B3[0]; s[13]=w14*s[13]+du*B3[1];
            s[14]=w15*s[14]+du*B3[2]; s[15]=w16*s[15]+du*B3[3];
        }
    } else {
        float a[D_STATE];
#pragma unroll
        for (int n = 0; n < D_STATE; ++n)
            a[n] = -__expf(Alog[(size_t)i * D_STATE + n]);
#pragma unroll 2
        for (int t = 0; t < TC; ++t) {
            float dt = b2f(dtp[(size_t)t * INTER]);
            float u  = b2f(up[(size_t)t * INTER]);
            float du = dt * u;
            dsum += dt;
            f32x4 B0 = *(const f32x4*)&Bs[t][0];
            f32x4 B1 = *(const f32x4*)&Bs[t][4];
            f32x4 B2 = *(const f32x4*)&Bs[t][8];
            f32x4 B3 = *(const f32x4*)&Bs[t][12];
#pragma unroll
            for (int n = 0; n < 4; ++n) {
                s[n]      = __expf(dt * a[n])      * s[n]      + du * B0[n];
                s[n + 4]  = __expf(dt * a[n + 4])  * s[n + 4]  + du * B1[n];
                s[n + 8]  = __expf(dt * a[n + 8])  * s[n + 8]  + du * B2[n];
                s[n + 12] = __expf(dt * a[n + 12]) * s[n + 12] + du * B3[n];
            }
        }
    }
    size_t o = ((size_t)(b * GCH + g) * INTER + i) * D_STATE;
#pragma unroll
    for (int n = 0; n < D_STATE; n += 4) {
        f32x4 v = { s[n], s[n+1], s[n+2], s[n+3] };
        *(f32x4*)&cst[o + n] = v;
    }
    dts[(size_t)(b * GCH + g) * INTER + i] = dsum;
}

// in-place: cst local chunk-end -> chunk-START states.
__global__ __launch_bounds__(256)
void scan2_k(float* __restrict__ cst, const float* __restrict__ dts,
             const float* __restrict__ Alog)
{
    int idx = blockIdx.x * 256 + threadIdx.x;
    int sub = idx & 3;
    int i   = (idx >> 2) & (INTER - 1);
    int b   = idx >> 13;
    int n0  = sub * 4;
    float a[4];
#pragma unroll
    for (int n = 0; n < 4; ++n)
        a[n] = -__expf(Alog[(size_t)i * D_STATE + n0 + n]);
    f32x4 s = (f32x4)0.f;
    for (int g = 0; g < GCH; ++g) {
        size_t o = ((size_t)(b * GCH + g) * INTER + i) * D_STATE + n0;
        f32x4 tmp = *(const f32x4*)&cst[o];
        *(f32x4*)&cst[o] = s;
        float d = dts[(size_t)(b * GCH + g) * INTER + i];
#pragma unroll
        for (int n = 0; n < 4; ++n)
            s[n] = __expf(a[n] * d) * s[n] + tmp[n];
    }
}

__global__ __launch_bounds__(256)
void scan3_k(const u16* __restrict__ dtbf, const u16* __restrict__ ubf,
             const float* __restrict__ ssm, const u16* __restrict__ projbf,
             const float* __restrict__ Alog, const float* __restrict__ Dp,
             const int* __restrict__ flag,
             const float* __restrict__ sst, u16* __restrict__ ybf)
{
    __shared__ float Bs[TC][D_STATE];
    __shared__ float Cs[TC][D_STATE];
    const int tid = threadIdx.x;
    const int i   = blockIdx.x * 256 + tid;
    const int g   = blockIdx.y;
    const int b   = blockIdx.z;
    const int t0  = g * TC;
    for (int idx = tid * 4; idx < TC * D_STATE; idx += 1024) {
        int t = idx >> 4, n = idx & 15;
        size_t row = (size_t)(b * SEQ + t0 + t) * XROWS;
        *(f32x4*)&Bs[t][n] = *(const f32x4*)&ssm[row + DT_RANK + n];
        *(f32x4*)&Cs[t][n] = *(const f32x4*)&ssm[row + DT_RANK + D_STATE + n];
    }
    __syncthreads();

    const float Di = Dp[i];
    float s[D_STATE];
    size_t so = ((size_t)(b * GCH + g) * INTER + i) * D_STATE;
#pragma unroll
    for (int n = 0; n < D_STATE; n += 4) {
        f32x4 v = *(const f32x4*)&sst[so + n];
        s[n] = v[0]; s[n+1] = v[1]; s[n+2] = v[2]; s[n+3] = v[3];
    }

    const u16* dtp = dtbf   + (size_t)(b * SEQ + t0) * INTER + i;
    const u16* up  = ubf    + (size_t)(b * SEQ + t0) * INTER + i;
    const u16* gp  = projbf + (size_t)(b * SEQ + t0) * 4096 + INTER + i;
    u16*       yp  = ybf    + (size_t)(b * SEQ + t0) * INTER + i;

    if (flag[0]) {
#pragma unroll
        for (int t = 0; t < TC; ++t) {
            float dt = b2f(dtp[(size_t)t * INTER]);
            float u  = b2f(up[(size_t)t * INTER]);
            float gt = b2f(gp[(size_t)t * 4096]);
            float du = dt * u;
            float w = __expf(-dt);
            POWCHAIN(w)
            f32x4 B0 = *(const f32x4*)&Bs[t][0];
            f32x4 B1 = *(const f32x4*)&Bs[t][4];
            f32x4 B2 = *(const f32x4*)&Bs[t][8];
            f32x4 B3 = *(const f32x4*)&Bs[t][12];
            f32x4 C0 = *(const f32x4*)&Cs[t][0];
            f32x4 C1 = *(const f32x4*)&Cs[t][4];
            f32x4 C2 = *(const f32x4*)&Cs[t][8];
            f32x4 C3 = *(const f32x4*)&Cs[t][12];
            s[0]=w*s[0]+du*B0[0];   s[1]=w2*s[1]+du*B0[1];
            s[2]=w3*s[2]+du*B0[2];  s[3]=w4*s[3]+du*B0[3];
            s[4]=w5*s[4]+du*B1[0];  s[5]=w6*s[5]+du*B1[1];
            s[6]=w7*s[6]+du*B1[2];  s[7]=w8*s[7]+du*B1[3];
            s[8]=w9*s[8]+du*B2[0];  s[9]=w10*s[9]+du*B2[1];
            s[10]=w11*s[10]+du*B2[2]; s[11]=w12*s[11]+du*B2[3];
            s[12]=w13*s[12]+du*B3[0]; s[13]=w14*s[13]+du*B3[1];
            s[14]=w15*s[14]+du*B3[2]; s[15]=w16*s[15]+du*B3[3];
            float y = s[0]*C0[0] + s[1]*C0[1] + s[2]*C0[2] + s[3]*C0[3]
                    + s[4]*C1[0] + s[5]*C1[1] + s[6]*C1[2] + s[7]*C1[3]
                    + s[8]*C2[0] + s[9]*C2[1] + s[10]*C2[2] + s[11]*C2[3]
                    + s[12]*C3[0] + s[13]*C3[1] + s[14]*C3[2] + s[15]*C3[3];
            yp[(size_t)t * INTER] = f2b((y + Di * u) * silu(gt));
        }
    } else {
        float a[D_STATE];
#pragma unroll
        for (int n = 0; n < D_STATE; ++n)
            a[n] = -__expf(Alog[(size_t)i * D_STATE + n]);
#pragma unroll 2
        for (int t = 0; t < TC; ++t) {
            float dt = b2f(dtp[(size_t)t * INTER]);
            float u  = b2f(up[(size_t)t * INTER]);
            float gt = b2f(gp[(size_t)t * 4096]);
            float du = dt * u;
            f32x4 B0 = *(const f32x4*)&Bs[t][0];
            f32x4 B1 = *(const f32x4*)&Bs[t][4];
            f32x4 B2 = *(const f32x4*)&Bs[t][8];
            f32x4 B3 = *(const f32x4*)&Bs[t][12];
            f32x4 C0 = *(const f32x4*)&Cs[t][0];
            f32x4 C1 = *(const f32x4*)&Cs[t][4];
            f32x4 C2 = *(const f32x4*)&Cs[t][8];
            f32x4 C3 = *(const f32x4*)&Cs[t][12];
            float y = 0.f;
#pragma unroll
            for (int n = 0; n < 4; ++n) {
                s[n]      = __expf(dt * a[n])      * s[n]      + du * B0[n];
                s[n + 4]  = __expf(dt * a[n + 4])  * s[n + 4]  + du * B1[n];
                s[n + 8]  = __expf(dt * a[n + 8])  * s[n + 8]  + du * B2[n];
                s[n + 12] = __expf(dt * a[n + 12]) * s[n + 12] + du * B3[n];
                y += s[n] * C0[n] + s[n + 4] * C1[n] + s[n + 8] * C2[n] + s[n + 12] * C3[n];
            }
            yp[(size_t)t * INTER] = f2b((y + Di * u) * silu(gt));
        }
    }
}

// ---------------------------------------------------------------------------
__global__ __launch_bounds__(256)
void cvt_f2b_k(const float* __restrict__ in, u16* __restrict__ out, int n)
{
    int idx = blockIdx.x * 256 + threadIdx.x;
    if (idx < n) out[idx] = f2b(in[idx]);
}

__global__ __launch_bounds__(256)
void pad_xw_k(const float* __restrict__ xw, u16* __restrict__ out)
{
    int idx = blockIdx.x * 256 + threadIdx.x;
    if (idx >= N_LAYERS * XROWS * INTER) return;
    int l = idx / (XROWS * INTER);
    int r = (idx >> 11) & (XROWS - 1);
    int c = idx & (INTER - 1);
    out[idx] = (r < 96) ? f2b(xw[((size_t)l * 96 + r) * INTER + c]) : (u16)0;
}

// ---------------------------------------------------------------------------
extern "C" void kernel_launch(void* const* d_in, const int* in_sizes, int n_in,
                              void* d_out, int out_size, void* d_ws, size_t ws_size,
                              hipStream_t stream)
{
    const float* x      = (const float*)d_in[0];
    const float* in_w   = (const float*)d_in[1];
    const float* conv_w = (const float*)d_in[2];
    const float* conv_b = (const float*)d_in[3];
    const float* x_w    = (const float*)d_in[4];
    const float* dt_w   = (const float*)d_in[5];
    const float* dt_b   = (const float*)d_in[6];
    const float* A_log  = (const float*)d_in[7];
    const float* Dp     = (const float*)d_in[8];
    const float* out_w  = (const float*)d_in[9];
    const float* norm_w = (const float*)d_in[10];
    const float* norm_f = (const float*)d_in[11];

    char* ws = (char*)d_ws;
    size_t off = 0;
    auto alloc = [&](size_t bytes) { char* p = ws + off; off += (bytes + 255) & ~(size_t)255; return p; };

    u16*   inw_bf  = (u16*)  alloc((size_t)N_LAYERS * 4096 * 1024 * 2);
    u16*   xw_bf   = (u16*)  alloc((size_t)N_LAYERS * XROWS * INTER * 2);
    u16*   dtw_bf  = (u16*)  alloc((size_t)N_LAYERS * INTER * DT_RANK * 2);
    u16*   outw_bf = (u16*)  alloc((size_t)N_LAYERS * D_MODEL * INTER * 2);
    float* h       = (float*)alloc((size_t)TOK * D_MODEL * 4);
    u16*   xn_bf   = (u16*)  alloc((size_t)TOK * D_MODEL * 2);
    u16*   proj_bf = (u16*)  alloc((size_t)TOK * 4096 * 2);
    u16*   u_bf    = (u16*)  alloc((size_t)TOK * INTER * 2);
    float* ssm     = (float*)alloc((size_t)TOK * XROWS * 4);
    float* ssm_p   = (float*)alloc((size_t)KSPL * TOK * XROWS * 4);
    u16*   dtr_bf  = (u16*)  alloc((size_t)TOK * DT_RANK * 2);
    u16*   dt_bf   = (u16*)  alloc((size_t)TOK * INTER * 2);
    u16*   y_bf    = (u16*)  alloc((size_t)TOK * INTER * 2);
    float* cst     = (float*)alloc((size_t)B_SZ * GCH * INTER * D_STATE * 4);
    float* dts     = (float*)alloc((size_t)B_SZ * GCH * INTER * 4);
    int*   aflags  = (int*)  alloc(N_LAYERS * sizeof(int));
    (void)ws_size; (void)n_in; (void)in_sizes; (void)out_size;

    // weight conversion + A_log structure check (every launch; deterministic)
    {
        int n = N_LAYERS * 4096 * 1024;
        cvt_f2b_k<<<n / 256, 256, 0, stream>>>(in_w, inw_bf, n);
        int np = N_LAYERS * XROWS * INTER;
        pad_xw_k<<<np / 256, 256, 0, stream>>>(x_w, xw_bf);
        int nd = N_LAYERS * INTER * DT_RANK;
        cvt_f2b_k<<<nd / 256, 256, 0, stream>>>(dt_w, dtw_bf, nd);
        int no = N_LAYERS * D_MODEL * INTER;
        cvt_f2b_k<<<no / 256, 256, 0, stream>>>(out_w, outw_bf, no);
        hipMemsetAsync(aflags, 0xFF, N_LAYERS * sizeof(int), stream);
        int na = N_LAYERS * INTER * D_STATE;
        achk_k<<<(na + 255) / 256, 256, 0, stream>>>(A_log, aflags);
    }

    hipMemcpyAsync(h, x, (size_t)TOK * D_MODEL * 4, hipMemcpyDeviceToDevice, stream);

    for (int l = 0; l < N_LAYERS; ++l) {
        // 1. rmsnorm -> xn_bf
        rmsnorm_k<1><<<TOK, 256, 0, stream>>>(h, norm_w + (size_t)l * D_MODEL, xn_bf);
        // 2. in_proj (256^2 8-phase): [4096,1024] @ [4096,1024]^T -> proj_bf
        gemm256_k<<<dim3(16, 16), 512, 0, stream>>>(
            xn_bf, inw_bf + (size_t)l * 4096 * 1024, proj_bf, 1024, 4096);
        // 3. conv + silu -> u_bf
        conv_silu_k<<<TOK, 256, 0, stream>>>(
            proj_bf, conv_w + (size_t)l * INTER * D_CONV, conv_b + (size_t)l * INTER, u_bf);
        // 4. x_proj split-K: [4096,2048] @ [128,2048]^T -> 4 partials
        gemm_bt<4><<<dim3(KSPL, 32), 256, 0, stream>>>(
            u_bf, xw_bf + (size_t)l * XROWS * INTER, ssm_p, nullptr,
            INTER / KSPL, INTER, XROWS);
        // 4b. reduce partials -> ssm fp32 + dtr bf16
        xred_k<<<(TOK * 32) / 256, 256, 0, stream>>>(ssm_p, ssm, dtr_bf);
        // 5. dt_proj + softplus -> dt_bf [4096,2048]
        gemm_bt<2><<<dim3(16, 32), 256, 0, stream>>>(
            dtr_bf, dtw_bf + (size_t)l * INTER * DT_RANK, dt_bf,
            dt_b + (size_t)l * INTER, DT_RANK, DT_RANK, INTER);
        // 6. chunked scan (+ skip + gate) -> y_bf
        scan1_k<<<dim3(INTER / 256, GCH, B_SZ), 256, 0, stream>>>(
            dt_bf, u_bf, ssm, A_log + (size_t)l * INTER * D_STATE, aflags + l, cst, dts);
        scan2_k<<<(B_SZ * INTER * 4) / 256, 256, 0, stream>>>(
            cst, dts, A_log + (size_t)l * INTER * D_STATE);
        scan3_k<<<dim3(INTER / 256, GCH, B_SZ), 256, 0, stream>>>(
            dt_bf, u_bf, ssm, proj_bf, A_log + (size_t)l * INTER * D_STATE,
            Dp + (size_t)l * INTER, aflags + l, cst, y_bf);
        // 7. out_proj + residual -> h
        gemm_bt<3><<<dim3(8, 32), 256, 0, stream>>>(
            y_bf, outw_bf + (size_t)l * D_MODEL * INTER, h, h, INTER, INTER, D_MODEL);
    }
    // final rmsnorm -> d_out (fp32)
    rmsnorm_k<0><<<TOK, 256, 0, stream>>>(h, norm_f, d_out);
}

// Round 8
// 940.080 us; speedup vs baseline: 3.8532x; 1.0319x over previous
//
#include <hip/hip_runtime.h>
#include <hip/hip_bf16.h>
#include <math.h>

#define D_MODEL 1024
#define N_LAYERS 4
#define INTER 2048
#define D_CONV 4
#define D_STATE 16
#define DT_RANK 64
#define B_SZ 4
#define SEQ 1024
#define TOK (B_SZ*SEQ)          // 4096 token rows
#define XROWS 128               // x_proj rows padded 96 -> 128
#define EPSV 1e-5f
#define GCH 64                  // scan chunks
#define TC (SEQ/GCH)            // 16 timesteps per chunk
#define KSPL 4                  // x_proj K-split factor
#define OSPL 2                  // out_proj K-split factor

typedef unsigned short u16;
typedef unsigned int u32;
typedef __attribute__((ext_vector_type(8))) short bf16x8;
typedef __attribute__((ext_vector_type(4))) short s16x4;
typedef __attribute__((ext_vector_type(4))) float f32x4;

__device__ __forceinline__ u16 f2b(float f) {
    union { float f; unsigned u; } v; v.f = f;
    unsigned r = v.u + 0x7fffu + ((v.u >> 16) & 1u);
    return (u16)(r >> 16);
}
__device__ __forceinline__ float b2f(u16 h) {
    union { unsigned u; float f; } v; v.u = ((unsigned)h) << 16;
    return v.f;
}
__device__ __forceinline__ float silu(float x) {
    return x / (1.f + __expf(-x));
}
__device__ __forceinline__ void gload16(const void* g, void* l) {
    __builtin_amdgcn_global_load_lds(
        (const __attribute__((address_space(1))) void*)g,
        (__attribute__((address_space(3))) void*)l, 16, 0, 0);
}

// ---------------------------------------------------------------------------
// 256x256 8-phase GEMM (in_proj). T2+T3+T4+T5 schedule (see R5/R6 notes).
// ---------------------------------------------------------------------------
__global__ __launch_bounds__(512, 2)
void gemm256_k(const u16* __restrict__ A, const u16* __restrict__ B,
               u16* __restrict__ C, int K, int ldc)
{
    __shared__ u16 lds[2][2][256 * 64];
    const int tid  = threadIdx.x;
    const int lane = tid & 63;
    const int wid  = tid >> 6;
    const int wr   = wid >> 2;
    const int wc   = wid & 3;
    const int row0 = blockIdx.y * 256;
    const int col0 = blockIdx.x * 256;
    const int r16   = lane & 15;
    const int khalf = lane >> 4;

    auto stage = [&](int buf, int k0) {
#pragma unroll
        for (int l = 0; l < 8; ++l) {
            int op = l >> 2;
            int c  = tid + (l & 3) * 512;
            int r  = c >> 3;
            int ds = c & 7;
            int sc = (ds ^ (r & 7)) * 8;
            const u16* src = op ? &B[(size_t)(col0 + r) * K + k0 + sc]
                                : &A[(size_t)(row0 + r) * K + k0 + sc];
            gload16(src, &lds[buf][op][c * 8]);
        }
    };
    auto rdA = [&](int buf, int mrow, int ks) -> bf16x8 {
        int row  = wr * 128 + mrow + r16;
        int phys = ((ks << 2) | khalf) ^ (row & 7);
        return *(const bf16x8*)&lds[buf][0][row * 64 + phys * 8];
    };
    auto rdB = [&](int buf, int nrow, int ks) -> bf16x8 {
        int row  = wc * 64 + nrow + r16;
        int phys = ((ks << 2) | khalf) ^ (row & 7);
        return *(const bf16x8*)&lds[buf][1][row * 64 + phys * 8];
    };

    f32x4 acc[8][4];
#pragma unroll
    for (int m = 0; m < 8; ++m)
#pragma unroll
        for (int n = 0; n < 4; ++n)
            acc[m][n] = (f32x4)0.f;

    bf16x8 af[4][2], bf2[2][2];

#define PHASE_MFMA(MH, NH, VMDRAIN) do {                                      \
    asm volatile("s_waitcnt lgkmcnt(0)" ::: "memory");                        \
    __builtin_amdgcn_sched_barrier(0);                                        \
    __builtin_amdgcn_s_setprio(1);                                            \
    _Pragma("unroll")                                                         \
    for (int ks = 0; ks < 2; ++ks)                                            \
        _Pragma("unroll")                                                     \
        for (int m = 0; m < 4; ++m)                                           \
            _Pragma("unroll")                                                 \
            for (int n = 0; n < 2; ++n)                                       \
                acc[(MH)*4+m][(NH)*2+n] =                                     \
                    __builtin_amdgcn_mfma_f32_16x16x32_bf16(                  \
                        af[m][ks], bf2[n][ks], acc[(MH)*4+m][(NH)*2+n],0,0,0);\
    __builtin_amdgcn_s_setprio(0);                                            \
    if (VMDRAIN) { asm volatile("s_waitcnt vmcnt(0)" ::: "memory"); }         \
    __builtin_amdgcn_s_barrier();                                             \
} while (0)

    const int nt = K >> 6;
    stage(0, 0);
    asm volatile("s_waitcnt vmcnt(0)" ::: "memory");
    __builtin_amdgcn_s_barrier();

    for (int j = 0; j < nt; ++j) {
        const int buf = j & 1;
        if (j + 1 < nt) stage(buf ^ 1, (j + 1) << 6);
#pragma unroll
        for (int m = 0; m < 4; ++m) {
            af[m][0] = rdA(buf, m * 16, 0); af[m][1] = rdA(buf, m * 16, 1);
        }
#pragma unroll
        for (int n = 0; n < 2; ++n) {
            bf2[n][0] = rdB(buf, n * 16, 0); bf2[n][1] = rdB(buf, n * 16, 1);
        }
        __builtin_amdgcn_s_barrier();
        PHASE_MFMA(0, 0, 0);
#pragma unroll
        for (int n = 0; n < 2; ++n) {
            bf2[n][0] = rdB(buf, 32 + n * 16, 0); bf2[n][1] = rdB(buf, 32 + n * 16, 1);
        }
        __builtin_amdgcn_s_barrier();
        PHASE_MFMA(0, 1, 0);
#pragma unroll
        for (int m = 0; m < 4; ++m) {
            af[m][0] = rdA(buf, 64 + m * 16, 0); af[m][1] = rdA(buf, 64 + m * 16, 1);
        }
        __builtin_amdgcn_s_barrier();
        PHASE_MFMA(1, 1, 0);
#pragma unroll
        for (int n = 0; n < 2; ++n) {
            bf2[n][0] = rdB(buf, n * 16, 0); bf2[n][1] = rdB(buf, n * 16, 1);
        }
        __builtin_amdgcn_s_barrier();
        PHASE_MFMA(1, 0, 1);
    }
#undef PHASE_MFMA

    const int orow = row0 + wr * 128;
    const int ocol = col0 + wc * 64;
#pragma unroll
    for (int am = 0; am < 8; ++am)
#pragma unroll
        for (int an = 0; an < 4; ++an)
#pragma unroll
            for (int r = 0; r < 4; ++r) {
                int rr = orow + am * 16 + khalf * 4 + r;
                int cc = ocol + an * 16 + r16;
                C[(size_t)rr * ldc + cc] = f2b(acc[am][an][r]);
            }
}

// ---------------------------------------------------------------------------
// 128x128 GEMM: 3-buffer pipeline, swizzled.
// EPI: 0 = fp32, 2 = softplus(acc+aux[col])->bf16,
//      4 = split-K partial fp32: part = blockIdx.x / NPX, col-tile = % NPX,
//          C += part * pstride
// ---------------------------------------------------------------------------
template<int EPI, int NPX = 1>
__global__ __launch_bounds__(256)
void gemm_bt(const u16* __restrict__ A, const u16* __restrict__ B,
             void* __restrict__ C, const float* __restrict__ aux,
             int K, int lda, int ldc, size_t pstride)
{
    __shared__ u16 As[3][128 * 32];
    __shared__ u16 Bs[3][128 * 32];
    const int tid  = threadIdx.x;
    const int lane = tid & 63;
    const int w    = tid >> 6;
    const int wr   = w >> 1, wc = w & 1;
    const int row0 = blockIdx.y * 128;
    int col0 = blockIdx.x * 128;
    if (EPI == 4) {
        int part = blockIdx.x / NPX;
        col0 = (blockIdx.x % NPX) * 128;
        A += (size_t)part * K;
        B += (size_t)part * K;
        C = (void*)((float*)C + (size_t)part * pstride);
    }
    const int r16   = lane & 15;
    const int khalf = lane >> 4;
    const int kslot = khalf ^ ((r16 >> 1) & 3);

    auto stage = [&](int buf, int k0) {
#pragma unroll
        for (int c = 0; c < 2; ++c) {
            int chunk = tid + c * 256;
            int r  = chunk >> 2;
            int j  = chunk & 3;
            int k8 = (j ^ ((r >> 1) & 3)) * 8;
            gload16(&A[(size_t)(row0 + r) * lda + k0 + k8], &As[buf][chunk * 8]);
            gload16(&B[(size_t)(col0 + r) * lda + k0 + k8], &Bs[buf][chunk * 8]);
        }
    };

    f32x4 acc[4][4];
#pragma unroll
    for (int m = 0; m < 4; ++m)
#pragma unroll
        for (int n = 0; n < 4; ++n)
            acc[m][n] = (f32x4)0.f;

    const int nt = K >> 5;
    stage(0, 0);
    if (nt > 1) stage(1, 32);

    int cur = 0, sb = 2;
    for (int t = 0; t < nt; ++t) {
        if (t + 2 < nt) {
            stage(sb, (t + 2) << 5);
            asm volatile("s_waitcnt vmcnt(8)" ::: "memory");
        } else if (t + 1 < nt) {
            asm volatile("s_waitcnt vmcnt(4)" ::: "memory");
        } else {
            asm volatile("s_waitcnt vmcnt(0)" ::: "memory");
        }
        __builtin_amdgcn_s_barrier();

        bf16x8 af[4], bfr[4];
#pragma unroll
        for (int m = 0; m < 4; ++m)
            af[m]  = *(const bf16x8*)&As[cur][(wr * 64 + m * 16 + r16) * 32 + kslot * 8];
#pragma unroll
        for (int n = 0; n < 4; ++n)
            bfr[n] = *(const bf16x8*)&Bs[cur][(wc * 64 + n * 16 + r16) * 32 + kslot * 8];
#pragma unroll
        for (int m = 0; m < 4; ++m)
#pragma unroll
            for (int n = 0; n < 4; ++n)
                acc[m][n] = __builtin_amdgcn_mfma_f32_16x16x32_bf16(
                    af[m], bfr[n], acc[m][n], 0, 0, 0);

        __builtin_amdgcn_sched_barrier(0);
        asm volatile("s_waitcnt lgkmcnt(0)" ::: "memory");
        __builtin_amdgcn_s_barrier();
        cur = (cur == 2) ? 0 : cur + 1;
        sb  = (sb  == 2) ? 0 : sb  + 1;
    }

    const int orow = row0 + wr * 64;
    const int ocol = col0 + wc * 64;
#pragma unroll
    for (int m = 0; m < 4; ++m)
#pragma unroll
        for (int n = 0; n < 4; ++n) {
#pragma unroll
            for (int r = 0; r < 4; ++r) {
                int rr = orow + m * 16 + khalf * 4 + r;
                int cc = ocol + n * 16 + r16;
                float v = acc[m][n][r];
                size_t o = (size_t)rr * ldc + cc;
                if (EPI == 0 || EPI == 4) {
                    ((float*)C)[o] = v;
                } else if (EPI == 2) {
                    float x = v + aux[cc];
                    float sp = (x > 20.f) ? x : log1pf(__expf(x));
                    ((u16*)C)[o] = f2b(sp);
                }
            }
        }
}

// ---------------------------------------------------------------------------
// x_proj split-K reduce: ssm = sum of KSPL partials + bf16 dt-rank cols.
// ---------------------------------------------------------------------------
__global__ __launch_bounds__(256)
void xred_k(const float* __restrict__ part, float* __restrict__ ssm,
            u16* __restrict__ dtr)
{
    int idx = blockIdx.x * 256 + threadIdx.x;
    int row = idx >> 5;
    int col = (idx & 31) * 4;
    size_t o = (size_t)row * XROWS + col;
    const size_t stride = (size_t)TOK * XROWS;
    f32x4 v = *(const f32x4*)&part[o];
#pragma unroll
    for (int p = 1; p < KSPL; ++p)
        v += *(const f32x4*)&part[o + p * stride];
    *(f32x4*)&ssm[o] = v;
    if (col < DT_RANK) {
        s16x4 d;
#pragma unroll
        for (int j = 0; j < 4; ++j) d[j] = (short)f2b(v[j]);
        *(s16x4*)&dtr[(size_t)row * DT_RANK + col] = d;
    }
}

// ---------------------------------------------------------------------------
// RMSNorm (plain): rows of 1024 fp32 -> bf16/fp32.
// ---------------------------------------------------------------------------
template<int OUTBF>
__global__ __launch_bounds__(256)
void rmsnorm_k(const float* __restrict__ in, const float* __restrict__ w,
               void* __restrict__ out)
{
    __shared__ float red[4];
    const int row = blockIdx.x;
    const int tid = threadIdx.x;
    const float* r = in + (size_t)row * D_MODEL;
    f32x4 v = *(const f32x4*)&r[tid * 4];
    float ss = v[0]*v[0] + v[1]*v[1] + v[2]*v[2] + v[3]*v[3];
#pragma unroll
    for (int m = 32; m >= 1; m >>= 1) ss += __shfl_xor(ss, m, 64);
    if ((tid & 63) == 0) red[tid >> 6] = ss;
    __syncthreads();
    if (tid == 0) {
        float s = red[0] + red[1] + red[2] + red[3];
        red[0] = rsqrtf(s / (float)D_MODEL + EPSV);
    }
    __syncthreads();
    float sc = red[0];
    if (OUTBF) {
        u16* o = (u16*)out + (size_t)row * D_MODEL + tid * 4;
#pragma unroll
        for (int j = 0; j < 4; ++j) o[j] = f2b(v[j] * sc * w[tid * 4 + j]);
    } else {
        float* o = (float*)out + (size_t)row * D_MODEL + tid * 4;
#pragma unroll
        for (int j = 0; j < 4; ++j) o[j] = v[j] * sc * w[tid * 4 + j];
    }
}

// ---------------------------------------------------------------------------
// Fused residual + RMSNorm: hn = hin + p0 + p1 (out_proj split-K partials);
// optionally write hn to hout; write normalized output (bf16 or fp32).
// ---------------------------------------------------------------------------
template<int OUTBF, int WRITEH>
__global__ __launch_bounds__(256)
void rmsnorm_res_k(const float* __restrict__ hin, const float* __restrict__ p,
                   const float* __restrict__ w, float* __restrict__ hout,
                   void* __restrict__ out)
{
    __shared__ float red[4];
    const int row = blockIdx.x;
    const int tid = threadIdx.x;
    const size_t o4 = (size_t)row * D_MODEL + tid * 4;
    f32x4 v  = *(const f32x4*)&hin[o4];
    f32x4 p0 = *(const f32x4*)&p[o4];
    f32x4 p1 = *(const f32x4*)&p[(size_t)TOK * D_MODEL + o4];
    v += p0 + p1;
    if (WRITEH) *(f32x4*)&hout[o4] = v;
    float ss = v[0]*v[0] + v[1]*v[1] + v[2]*v[2] + v[3]*v[3];
#pragma unroll
    for (int m = 32; m >= 1; m >>= 1) ss += __shfl_xor(ss, m, 64);
    if ((tid & 63) == 0) red[tid >> 6] = ss;
    __syncthreads();
    if (tid == 0) {
        float s = red[0] + red[1] + red[2] + red[3];
        red[0] = rsqrtf(s / (float)D_MODEL + EPSV);
    }
    __syncthreads();
    float sc = red[0];
    if (OUTBF) {
        u16* o = (u16*)out + o4;
#pragma unroll
        for (int j = 0; j < 4; ++j) o[j] = f2b(v[j] * sc * w[tid * 4 + j]);
    } else {
        float* o = (float*)out + o4;
#pragma unroll
        for (int j = 0; j < 4; ++j) o[j] = v[j] * sc * w[tid * 4 + j];
    }
}

// ---------------------------------------------------------------------------
// Depthwise causal conv (width 4) + bias + SiLU, 8 channels/thread.
// ---------------------------------------------------------------------------
__global__ __launch_bounds__(256)
void conv_silu_k(const u16* __restrict__ projbf, const float* __restrict__ w,
                 const float* __restrict__ bias, u16* __restrict__ ubf)
{
    const int row = blockIdx.x;
    const int t   = row & (SEQ - 1);
    const int i0  = threadIdx.x * 8;
    float acc[8];
    {
        f32x4 b0 = *(const f32x4*)&bias[i0];
        f32x4 b1 = *(const f32x4*)&bias[i0 + 4];
#pragma unroll
        for (int j = 0; j < 4; ++j) { acc[j] = b0[j]; acc[j + 4] = b1[j]; }
    }
    f32x4 wv[8];
#pragma unroll
    for (int j = 0; j < 8; ++j)
        wv[j] = *(const f32x4*)&w[(i0 + j) * 4];
#pragma unroll
    for (int k = 0; k < 4; ++k) {
        int tt = t - 3 + k;
        if (tt >= 0) {
            bf16x8 hv = *(const bf16x8*)&projbf[(size_t)(row - 3 + k) * 4096 + i0];
#pragma unroll
            for (int j = 0; j < 8; ++j)
                acc[j] += b2f((u16)hv[j]) * wv[j][k];
        }
    }
    bf16x8 o;
#pragma unroll
    for (int j = 0; j < 8; ++j)
        o[j] = (short)f2b(silu(acc[j]));
    *(bf16x8*)&ubf[(size_t)row * INTER + i0] = o;
}

// ---------------------------------------------------------------------------
// A_log structure check (fast-path guard).
// ---------------------------------------------------------------------------
__global__ __launch_bounds__(256)
void achk_k(const float* __restrict__ Alog, int* __restrict__ flags)
{
    int idx = blockIdx.x * 256 + threadIdx.x;
    if (idx >= N_LAYERS * INTER * D_STATE) return;
    int l = idx / (INTER * D_STATE);
    int n = idx & (D_STATE - 1);
    float ref = logf((float)(n + 1));
    if (fabsf(Alog[idx] - ref) > 1e-4f) atomicAnd(&flags[l], 0);
}

// ---------------------------------------------------------------------------
// Chunked selective scan, 2 channels per thread (ILP x2, packed u32 loads).
// Fast path: decay exp(dt*a_n) == w^(n+1), w = exp(-dt).
// ---------------------------------------------------------------------------
#define POWCH(W, p) \
    float p##2=(W)*(W), p##3=p##2*(W), p##4=p##2*p##2, p##5=p##4*(W),        \
          p##6=p##4*p##2, p##7=p##4*p##3, p##8=p##4*p##4, p##9=p##8*(W),     \
          p##10=p##8*p##2, p##11=p##8*p##3, p##12=p##8*p##4, p##13=p##8*p##5,\
          p##14=p##8*p##6, p##15=p##8*p##7, p##16=p##8*p##8;

#define SUPD(S, B, du, w1) \
    S[0]=w1*S[0]+du*B[0][0];   S[1]=w1##2*S[1]+du*B[0][1];                   \
    S[2]=w1##3*S[2]+du*B[0][2];  S[3]=w1##4*S[3]+du*B[0][3];                 \
    S[4]=w1##5*S[4]+du*B[1][0];  S[5]=w1##6*S[5]+du*B[1][1];                 \
    S[6]=w1##7*S[6]+du*B[1][2];  S[7]=w1##8*S[7]+du*B[1][3];                 \
    S[8]=w1##9*S[8]+du*B[2][0];  S[9]=w1##10*S[9]+du*B[2][1];                \
    S[10]=w1##11*S[10]+du*B[2][2]; S[11]=w1##12*S[11]+du*B[2][3];            \
    S[12]=w1##13*S[12]+du*B[3][0]; S[13]=w1##14*S[13]+du*B[3][1];            \
    S[14]=w1##15*S[14]+du*B[3][2]; S[15]=w1##16*S[15]+du*B[3][3];

#define YDOT(S, Cv) \
    (S[0]*Cv[0][0]+S[1]*Cv[0][1]+S[2]*Cv[0][2]+S[3]*Cv[0][3]                 \
    +S[4]*Cv[1][0]+S[5]*Cv[1][1]+S[6]*Cv[1][2]+S[7]*Cv[1][3]                 \
    +S[8]*Cv[2][0]+S[9]*Cv[2][1]+S[10]*Cv[2][2]+S[11]*Cv[2][3]               \
    +S[12]*Cv[3][0]+S[13]*Cv[3][1]+S[14]*Cv[3][2]+S[15]*Cv[3][3])

__global__ __launch_bounds__(256)
void scan1_k(const u16* __restrict__ dtbf, const u16* __restrict__ ubf,
             const float* __restrict__ ssm, const float* __restrict__ Alog,
             const int* __restrict__ flag,
             float* __restrict__ cst, float* __restrict__ dts)
{
    __shared__ float Bsh[TC][D_STATE];
    const int tid = threadIdx.x;
    const int i2  = blockIdx.x * 256 + tid;     // channel pair index
    const int c0  = i2 * 2;
    const int g   = blockIdx.y;
    const int b   = blockIdx.z;
    const int t0  = g * TC;
    {
        int t = tid >> 4, n = tid & 15;        // TC*16 = 256
        Bsh[t][n] = ssm[(size_t)(b * SEQ + t0 + t) * XROWS + DT_RANK + n];
    }
    __syncthreads();

    float s0[D_STATE], s1[D_STATE];
#pragma unroll
    for (int n = 0; n < D_STATE; ++n) { s0[n] = 0.f; s1[n] = 0.f; }
    float ds0 = 0.f, ds1 = 0.f;

    const u32* dtp = (const u32*)dtbf + ((size_t)(b * SEQ + t0) * INTER >> 1) + i2;
    const u32* up  = (const u32*)ubf  + ((size_t)(b * SEQ + t0) * INTER >> 1) + i2;

    if (flag[0]) {
#pragma unroll
        for (int t = 0; t < TC; ++t) {
            u32 dp = dtp[(size_t)t * (INTER / 2)];
            u32 uq = up[(size_t)t * (INTER / 2)];
            float dta = b2f((u16)dp), dtb = b2f((u16)(dp >> 16));
            float ua  = b2f((u16)uq), ub  = b2f((u16)(uq >> 16));
            float dua = dta * ua, dub = dtb * ub;
            ds0 += dta; ds1 += dtb;
            float wa = __expf(-dta), wb = __expf(-dtb);
            POWCH(wa, wa) POWCH(wb, wb)
            const float (*Bv)[D_STATE] = nullptr; (void)Bv;
            f32x4 Bq[4];
#pragma unroll
            for (int q = 0; q < 4; ++q) Bq[q] = *(const f32x4*)&Bsh[t][q * 4];
            SUPD(s0, Bq, dua, wa)
            SUPD(s1, Bq, dub, wb)
        }
    } else {
        float a0[D_STATE], a1[D_STATE];
#pragma unroll
        for (int n = 0; n < D_STATE; ++n) {
            a0[n] = -__expf(Alog[(size_t)c0 * D_STATE + n]);
            a1[n] = -__expf(Alog[(size_t)(c0 + 1) * D_STATE + n]);
        }
        for (int t = 0; t < TC; ++t) {
            u32 dp = dtp[(size_t)t * (INTER / 2)];
            u32 uq = up[(size_t)t * (INTER / 2)];
            float dta = b2f((u16)dp), dtb = b2f((u16)(dp >> 16));
            float ua  = b2f((u16)uq), ub  = b2f((u16)(uq >> 16));
            float dua = dta * ua, dub = dtb * ub;
            ds0 += dta; ds1 += dtb;
#pragma unroll
            for (int n = 0; n < D_STATE; ++n) {
                float Bn = Bsh[t][n];
                s0[n] = __expf(dta * a0[n]) * s0[n] + dua * Bn;
                s1[n] = __expf(dtb * a1[n]) * s1[n] + dub * Bn;
            }
        }
    }
    size_t o = ((size_t)(b * GCH + g) * INTER + c0) * D_STATE;
#pragma unroll
    for (int n = 0; n < D_STATE; n += 4) {
        f32x4 v0 = { s0[n], s0[n+1], s0[n+2], s0[n+3] };
        f32x4 v1 = { s1[n], s1[n+1], s1[n+2], s1[n+3] };
        *(f32x4*)&cst[o + n] = v0;
        *(f32x4*)&cst[o + D_STATE + n] = v1;
    }
    size_t od = (size_t)(b * GCH + g) * INTER + c0;
    dts[od] = ds0; dts[od + 1] = ds1;
}

// in-place: cst local chunk-end -> chunk-START states.
__global__ __launch_bounds__(256)
void scan2_k(float* __restrict__ cst, const float* __restrict__ dts,
             const float* __restrict__ Alog)
{
    int idx = blockIdx.x * 256 + threadIdx.x;
    int sub = idx & 3;
    int i   = (idx >> 2) & (INTER - 1);
    int b   = idx >> 13;
    int n0  = sub * 4;
    float a[4];
#pragma unroll
    for (int n = 0; n < 4; ++n)
        a[n] = -__expf(Alog[(size_t)i * D_STATE + n0 + n]);
    f32x4 s = (f32x4)0.f;
    for (int g = 0; g < GCH; ++g) {
        size_t o = ((size_t)(b * GCH + g) * INTER + i) * D_STATE + n0;
        f32x4 tmp = *(const f32x4*)&cst[o];
        *(f32x4*)&cst[o] = s;
        float d = dts[(size_t)(b * GCH + g) * INTER + i];
#pragma unroll
        for (int n = 0; n < 4; ++n)
            s[n] = __expf(a[n] * d) * s[n] + tmp[n];
    }
}

__global__ __launch_bounds__(256)
void scan3_k(const u16* __restrict__ dtbf, const u16* __restrict__ ubf,
             const float* __restrict__ ssm, const u16* __restrict__ projbf,
             const float* __restrict__ Alog, const float* __restrict__ Dp,
             const int* __restrict__ flag,
             const float* __restrict__ sst, u16* __restrict__ ybf)
{
    __shared__ float Bsh[TC][D_STATE];
    __shared__ float Csh[TC][D_STATE];
    const int tid = threadIdx.x;
    const int i2  = blockIdx.x * 256 + tid;
    const int c0  = i2 * 2;
    const int g   = blockIdx.y;
    const int b   = blockIdx.z;
    const int t0  = g * TC;
    {
        int t = tid >> 4, n = tid & 15;
        size_t row = (size_t)(b * SEQ + t0 + t) * XROWS;
        Bsh[t][n] = ssm[row + DT_RANK + n];
        Csh[t][n] = ssm[row + DT_RANK + D_STATE + n];
    }
    __syncthreads();

    const float Da = Dp[c0], Db = Dp[c0 + 1];
    float s0[D_STATE], s1[D_STATE];
    size_t so = ((size_t)(b * GCH + g) * INTER + c0) * D_STATE;
#pragma unroll
    for (int n = 0; n < D_STATE; n += 4) {
        f32x4 v0 = *(const f32x4*)&sst[so + n];
        f32x4 v1 = *(const f32x4*)&sst[so + D_STATE + n];
        s0[n] = v0[0]; s0[n+1] = v0[1]; s0[n+2] = v0[2]; s0[n+3] = v0[3];
        s1[n] = v1[0]; s1[n+1] = v1[1]; s1[n+2] = v1[2]; s1[n+3] = v1[3];
    }

    const u32* dtp = (const u32*)dtbf + ((size_t)(b * SEQ + t0) * INTER >> 1) + i2;
    const u32* up  = (const u32*)ubf  + ((size_t)(b * SEQ + t0) * INTER >> 1) + i2;
    const u32* gp  = (const u32*)projbf + (((size_t)(b * SEQ + t0) * 4096 + INTER) >> 1) + i2;
    u32*       yp  = (u32*)ybf + ((size_t)(b * SEQ + t0) * INTER >> 1) + i2;

    if (flag[0]) {
#pragma unroll
        for (int t = 0; t < TC; ++t) {
            u32 dp = dtp[(size_t)t * (INTER / 2)];
            u32 uq = up[(size_t)t * (INTER / 2)];
            u32 gq = gp[(size_t)t * (4096 / 2)];
            float dta = b2f((u16)dp), dtb = b2f((u16)(dp >> 16));
            float ua  = b2f((u16)uq), ub  = b2f((u16)(uq >> 16));
            float ga  = b2f((u16)gq), gb  = b2f((u16)(gq >> 16));
            float dua = dta * ua, dub = dtb * ub;
            float wa = __expf(-dta), wb = __expf(-dtb);
            POWCH(wa, wa) POWCH(wb, wb)
            f32x4 Bq[4], Cq[4];
#pragma unroll
            for (int q = 0; q < 4; ++q) {
                Bq[q] = *(const f32x4*)&Bsh[t][q * 4];
                Cq[q] = *(const f32x4*)&Csh[t][q * 4];
            }
            SUPD(s0, Bq, dua, wa)
            SUPD(s1, Bq, dub, wb)
            float y0 = YDOT(s0, Cq);
            float y1 = YDOT(s1, Cq);
            y0 = (y0 + Da * ua) * silu(ga);
            y1 = (y1 + Db * ub) * silu(gb);
            yp[(size_t)t * (INTER / 2)] = (u32)f2b(y0) | ((u32)f2b(y1) << 16);
        }
    } else {
        float a0[D_STATE], a1[D_STATE];
#pragma unroll
        for (int n = 0; n < D_STATE; ++n) {
            a0[n] = -__expf(Alog[(size_t)c0 * D_STATE + n]);
            a1[n] = -__expf(Alog[(size_t)(c0 + 1) * D_STATE + n]);
        }
        for (int t = 0; t < TC; ++t) {
            u32 dp = dtp[(size_t)t * (INTER / 2)];
            u32 uq = up[(size_t)t * (INTER / 2)];
            u32 gq = gp[(size_t)t * (4096 / 2)];
            float dta = b2f((u16)dp), dtb = b2f((u16)(dp >> 16));
            float ua  = b2f((u16)uq), ub  = b2f((u16)(uq >> 16));
            float ga  = b2f((u16)gq), gb  = b2f((u16)(gq >> 16));
            float dua = dta * ua, dub = dtb * ub;
            float y0 = 0.f, y1 = 0.f;
#pragma unroll
            for (int n = 0; n < D_STATE; ++n) {
                float Bn = Bsh[t][n], Cn = Csh[t][n];
                s0[n] = __expf(dta * a0[n]) * s0[n] + dua * Bn;
                s1[n] = __expf(dtb * a1[n]) * s1[n] + dub * Bn;
                y0 += s0[n] * Cn; y1 += s1[n] * Cn;
            }
            y0 = (y0 + Da * ua) * silu(ga);
            y1 = (y1 + Db * ub) * silu(gb);
            yp[(size_t)t * (INTER / 2)] = (u32)f2b(y0) | ((u32)f2b(y1) << 16);
        }
    }
}

// ---------------------------------------------------------------------------
__global__ __launch_bounds__(256)
void cvt_f2b_k(const float* __restrict__ in, u16* __restrict__ out, int n)
{
    int idx = blockIdx.x * 256 + threadIdx.x;
    if (idx < n) out[idx] = f2b(in[idx]);
}

__global__ __launch_bounds__(256)
void pad_xw_k(const float* __restrict__ xw, u16* __restrict__ out)
{
    int idx = blockIdx.x * 256 + threadIdx.x;
    if (idx >= N_LAYERS * XROWS * INTER) return;
    int l = idx / (XROWS * INTER);
    int r = (idx >> 11) & (XROWS - 1);
    int c = idx & (INTER - 1);
    out[idx] = (r < 96) ? f2b(xw[((size_t)l * 96 + r) * INTER + c]) : (u16)0;
}

// ---------------------------------------------------------------------------
extern "C" void kernel_launch(void* const* d_in, const int* in_sizes, int n_in,
                              void* d_out, int out_size, void* d_ws, size_t ws_size,
                              hipStream_t stream)
{
    const float* x      = (const float*)d_in[0];
    const float* in_w   = (const float*)d_in[1];
    const float* conv_w = (const float*)d_in[2];
    const float* conv_b = (const float*)d_in[3];
    const float* x_w    = (const float*)d_in[4];
    const float* dt_w   = (const float*)d_in[5];
    const float* dt_b   = (const float*)d_in[6];
    const float* A_log  = (const float*)d_in[7];
    const float* Dp     = (const float*)d_in[8];
    const float* out_w  = (const float*)d_in[9];
    const float* norm_w = (const float*)d_in[10];
    const float* norm_f = (const float*)d_in[11];

    char* ws = (char*)d_ws;
    size_t off = 0;
    auto alloc = [&](size_t bytes) { char* p = ws + off; off += (bytes + 255) & ~(size_t)255; return p; };

    u16*   inw_bf  = (u16*)  alloc((size_t)N_LAYERS * 4096 * 1024 * 2);
    u16*   xw_bf   = (u16*)  alloc((size_t)N_LAYERS * XROWS * INTER * 2);
    u16*   dtw_bf  = (u16*)  alloc((size_t)N_LAYERS * INTER * DT_RANK * 2);
    u16*   outw_bf = (u16*)  alloc((size_t)N_LAYERS * D_MODEL * INTER * 2);
    float* h       = (float*)alloc((size_t)TOK * D_MODEL * 4);
    u16*   xn_bf   = (u16*)  alloc((size_t)TOK * D_MODEL * 2);
    u16*   proj_bf = (u16*)  alloc((size_t)TOK * 4096 * 2);
    u16*   u_bf    = (u16*)  alloc((size_t)TOK * INTER * 2);
    float* ssm     = (float*)alloc((size_t)TOK * XROWS * 4);
    // shared partials buffer: x_proj partials (8.4MB) and out_proj partials
    // (33.6MB) have disjoint lifetimes within a layer -> alias.
    float* parts   = (float*)alloc((size_t)OSPL * TOK * D_MODEL * 4);
    u16*   dtr_bf  = (u16*)  alloc((size_t)TOK * DT_RANK * 2);
    u16*   dt_bf   = (u16*)  alloc((size_t)TOK * INTER * 2);
    u16*   y_bf    = (u16*)  alloc((size_t)TOK * INTER * 2);
    float* cst     = (float*)alloc((size_t)B_SZ * GCH * INTER * D_STATE * 4);
    float* dts     = (float*)alloc((size_t)B_SZ * GCH * INTER * 4);
    int*   aflags  = (int*)  alloc(N_LAYERS * sizeof(int));
    (void)ws_size; (void)n_in; (void)in_sizes; (void)out_size;

    // weight conversion + A_log structure check (every launch; deterministic)
    {
        int n = N_LAYERS * 4096 * 1024;
        cvt_f2b_k<<<n / 256, 256, 0, stream>>>(in_w, inw_bf, n);
        int np = N_LAYERS * XROWS * INTER;
        pad_xw_k<<<np / 256, 256, 0, stream>>>(x_w, xw_bf);
        int nd = N_LAYERS * INTER * DT_RANK;
        cvt_f2b_k<<<nd / 256, 256, 0, stream>>>(dt_w, dtw_bf, nd);
        int no = N_LAYERS * D_MODEL * INTER;
        cvt_f2b_k<<<no / 256, 256, 0, stream>>>(out_w, outw_bf, no);
        hipMemsetAsync(aflags, 0xFF, N_LAYERS * sizeof(int), stream);
        int na = N_LAYERS * INTER * D_STATE;
        achk_k<<<(na + 255) / 256, 256, 0, stream>>>(A_log, aflags);
    }

    for (int l = 0; l < N_LAYERS; ++l) {
        // 1. residual + rmsnorm -> xn_bf (and h update for l>=1)
        if (l == 0)
            rmsnorm_k<1><<<TOK, 256, 0, stream>>>(x, norm_w, xn_bf);
        else
            rmsnorm_res_k<1, 1><<<TOK, 256, 0, stream>>>(
                (l == 1) ? x : h, parts, norm_w + (size_t)l * D_MODEL, h, xn_bf);
        // 2. in_proj (256^2 8-phase): [4096,1024] @ [4096,1024]^T -> proj_bf
        gemm256_k<<<dim3(16, 16), 512, 0, stream>>>(
            xn_bf, inw_bf + (size_t)l * 4096 * 1024, proj_bf, 1024, 4096);
        // 3. conv + silu -> u_bf
        conv_silu_k<<<TOK, 256, 0, stream>>>(
            proj_bf, conv_w + (size_t)l * INTER * D_CONV, conv_b + (size_t)l * INTER, u_bf);
        // 4. x_proj split-K -> partials (aliased buffer)
        gemm_bt<4, 1><<<dim3(KSPL, 32), 256, 0, stream>>>(
            u_bf, xw_bf + (size_t)l * XROWS * INTER, parts, nullptr,
            INTER / KSPL, INTER, XROWS, (size_t)TOK * XROWS);
        // 4b. reduce partials -> ssm fp32 + dtr bf16
        xred_k<<<(TOK * 32) / 256, 256, 0, stream>>>(parts, ssm, dtr_bf);
        // 5. dt_proj + softplus -> dt_bf [4096,2048]
        gemm_bt<2><<<dim3(16, 32), 256, 0, stream>>>(
            dtr_bf, dtw_bf + (size_t)l * INTER * DT_RANK, dt_bf,
            dt_b + (size_t)l * INTER, DT_RANK, DT_RANK, INTER, 0);
        // 6. chunked scan (+ skip + gate) -> y_bf
        scan1_k<<<dim3(INTER / 512, GCH, B_SZ), 256, 0, stream>>>(
            dt_bf, u_bf, ssm, A_log + (size_t)l * INTER * D_STATE, aflags + l, cst, dts);
        scan2_k<<<(B_SZ * INTER * 4) / 256, 256, 0, stream>>>(
            cst, dts, A_log + (size_t)l * INTER * D_STATE);
        scan3_k<<<dim3(INTER / 512, GCH, B_SZ), 256, 0, stream>>>(
            dt_bf, u_bf, ssm, proj_bf, A_log + (size_t)l * INTER * D_STATE,
            Dp + (size_t)l * INTER, aflags + l, cst, y_bf);
        // 7. out_proj split-K -> partials (consumed by next rmsnorm_res)
        gemm_bt<4, 8><<<dim3(OSPL * 8, 32), 256, 0, stream>>>(
            y_bf, outw_bf + (size_t)l * D_MODEL * INTER, parts, nullptr,
            INTER / OSPL, INTER, D_MODEL, (size_t)TOK * D_MODEL);
    }
    // final residual + rmsnorm -> d_out (fp32)
    rmsnorm_res_k<0, 0><<<TOK, 256, 0, stream>>>(
        h, parts, norm_f, nullptr, d_out);
}